// Round 9
// baseline (393.981 us; speedup 1.0000x reference)
//
#include <hip/hip_runtime.h>

typedef __attribute__((ext_vector_type(8))) short s16x8;
typedef __attribute__((ext_vector_type(4))) float f32x4;
typedef __attribute__((ext_vector_type(16))) float f32x16;
typedef __attribute__((ext_vector_type(4))) uint u32x4;

#define MFMA16(a, b, c) __builtin_amdgcn_mfma_f32_16x16x32_bf16((a), (b), (c), 0, 0, 0)
#define MFMA32(a, b, c) __builtin_amdgcn_mfma_f32_32x32x16_bf16((a), (b), (c), 0, 0, 0)

__device__ __forceinline__ ushort f2bf(float f) {
  uint u = __builtin_bit_cast(uint, f);
  u = (u + 0x7fffu + ((u >> 16) & 1u)) >> 16;
  return (ushort)u;
}

// ---------------- weight fp32 -> bf16 ----------------
__global__ __launch_bounds__(256) void cvt_w_kernel(
    const float* __restrict__ s0, const float* __restrict__ s1,
    const float* __restrict__ s2, const float* __restrict__ s3,
    ushort* __restrict__ d0, ushort* __restrict__ d1,
    ushort* __restrict__ d2, ushort* __restrict__ d3) {
  int i = blockIdx.x * 256 + threadIdx.x;
  const float4* s[4] = {(const float4*)s0, (const float4*)s1, (const float4*)s2, (const float4*)s3};
  ushort* d[4] = {d0, d1, d2, d3};
#pragma unroll
  for (int m = 0; m < 4; ++m) {
    float4 v = s[m][i];
    uint lo = (uint)f2bf(v.x) | ((uint)f2bf(v.y) << 16);
    uint hi = (uint)f2bf(v.z) | ((uint)f2bf(v.w) << 16);
    *(uint2*)(d[m] + (size_t)i * 4) = make_uint2(lo, hi);
  }
}

// ---------------- GroupNorm stats -> per-channel scale/shift ----------------
__global__ __launch_bounds__(256) void gn_stats_kernel(
    const float* __restrict__ x, const float* __restrict__ gw,
    const float* __restrict__ gb, float* __restrict__ scaleB,
    float* __restrict__ shiftB) {
  int b = blockIdx.x >> 3, g = blockIdx.x & 7;
  const float4* src = (const float4*)(x + ((size_t)b * 256 + g * 32) * 4096);
  float s = 0.f, ss = 0.f;
  for (int i = threadIdx.x; i < 32768; i += 256) {
    float4 v = src[i];
    s += v.x + v.y + v.z + v.w;
    ss += v.x * v.x + v.y * v.y + v.z * v.z + v.w * v.w;
  }
#pragma unroll
  for (int off = 32; off; off >>= 1) {
    s += __shfl_down(s, off);
    ss += __shfl_down(ss, off);
  }
  __shared__ float ps[4], pss[4];
  __shared__ float smu, srs;
  int w = threadIdx.x >> 6, lane = threadIdx.x & 63;
  if (lane == 0) { ps[w] = s; pss[w] = ss; }
  __syncthreads();
  if (threadIdx.x == 0) {
    float S = ps[0] + ps[1] + ps[2] + ps[3];
    float SS = pss[0] + pss[1] + pss[2] + pss[3];
    float mu = S * (1.f / 131072.f);
    float var = SS * (1.f / 131072.f) - mu * mu;
    smu = mu;
    srs = rsqrtf(var + 1e-5f);
  }
  __syncthreads();
  if (threadIdx.x < 32) {
    int ch = g * 32 + threadIdx.x;
    float sc = gw[ch] * srs;
    scaleB[b * 256 + ch] = sc;
    shiftB[b * 256 + ch] = gb[ch] - smu * sc;
  }
}

// ---------------- GN apply + transpose: x[b][c][n] -> y[b][n][c] bf16 ----------------
__global__ __launch_bounds__(256) void gn_apply_kernel(
    const float* __restrict__ x, const float* __restrict__ scaleB,
    const float* __restrict__ shiftB, ushort* __restrict__ y) {
  int bid = blockIdx.x;
  int b = bid >> 8;
  int rem = bid & 255;
  int ct = rem >> 6, nt = rem & 63;
  int t = threadIdx.x;
  __shared__ float xs[64][65];
  const float* xb = x + ((size_t)b * 256 + ct * 64) * 4096 + nt * 64;
  {
    int r = t >> 2, q = t & 3;
    const float4* src = (const float4*)(xb + (size_t)r * 4096 + q * 16);
#pragma unroll
    for (int i = 0; i < 4; ++i) {
      float4 v = src[i];
      xs[r][q * 16 + i * 4 + 0] = v.x;
      xs[r][q * 16 + i * 4 + 1] = v.y;
      xs[r][q * 16 + i * 4 + 2] = v.z;
      xs[r][q * 16 + i * 4 + 3] = v.w;
    }
  }
  __syncthreads();
  {
    int nr = t >> 2, q = t & 3;
    int c0 = q * 16;
    ushort tmp[16];
#pragma unroll
    for (int i = 0; i < 16; ++i) {
      int ch = ct * 64 + c0 + i;
      float v = xs[c0 + i][nr] * scaleB[b * 256 + ch] + shiftB[b * 256 + ch];
      tmp[i] = f2bf(v);
    }
    ushort* dst = y + ((size_t)b * 4096 + nt * 64 + nr) * 256 + ct * 64 + c0;
    uint p[8];
#pragma unroll
    for (int j = 0; j < 8; ++j) p[j] = (uint)tmp[2 * j] | ((uint)tmp[2 * j + 1] << 16);
    *(uint4*)dst = make_uint4(p[0], p[1], p[2], p[3]);
    *((uint4*)dst + 1) = make_uint4(p[4], p[5], p[6], p[7]);
  }
}

// ---------------- GEMM: C[M][N] = A[M][256] . B[N][256]^T (+bias, +resid) ----------------
template <int MODE>
__global__ __launch_bounds__(256) void gemm_bt(
    const ushort* __restrict__ A, const ushort* __restrict__ B,
    size_t aB, size_t bB, int M, int N,
    const float* __restrict__ bias, const float* __restrict__ resid,
    size_t rB, void* __restrict__ Cout, size_t cB) {
  int mTiles = M >> 7;
  int tm = blockIdx.x % mTiles, tn = blockIdx.x / mTiles;
  const ushort* Ab = A + blockIdx.y * aB + (size_t)tm * 128 * 256;
  const ushort* Bb = B + blockIdx.y * bB + (size_t)tn * 128 * 256;

  __shared__ ushort As[128 * 72];
  __shared__ ushort Bs[128 * 72];

  int t = threadIdx.x, lane = t & 63, w = t >> 6;
  int wr = w >> 1, wc = w & 1, lq = lane & 15, lg = lane >> 4;

  f32x4 acc[4][4];
#pragma unroll
  for (int i = 0; i < 4; ++i)
#pragma unroll
    for (int j = 0; j < 4; ++j) acc[i][j] = f32x4{0.f, 0.f, 0.f, 0.f};

  int srow = t >> 1, shalf = t & 1;
#pragma unroll 1
  for (int kb = 0; kb < 4; ++kb) {
    __syncthreads();
    {
      const ushort* sa = Ab + (size_t)srow * 256 + kb * 64 + shalf * 32;
      const ushort* sb = Bb + (size_t)srow * 256 + kb * 64 + shalf * 32;
      ushort* da = &As[srow * 72 + shalf * 32];
      ushort* db = &Bs[srow * 72 + shalf * 32];
#pragma unroll
      for (int j = 0; j < 4; ++j) {
        *(uint4*)(da + j * 8) = *(const uint4*)(sa + j * 8);
        *(uint4*)(db + j * 8) = *(const uint4*)(sb + j * 8);
      }
    }
    __syncthreads();
#pragma unroll
    for (int ks = 0; ks < 2; ++ks) {
      s16x8 af[4], bf[4];
#pragma unroll
      for (int mt = 0; mt < 4; ++mt)
        af[mt] = *(const s16x8*)&As[(wr * 64 + mt * 16 + lq) * 72 + ks * 32 + lg * 8];
#pragma unroll
      for (int nt = 0; nt < 4; ++nt)
        bf[nt] = *(const s16x8*)&Bs[(wc * 64 + nt * 16 + lq) * 72 + ks * 32 + lg * 8];
#pragma unroll
      for (int mt = 0; mt < 4; ++mt)
#pragma unroll
        for (int nt = 0; nt < 4; ++nt)
          acc[mt][nt] = MFMA16(af[mt], bf[nt], acc[mt][nt]);
    }
  }

  int mBase = tm * 128 + wr * 64;
  int nBase = tn * 128 + wc * 64;
#pragma unroll
  for (int mt = 0; mt < 4; ++mt) {
#pragma unroll
    for (int nt = 0; nt < 4; ++nt) {
#pragma unroll
      for (int r = 0; r < 4; ++r) {
        int row = mBase + mt * 16 + lg * 4 + r;
        int col = nBase + nt * 16 + lq;
        size_t idx = (size_t)row * N + col;
        float v = acc[mt][nt][r];
        if (MODE == 0) v += bias[col];
        else v += bias[row];
        if (MODE == 2) {
          float* C = (float*)Cout + blockIdx.y * cB;
          C[idx] = v + resid[blockIdx.y * rB + idx];
        } else {
          ushort* C = (ushort*)Cout + blockIdx.y * cB;
          C[idx] = f2bf(v);
        }
      }
    }
  }
}

// ---------------- Flash attention v7: KVBLK=64 (2 sub-passes per barrier pair) ----------------
// Grid 256 = 8 batch x 16 qtiles x 2 kv-halves; 512 thr = 8 waves x 32 q-rows.
// Per big-iter: stage TWO 32-kv chunks (64KB buf, dbuf=128KB LDS), compute two
// sequential 32-kv passes between ONE barrier pair -> barrier tax amortized 2x.
__global__ __launch_bounds__(512, 1) void attn7_kernel(
    const ushort* __restrict__ q, const ushort* __restrict__ k,
    const ushort* __restrict__ vT, ushort* __restrict__ pb0,
    ushort* __restrict__ pb1, float* __restrict__ mlbuf) {
  const int bb = blockIdx.x & 7;          // batch -> XCD pinning
  const int rem = blockIdx.x >> 3;        // 0..31
  const int qt = rem & 15;                // 16 qtiles x 256 rows
  const int half = rem >> 4;              // kv half
  const int t = threadIdx.x, w = t >> 6, lane = t & 63;
  const int lq = lane & 31, lh = lane >> 5;

  // 2 bufs x 32768 ushorts; buf db, sub s: K at db*32768+s*16384, V at +8192
  __shared__ ushort Lf[65536];

  const ushort* kb = k + (size_t)bb * (4096 * 256);
  const ushort* vb = vT + (size_t)bb * (4096 * 256);

  // Q fragments (loop-invariant)
  const int qrow = bb * 4096 + qt * 256 + w * 32 + lq;
  s16x8 qf[16];
  {
    const ushort* qp = q + (size_t)qrow * 256 + lh * 8;
#pragma unroll
    for (int ct = 0; ct < 16; ++ct) qf[ct] = *(const s16x8*)(qp + ct * 16);
  }
  f32x16 oacc[8];
#pragma unroll
  for (int i = 0; i < 8; ++i) oacc[i] = (f32x16)(0.f);
  float mrun = -3e38f, lrun = 0.f;

  // stage one 32-row chunk (32KB) at ushort offset `dst`; 4 gload_lds per thread
  auto stage = [&](int it, int dst) {
    const int ci = half * 64 + it;
    const ushort* kcb = kb + (size_t)ci * (32 * 256);
    const ushort* vcb = vb + (size_t)ci * 32;
    ushort* base = Lf + dst;
#pragma unroll
    for (int i = 0; i < 4; ++i) {
      int bu = (w * 4 + i) * 64;          // wave-uniform base unit (16B units)
      int u = bu + lane;
      if (bu < 1024) {                    // K region: row-major, unit-XOR swizzle
        int row = u >> 5, c = u & 31;
        const ushort* ksrc = kcb + row * 256 + ((c ^ (row & 7)) << 3);
        __builtin_amdgcn_global_load_lds(
            (const __attribute__((address_space(1))) uint*)ksrc,
            (__attribute__((address_space(3))) uint*)(base + bu * 8), 16, 0, 0);
      } else {                            // V region: row-pair swizzle
        int tv = u - 1024;
        int rp = tv >> 3, s8 = tv & 7;
        int x = s8 ^ (rp & 7);
        int vrow = rp * 2 + (x >> 2), uu = x & 3;
        const ushort* vsrc = vcb + (size_t)vrow * 4096 + uu * 8;
        __builtin_amdgcn_global_load_lds(
            (const __attribute__((address_space(1))) uint*)vsrc,
            (__attribute__((address_space(3))) uint*)(base + bu * 8), 16, 0, 0);
      }
    }
  };

  const int rp7 = (lq >> 1) & 7;
  const int b4 = (lq & 1) * 4;

  stage(0, 0);
  stage(1, 16384);

#pragma unroll 1
  for (int j = 0; j < 32; ++j) {
    if (j < 31) {
      int nb = ((j + 1) & 1) * 32768;
      stage(2 * j + 2, nb);
      stage(2 * j + 3, nb + 16384);
      asm volatile("s_waitcnt vmcnt(8)" ::: "memory");
    } else {
      asm volatile("s_waitcnt vmcnt(0)" ::: "memory");
    }
    __builtin_amdgcn_s_barrier();

#pragma unroll
    for (int s = 0; s < 2; ++s) {
      const ushort* Kbf = Lf + (j & 1) * 32768 + s * 16384;
      const ushort* Vbf = Kbf + 8192;

      // ---- QK^T: 16 MFMAs, 2 interleaved accumulator chains ----
      __builtin_amdgcn_s_setprio(1);
      f32x16 s0 = (f32x16)(0.f), s1 = (f32x16)(0.f);
#pragma unroll
      for (int ct = 0; ct < 16; ct += 2) {
        int u0 = (ct * 2 + lh) ^ (lq & 7);
        int u1 = ((ct + 1) * 2 + lh) ^ (lq & 7);
        s16x8 kf0 = *(const s16x8*)(Kbf + lq * 256 + u0 * 8);
        s16x8 kf1 = *(const s16x8*)(Kbf + lq * 256 + u1 * 8);
        s0 = MFMA32(kf0, qf[ct], s0);
        s1 = MFMA32(kf1, qf[ct + 1], s1);
      }
      __builtin_amdgcn_s_setprio(0);
      // ---- in-register online softmax ----
      float sv[16];
#pragma unroll
      for (int r = 0; r < 16; ++r) sv[r] = (s0[r] + s1[r]) * 0.0625f;
      float pmax = sv[0];
#pragma unroll
      for (int r = 1; r < 16; ++r) pmax = fmaxf(pmax, sv[r]);
      pmax = fmaxf(pmax, __shfl_xor(pmax, 32));
      if (!__all(pmax - mrun <= 8.f)) {   // defer-max (T13)
        float mnew = fmaxf(mrun, pmax);
        float alpha = __expf(mrun - mnew);
#pragma unroll
        for (int i = 0; i < 8; ++i) oacc[i] *= alpha;
        lrun *= alpha;
        mrun = mnew;
      }
      float p[16], psum = 0.f;
#pragma unroll
      for (int r = 0; r < 16; ++r) {
        p[r] = __expf(sv[r] - mrun);
        psum += p[r];
      }
      psum += __shfl_xor(psum, 32);
      lrun += psum;
      // ---- P -> PV B-frags (T12) ----
      uint c00, c01, c10, c11, c20, c21, c30, c31;
      asm("v_cvt_pk_bf16_f32 %0, %1, %2" : "=v"(c00) : "v"(p[0]),  "v"(p[1]));
      asm("v_cvt_pk_bf16_f32 %0, %1, %2" : "=v"(c01) : "v"(p[2]),  "v"(p[3]));
      asm("v_cvt_pk_bf16_f32 %0, %1, %2" : "=v"(c10) : "v"(p[4]),  "v"(p[5]));
      asm("v_cvt_pk_bf16_f32 %0, %1, %2" : "=v"(c11) : "v"(p[6]),  "v"(p[7]));
      asm("v_cvt_pk_bf16_f32 %0, %1, %2" : "=v"(c20) : "v"(p[8]),  "v"(p[9]));
      asm("v_cvt_pk_bf16_f32 %0, %1, %2" : "=v"(c21) : "v"(p[10]), "v"(p[11]));
      asm("v_cvt_pk_bf16_f32 %0, %1, %2" : "=v"(c30) : "v"(p[12]), "v"(p[13]));
      asm("v_cvt_pk_bf16_f32 %0, %1, %2" : "=v"(c31) : "v"(p[14]), "v"(p[15]));
      asm("v_permlane32_swap_b32 %0, %1" : "+v"(c00), "+v"(c10));
      asm("v_permlane32_swap_b32 %0, %1" : "+v"(c01), "+v"(c11));
      asm("v_permlane32_swap_b32 %0, %1" : "+v"(c20), "+v"(c30));
      asm("v_permlane32_swap_b32 %0, %1" : "+v"(c21), "+v"(c31));
      u32x4 t0 = {c00, c01, c10, c11};
      u32x4 t1 = {c20, c21, c30, c31};
      s16x8 pf0 = __builtin_bit_cast(s16x8, t0);
      s16x8 pf1 = __builtin_bit_cast(s16x8, t1);
      // ---- PV: A-frags from swizzled V LDS ----
      __builtin_amdgcn_s_setprio(1);
#pragma unroll
      for (int db = 0; db < 8; ++db) {
        const ushort* base = Vbf + (db * 16 + (lq >> 1)) * 64;
        int sl0 = (b4 + lh) ^ rp7;
        int sl1 = (b4 + 2 + lh) ^ rp7;
        s16x8 vf0 = *(const s16x8*)(base + sl0 * 8);
        s16x8 vf1 = *(const s16x8*)(base + sl1 * 8);
        oacc[db] = MFMA32(vf0, pf0, oacc[db]);
        oacc[db] = MFMA32(vf1, pf1, oacc[db]);
      }
      __builtin_amdgcn_s_setprio(0);
    }

    asm volatile("" ::: "memory");
    __builtin_amdgcn_s_barrier();
    asm volatile("" ::: "memory");
  }

  // ---- epilogue: raw partials -> LDS transpose (XOR-swz) -> coalesced store ----
  {
    uint* wregu = (uint*)Lf + w * 4096;   // 32 q-rows x 128 uints per wave
#pragma unroll
    for (int db = 0; db < 8; ++db)
#pragma unroll
      for (int rp = 0; rp < 8; ++rp) {
        int r0 = rp * 2;
        int d0 = db * 32 + (r0 & 3) + 8 * (r0 >> 2) + 4 * lh;
        uint pk;
        asm("v_cvt_pk_bf16_f32 %0, %1, %2"
            : "=v"(pk) : "v"(oacc[db][r0]), "v"(oacc[db][r0 + 1]));
        int idx = lq * 128 + (d0 >> 1);
        wregu[idx ^ ((lq & 7) << 2)] = pk;
      }
    if (lh == 0) {
      int idx = half * 32768 + bb * 4096 + qt * 256 + w * 32 + lq;
      mlbuf[idx] = mrun;
      mlbuf[65536 + idx] = lrun;
    }
  }
  __syncthreads();
  {
    int r = t >> 1;                        // 0..255 row in tile
    int wv2 = r >> 5, lqr = r & 31;
    const uint* basep = (const uint*)Lf + wv2 * 4096;
    ushort* pbase = half ? pb1 : pb0;
    ushort* dstr = pbase + ((size_t)bb * 4096 + qt * 256 + r) * 256 + (t & 1) * 128;
#pragma unroll
    for (int jj = 0; jj < 16; ++jj) {
      int ui = lqr * 128 + (t & 1) * 64 + jj * 4;
      u32x4 v = *(const u32x4*)(basep + (ui ^ ((lqr & 7) << 2)));
      *(u32x4*)(dstr + jj * 8) = v;
    }
  }
}

// ---------------- merge the two kv-half partials ----------------
__global__ __launch_bounds__(256) void attn_merge_kernel(
    const ushort* __restrict__ pb0, const ushort* __restrict__ pb1,
    const float* __restrict__ mlbuf, ushort* __restrict__ o) {
  int gr = blockIdx.x * 8 + (threadIdx.x >> 5);   // global row 0..32767
  int dq = threadIdx.x & 31;                      // 8 d-elems each
  float m0 = mlbuf[gr], m1 = mlbuf[32768 + gr];
  float l0 = mlbuf[65536 + gr], l1 = mlbuf[65536 + 32768 + gr];
  float M = fmaxf(m0, m1);
  float e0 = __expf(m0 - M), e1 = __expf(m1 - M);
  float inv = 1.f / (l0 * e0 + l1 * e1);
  float w0 = e0 * inv, w1 = e1 * inv;
  const size_t off = (size_t)gr * 256 + dq * 8;
  u32x4 a = *(const u32x4*)(pb0 + off);
  u32x4 b = *(const u32x4*)(pb1 + off);
  uint outw[4];
#pragma unroll
  for (int i = 0; i < 4; ++i) {
    float alo = __builtin_bit_cast(float, a[i] << 16);
    float ahi = __builtin_bit_cast(float, a[i] & 0xffff0000u);
    float blo = __builtin_bit_cast(float, b[i] << 16);
    float bhi = __builtin_bit_cast(float, b[i] & 0xffff0000u);
    float flo = alo * w0 + blo * w1;
    float fhi = ahi * w0 + bhi * w1;
    asm("v_cvt_pk_bf16_f32 %0, %1, %2" : "=v"(outw[i]) : "v"(flo), "v"(fhi));
  }
  u32x4 ov = {outw[0], outw[1], outw[2], outw[3]};
  *(u32x4*)(o + off) = ov;
}

extern "C" void kernel_launch(void* const* d_in, const int* in_sizes, int n_in,
                              void* d_out, int out_size, void* d_ws, size_t ws_size,
                              hipStream_t stream) {
  const float* x   = (const float*)d_in[0];
  const float* gnw = (const float*)d_in[1];
  const float* gnb = (const float*)d_in[2];
  const float* wq  = (const float*)d_in[3];
  const float* bq  = (const float*)d_in[4];
  const float* wk  = (const float*)d_in[5];
  const float* bk  = (const float*)d_in[6];
  const float* wv  = (const float*)d_in[7];
  const float* bv  = (const float*)d_in[8];
  const float* wp  = (const float*)d_in[9];
  const float* bp  = (const float*)d_in[10];

  const size_t SEQ = 4096, CH = 256;
  const size_t MAT = SEQ * CH;
  char* ws = (char*)d_ws;
  const size_t BUF = 8 * MAT * 2;        // 16 MiB
  ushort* y    = (ushort*)(ws + 0 * BUF);
  ushort* qb   = (ushort*)(ws + 1 * BUF);
  ushort* kb_  = (ushort*)(ws + 2 * BUF);
  ushort* vtb  = (ushort*)(ws + 3 * BUF);
  ushort* pb1  = (ushort*)(ws + 4 * BUF);
  ushort* pb0  = y;                      // y dead after V GEMM
  ushort* oab  = qb;                     // q dead after attn; merge writes here
  ushort* wqb  = (ushort*)(ws + 5 * BUF);
  ushort* wkb  = wqb + 65536;
  ushort* wvb  = wkb + 65536;
  ushort* wpb  = wvb + 65536;
  float* scaleB = (float*)(wpb + 65536);
  float* shiftB = scaleB + 8 * 256;
  float* mlbuf  = (float*)d_out;         // 512KB scratch; overwritten by proj GEMM

  cvt_w_kernel<<<64, 256, 0, stream>>>(wq, wk, wv, wp, wqb, wkb, wvb, wpb);
  gn_stats_kernel<<<64, 256, 0, stream>>>(x, gnw, gnb, scaleB, shiftB);
  gn_apply_kernel<<<2048, 256, 0, stream>>>(x, scaleB, shiftB, y);

  gemm_bt<0><<<dim3(64, 8), 256, 0, stream>>>(y, wqb, MAT, 0, 4096, 256, bq,
                                              nullptr, 0, qb, MAT);
  gemm_bt<0><<<dim3(64, 8), 256, 0, stream>>>(y, wkb, MAT, 0, 4096, 256, bk,
                                              nullptr, 0, kb_, MAT);
  gemm_bt<1><<<dim3(64, 8), 256, 0, stream>>>(wvb, y, 0, MAT, 256, 4096, bv,
                                              nullptr, 0, vtb, MAT);

  attn7_kernel<<<256, 512, 0, stream>>>(qb, kb_, vtb, pb0, pb1, mlbuf);
  attn_merge_kernel<<<4096, 256, 0, stream>>>(pb0, pb1, mlbuf, oab);

  gemm_bt<2><<<dim3(64, 8), 256, 0, stream>>>(wpb, oab, 0, MAT, 256, 4096, bp,
                                              x, MAT, d_out, MAT);
}

// Round 10
// 366.191 us; speedup vs baseline: 1.0759x; 1.0759x over previous
//
#include <hip/hip_runtime.h>

typedef __attribute__((ext_vector_type(8))) short s16x8;
typedef __attribute__((ext_vector_type(4))) float f32x4;
typedef __attribute__((ext_vector_type(16))) float f32x16;
typedef __attribute__((ext_vector_type(4))) uint u32x4;

#define MFMA16(a, b, c) __builtin_amdgcn_mfma_f32_16x16x32_bf16((a), (b), (c), 0, 0, 0)
#define MFMA32(a, b, c) __builtin_amdgcn_mfma_f32_32x32x16_bf16((a), (b), (c), 0, 0, 0)

__device__ __forceinline__ ushort f2bf(float f) {
  uint u = __builtin_bit_cast(uint, f);
  u = (u + 0x7fffu + ((u >> 16) & 1u)) >> 16;
  return (ushort)u;
}

// ---------------- weight fp32 -> bf16 ----------------
__global__ __launch_bounds__(256) void cvt_w_kernel(
    const float* __restrict__ s0, const float* __restrict__ s1,
    const float* __restrict__ s2, const float* __restrict__ s3,
    ushort* __restrict__ d0, ushort* __restrict__ d1,
    ushort* __restrict__ d2, ushort* __restrict__ d3) {
  int i = blockIdx.x * 256 + threadIdx.x;
  const float4* s[4] = {(const float4*)s0, (const float4*)s1, (const float4*)s2, (const float4*)s3};
  ushort* d[4] = {d0, d1, d2, d3};
#pragma unroll
  for (int m = 0; m < 4; ++m) {
    float4 v = s[m][i];
    uint lo = (uint)f2bf(v.x) | ((uint)f2bf(v.y) << 16);
    uint hi = (uint)f2bf(v.z) | ((uint)f2bf(v.w) << 16);
    *(uint2*)(d[m] + (size_t)i * 4) = make_uint2(lo, hi);
  }
}

// ---------------- GroupNorm stats -> per-channel scale/shift ----------------
__global__ __launch_bounds__(256) void gn_stats_kernel(
    const float* __restrict__ x, const float* __restrict__ gw,
    const float* __restrict__ gb, float* __restrict__ scaleB,
    float* __restrict__ shiftB) {
  int b = blockIdx.x >> 3, g = blockIdx.x & 7;
  const float4* src = (const float4*)(x + ((size_t)b * 256 + g * 32) * 4096);
  float s = 0.f, ss = 0.f;
  for (int i = threadIdx.x; i < 32768; i += 256) {
    float4 v = src[i];
    s += v.x + v.y + v.z + v.w;
    ss += v.x * v.x + v.y * v.y + v.z * v.z + v.w * v.w;
  }
#pragma unroll
  for (int off = 32; off; off >>= 1) {
    s += __shfl_down(s, off);
    ss += __shfl_down(ss, off);
  }
  __shared__ float ps[4], pss[4];
  __shared__ float smu, srs;
  int w = threadIdx.x >> 6, lane = threadIdx.x & 63;
  if (lane == 0) { ps[w] = s; pss[w] = ss; }
  __syncthreads();
  if (threadIdx.x == 0) {
    float S = ps[0] + ps[1] + ps[2] + ps[3];
    float SS = pss[0] + pss[1] + pss[2] + pss[3];
    float mu = S * (1.f / 131072.f);
    float var = SS * (1.f / 131072.f) - mu * mu;
    smu = mu;
    srs = rsqrtf(var + 1e-5f);
  }
  __syncthreads();
  if (threadIdx.x < 32) {
    int ch = g * 32 + threadIdx.x;
    float sc = gw[ch] * srs;
    scaleB[b * 256 + ch] = sc;
    shiftB[b * 256 + ch] = gb[ch] - smu * sc;
  }
}

// ---------------- GN apply + transpose: x[b][c][n] -> y[b][n][c] bf16 ----------------
__global__ __launch_bounds__(256) void gn_apply_kernel(
    const float* __restrict__ x, const float* __restrict__ scaleB,
    const float* __restrict__ shiftB, ushort* __restrict__ y) {
  int bid = blockIdx.x;
  int b = bid >> 8;
  int rem = bid & 255;
  int ct = rem >> 6, nt = rem & 63;
  int t = threadIdx.x;
  __shared__ float xs[64][65];
  const float* xb = x + ((size_t)b * 256 + ct * 64) * 4096 + nt * 64;
  {
    int r = t >> 2, q = t & 3;
    const float4* src = (const float4*)(xb + (size_t)r * 4096 + q * 16);
#pragma unroll
    for (int i = 0; i < 4; ++i) {
      float4 v = src[i];
      xs[r][q * 16 + i * 4 + 0] = v.x;
      xs[r][q * 16 + i * 4 + 1] = v.y;
      xs[r][q * 16 + i * 4 + 2] = v.z;
      xs[r][q * 16 + i * 4 + 3] = v.w;
    }
  }
  __syncthreads();
  {
    int nr = t >> 2, q = t & 3;
    int c0 = q * 16;
    ushort tmp[16];
#pragma unroll
    for (int i = 0; i < 16; ++i) {
      int ch = ct * 64 + c0 + i;
      float v = xs[c0 + i][nr] * scaleB[b * 256 + ch] + shiftB[b * 256 + ch];
      tmp[i] = f2bf(v);
    }
    ushort* dst = y + ((size_t)b * 4096 + nt * 64 + nr) * 256 + ct * 64 + c0;
    uint p[8];
#pragma unroll
    for (int j = 0; j < 8; ++j) p[j] = (uint)tmp[2 * j] | ((uint)tmp[2 * j + 1] << 16);
    *(uint4*)dst = make_uint4(p[0], p[1], p[2], p[3]);
    *((uint4*)dst + 1) = make_uint4(p[4], p[5], p[6], p[7]);
  }
}

// ---------------- GEMM: C[M][N] = A[M][256] . B[N][256]^T (+bias, +resid) ----------------
template <int MODE>
__global__ __launch_bounds__(256) void gemm_bt(
    const ushort* __restrict__ A, const ushort* __restrict__ B,
    size_t aB, size_t bB, int M, int N,
    const float* __restrict__ bias, const float* __restrict__ resid,
    size_t rB, void* __restrict__ Cout, size_t cB) {
  int mTiles = M >> 7;
  int tm = blockIdx.x % mTiles, tn = blockIdx.x / mTiles;
  const ushort* Ab = A + blockIdx.y * aB + (size_t)tm * 128 * 256;
  const ushort* Bb = B + blockIdx.y * bB + (size_t)tn * 128 * 256;

  __shared__ ushort As[128 * 72];
  __shared__ ushort Bs[128 * 72];

  int t = threadIdx.x, lane = t & 63, w = t >> 6;
  int wr = w >> 1, wc = w & 1, lq = lane & 15, lg = lane >> 4;

  f32x4 acc[4][4];
#pragma unroll
  for (int i = 0; i < 4; ++i)
#pragma unroll
    for (int j = 0; j < 4; ++j) acc[i][j] = f32x4{0.f, 0.f, 0.f, 0.f};

  int srow = t >> 1, shalf = t & 1;
#pragma unroll 1
  for (int kb = 0; kb < 4; ++kb) {
    __syncthreads();
    {
      const ushort* sa = Ab + (size_t)srow * 256 + kb * 64 + shalf * 32;
      const ushort* sb = Bb + (size_t)srow * 256 + kb * 64 + shalf * 32;
      ushort* da = &As[srow * 72 + shalf * 32];
      ushort* db = &Bs[srow * 72 + shalf * 32];
#pragma unroll
      for (int j = 0; j < 4; ++j) {
        *(uint4*)(da + j * 8) = *(const uint4*)(sa + j * 8);
        *(uint4*)(db + j * 8) = *(const uint4*)(sb + j * 8);
      }
    }
    __syncthreads();
#pragma unroll
    for (int ks = 0; ks < 2; ++ks) {
      s16x8 af[4], bf[4];
#pragma unroll
      for (int mt = 0; mt < 4; ++mt)
        af[mt] = *(const s16x8*)&As[(wr * 64 + mt * 16 + lq) * 72 + ks * 32 + lg * 8];
#pragma unroll
      for (int nt = 0; nt < 4; ++nt)
        bf[nt] = *(const s16x8*)&Bs[(wc * 64 + nt * 16 + lq) * 72 + ks * 32 + lg * 8];
#pragma unroll
      for (int mt = 0; mt < 4; ++mt)
#pragma unroll
        for (int nt = 0; nt < 4; ++nt)
          acc[mt][nt] = MFMA16(af[mt], bf[nt], acc[mt][nt]);
    }
  }

  int mBase = tm * 128 + wr * 64;
  int nBase = tn * 128 + wc * 64;
#pragma unroll
  for (int mt = 0; mt < 4; ++mt) {
#pragma unroll
    for (int nt = 0; nt < 4; ++nt) {
#pragma unroll
      for (int r = 0; r < 4; ++r) {
        int row = mBase + mt * 16 + lg * 4 + r;
        int col = nBase + nt * 16 + lq;
        size_t idx = (size_t)row * N + col;
        float v = acc[mt][nt][r];
        if (MODE == 0) v += bias[col];
        else v += bias[row];
        if (MODE == 2) {
          float* C = (float*)Cout + blockIdx.y * cB;
          C[idx] = v + resid[blockIdx.y * rB + idx];
        } else {
          ushort* C = (ushort*)Cout + blockIdx.y * cB;
          C[idx] = f2bf(v);
        }
      }
    }
  }
}

// ---------------- Flash attention v8: attn3 structure + kv-split -> 2 blocks/CU ----------------
// Grid 512 = 8 batch x 32 qtiles(128 rows) x 2 kv-halves; 256 thr = 4 waves x 32 q-rows.
// LDS 64KB, VGPR ~204 -> TWO independent blocks resident per CU (uncorrelated
// barrier groups fill each other's vmcnt/lgkm stalls).
__global__ __launch_bounds__(256, 1) void attn8_kernel(
    const ushort* __restrict__ q, const ushort* __restrict__ k,
    const ushort* __restrict__ vT, ushort* __restrict__ pb0,
    ushort* __restrict__ pb1, float* __restrict__ mlbuf) {
  const int bb = blockIdx.x & 7;          // batch -> XCD pinning
  const int rem = blockIdx.x >> 3;        // 0..63
  const int qt = rem & 31;                // 32 qtiles x 128 rows
  const int half = rem >> 5;              // kv half
  const int t = threadIdx.x, w = t >> 6, lane = t & 63;
  const int lq = lane & 31, lh = lane >> 5;

  __shared__ ushort Lf[32768];            // 2 bufs x (K 16KB + V 16KB) = 64KB

  const ushort* kb = k + (size_t)bb * (4096 * 256);
  const ushort* vb = vT + (size_t)bb * (4096 * 256);

  // Q fragments (loop-invariant)
  const int qrow = bb * 4096 + qt * 128 + w * 32 + lq;
  s16x8 qf[16];
  {
    const ushort* qp = q + (size_t)qrow * 256 + lh * 8;
#pragma unroll
    for (int ct = 0; ct < 16; ++ct) qf[ct] = *(const s16x8*)(qp + ct * 16);
  }
  f32x16 oacc[8];
#pragma unroll
  for (int i = 0; i < 8; ++i) oacc[i] = (f32x16)(0.f);
  float mrun = -3e38f, lrun = 0.f;

  // stage one 32-row chunk (32KB) into buffer db; 8 gload_lds per thread
  auto stage = [&](int it, int db) {
    const int ci = half * 64 + it;
    const ushort* kcb = kb + (size_t)ci * (32 * 256);
    const ushort* vcb = vb + (size_t)ci * 32;
    ushort* Kd = Lf + db * 16384;
    ushort* Vd = Kd + 8192;
#pragma unroll
    for (int i = 0; i < 4; ++i) {
      int Lu = (w * 4 + i) * 64 + lane;
      // K: LDS(row, c) holds global K(row, c ^ (row&7)); row-major 512B rows
      int row = Lu >> 5, c = Lu & 31;
      const ushort* ksrc = kcb + row * 256 + ((c ^ (row & 7)) << 3);
      __builtin_amdgcn_global_load_lds(
          (const __attribute__((address_space(1))) uint*)ksrc,
          (__attribute__((address_space(3))) uint*)(Kd + (w * 4 + i) * 512), 16, 0, 0);
      // V: row-pair 128B blocks, slot8(row,u) = ((row&1)*4+u) ^ ((row>>1)&7)
      int rp = Lu >> 3, s8 = Lu & 7;
      int x = s8 ^ (rp & 7);
      int vrow = rp * 2 + (x >> 2), uu = x & 3;
      const ushort* vsrc = vcb + (size_t)vrow * 4096 + uu * 8;
      __builtin_amdgcn_global_load_lds(
          (const __attribute__((address_space(1))) uint*)vsrc,
          (__attribute__((address_space(3))) uint*)(Vd + (w * 4 + i) * 512), 16, 0, 0);
    }
  };

  const int rp7 = (lq >> 1) & 7;
  const int b4 = (lq & 1) * 4;

  stage(0, 0);

#pragma unroll 1
  for (int j = 0; j < 64; ++j) {
    if (j < 63) {
      stage(j + 1, (j + 1) & 1);
      asm volatile("s_waitcnt vmcnt(8)" ::: "memory");
    } else {
      asm volatile("s_waitcnt vmcnt(0)" ::: "memory");
    }
    __builtin_amdgcn_s_barrier();

    const ushort* Kbf = Lf + (j & 1) * 16384;
    const ushort* Vbf = Kbf + 8192;

    // ---- QK^T: 16 MFMAs, 2 interleaved accumulator chains ----
    __builtin_amdgcn_s_setprio(1);
    f32x16 s0 = (f32x16)(0.f), s1 = (f32x16)(0.f);
#pragma unroll
    for (int ct = 0; ct < 16; ct += 2) {
      int u0 = (ct * 2 + lh) ^ (lq & 7);
      int u1 = ((ct + 1) * 2 + lh) ^ (lq & 7);
      s16x8 kf0 = *(const s16x8*)(Kbf + lq * 256 + u0 * 8);
      s16x8 kf1 = *(const s16x8*)(Kbf + lq * 256 + u1 * 8);
      s0 = MFMA32(kf0, qf[ct], s0);
      s1 = MFMA32(kf1, qf[ct + 1], s1);
    }
    __builtin_amdgcn_s_setprio(0);
    // ---- in-register online softmax ----
    float sv[16];
#pragma unroll
    for (int r = 0; r < 16; ++r) sv[r] = (s0[r] + s1[r]) * 0.0625f;
    float pmax = sv[0];
#pragma unroll
    for (int r = 1; r < 16; ++r) pmax = fmaxf(pmax, sv[r]);
    pmax = fmaxf(pmax, __shfl_xor(pmax, 32));
    if (!__all(pmax - mrun <= 8.f)) {   // defer-max (T13)
      float mnew = fmaxf(mrun, pmax);
      float alpha = __expf(mrun - mnew);
#pragma unroll
      for (int i = 0; i < 8; ++i) oacc[i] *= alpha;
      lrun *= alpha;
      mrun = mnew;
    }
    float p[16], psum = 0.f;
#pragma unroll
    for (int r = 0; r < 16; ++r) {
      p[r] = __expf(sv[r] - mrun);
      psum += p[r];
    }
    psum += __shfl_xor(psum, 32);
    lrun += psum;
    // ---- P -> PV B-frags (T12) ----
    uint c00, c01, c10, c11, c20, c21, c30, c31;
    asm("v_cvt_pk_bf16_f32 %0, %1, %2" : "=v"(c00) : "v"(p[0]),  "v"(p[1]));
    asm("v_cvt_pk_bf16_f32 %0, %1, %2" : "=v"(c01) : "v"(p[2]),  "v"(p[3]));
    asm("v_cvt_pk_bf16_f32 %0, %1, %2" : "=v"(c10) : "v"(p[4]),  "v"(p[5]));
    asm("v_cvt_pk_bf16_f32 %0, %1, %2" : "=v"(c11) : "v"(p[6]),  "v"(p[7]));
    asm("v_cvt_pk_bf16_f32 %0, %1, %2" : "=v"(c20) : "v"(p[8]),  "v"(p[9]));
    asm("v_cvt_pk_bf16_f32 %0, %1, %2" : "=v"(c21) : "v"(p[10]), "v"(p[11]));
    asm("v_cvt_pk_bf16_f32 %0, %1, %2" : "=v"(c30) : "v"(p[12]), "v"(p[13]));
    asm("v_cvt_pk_bf16_f32 %0, %1, %2" : "=v"(c31) : "v"(p[14]), "v"(p[15]));
    asm("v_permlane32_swap_b32 %0, %1" : "+v"(c00), "+v"(c10));
    asm("v_permlane32_swap_b32 %0, %1" : "+v"(c01), "+v"(c11));
    asm("v_permlane32_swap_b32 %0, %1" : "+v"(c20), "+v"(c30));
    asm("v_permlane32_swap_b32 %0, %1" : "+v"(c21), "+v"(c31));
    u32x4 t0 = {c00, c01, c10, c11};
    u32x4 t1 = {c20, c21, c30, c31};
    s16x8 pf0 = __builtin_bit_cast(s16x8, t0);
    s16x8 pf1 = __builtin_bit_cast(s16x8, t1);
    // ---- PV: A-frags from swizzled V LDS ----
    __builtin_amdgcn_s_setprio(1);
#pragma unroll
    for (int db = 0; db < 8; ++db) {
      const ushort* base = Vbf + (db * 16 + (lq >> 1)) * 64;
      int sl0 = (b4 + lh) ^ rp7;
      int sl1 = (b4 + 2 + lh) ^ rp7;
      s16x8 vf0 = *(const s16x8*)(base + sl0 * 8);
      s16x8 vf1 = *(const s16x8*)(base + sl1 * 8);
      oacc[db] = MFMA32(vf0, pf0, oacc[db]);
      oacc[db] = MFMA32(vf1, pf1, oacc[db]);
    }
    __builtin_amdgcn_s_setprio(0);
    asm volatile("" ::: "memory");
    __builtin_amdgcn_s_barrier();
    asm volatile("" ::: "memory");
  }

  // ---- epilogue: raw partials -> LDS transpose (XOR-swz) -> coalesced store ----
  {
    uint* wregu = (uint*)Lf + w * 4096;   // 32 q-rows x 128 uints per wave
#pragma unroll
    for (int db = 0; db < 8; ++db)
#pragma unroll
      for (int rp = 0; rp < 8; ++rp) {
        int r0 = rp * 2;
        int d0 = db * 32 + (r0 & 3) + 8 * (r0 >> 2) + 4 * lh;
        uint pk;
        asm("v_cvt_pk_bf16_f32 %0, %1, %2"
            : "=v"(pk) : "v"(oacc[db][r0]), "v"(oacc[db][r0 + 1]));
        int idx = lq * 128 + (d0 >> 1);
        wregu[idx ^ ((lq & 7) << 2)] = pk;
      }
    if (lh == 0) {
      int idx = half * 32768 + bb * 4096 + qt * 128 + w * 32 + lq;
      mlbuf[idx] = mrun;
      mlbuf[65536 + idx] = lrun;
    }
  }
  __syncthreads();
  {
    int r = t >> 1;                        // 0..127 row in tile
    int wv2 = r >> 5, lqr = r & 31;
    const uint* basep = (const uint*)Lf + wv2 * 4096;
    ushort* pbase = half ? pb1 : pb0;
    ushort* dstr = pbase + ((size_t)bb * 4096 + qt * 128 + r) * 256 + (t & 1) * 128;
#pragma unroll
    for (int jj = 0; jj < 16; ++jj) {
      int ui = lqr * 128 + (t & 1) * 64 + jj * 4;
      u32x4 v = *(const u32x4*)(basep + (ui ^ ((lqr & 7) << 2)));
      *(u32x4*)(dstr + jj * 8) = v;
    }
  }
}

// ---------------- merge the two kv-half partials ----------------
__global__ __launch_bounds__(256) void attn_merge_kernel(
    const ushort* __restrict__ pb0, const ushort* __restrict__ pb1,
    const float* __restrict__ mlbuf, ushort* __restrict__ o) {
  int gr = blockIdx.x * 8 + (threadIdx.x >> 5);   // global row 0..32767
  int dq = threadIdx.x & 31;                      // 8 d-elems each
  float m0 = mlbuf[gr], m1 = mlbuf[32768 + gr];
  float l0 = mlbuf[65536 + gr], l1 = mlbuf[65536 + 32768 + gr];
  float M = fmaxf(m0, m1);
  float e0 = __expf(m0 - M), e1 = __expf(m1 - M);
  float inv = 1.f / (l0 * e0 + l1 * e1);
  float w0 = e0 * inv, w1 = e1 * inv;
  const size_t off = (size_t)gr * 256 + dq * 8;
  u32x4 a = *(const u32x4*)(pb0 + off);
  u32x4 b = *(const u32x4*)(pb1 + off);
  uint outw[4];
#pragma unroll
  for (int i = 0; i < 4; ++i) {
    float alo = __builtin_bit_cast(float, a[i] << 16);
    float ahi = __builtin_bit_cast(float, a[i] & 0xffff0000u);
    float blo = __builtin_bit_cast(float, b[i] << 16);
    float bhi = __builtin_bit_cast(float, b[i] & 0xffff0000u);
    float flo = alo * w0 + blo * w1;
    float fhi = ahi * w0 + bhi * w1;
    asm("v_cvt_pk_bf16_f32 %0, %1, %2" : "=v"(outw[i]) : "v"(flo), "v"(fhi));
  }
  u32x4 ov = {outw[0], outw[1], outw[2], outw[3]};
  *(u32x4*)(o + off) = ov;
}

extern "C" void kernel_launch(void* const* d_in, const int* in_sizes, int n_in,
                              void* d_out, int out_size, void* d_ws, size_t ws_size,
                              hipStream_t stream) {
  const float* x   = (const float*)d_in[0];
  const float* gnw = (const float*)d_in[1];
  const float* gnb = (const float*)d_in[2];
  const float* wq  = (const float*)d_in[3];
  const float* bq  = (const float*)d_in[4];
  const float* wk  = (const float*)d_in[5];
  const float* bk  = (const float*)d_in[6];
  const float* wv  = (const float*)d_in[7];
  const float* bv  = (const float*)d_in[8];
  const float* wp  = (const float*)d_in[9];
  const float* bp  = (const float*)d_in[10];

  const size_t SEQ = 4096, CH = 256;
  const size_t MAT = SEQ * CH;
  char* ws = (char*)d_ws;
  const size_t BUF = 8 * MAT * 2;        // 16 MiB
  ushort* y    = (ushort*)(ws + 0 * BUF);
  ushort* qb   = (ushort*)(ws + 1 * BUF);
  ushort* kb_  = (ushort*)(ws + 2 * BUF);
  ushort* vtb  = (ushort*)(ws + 3 * BUF);
  ushort* pb1  = (ushort*)(ws + 4 * BUF);
  ushort* pb0  = y;                      // y dead after V GEMM
  ushort* oab  = qb;                     // q dead after attn; merge writes here
  ushort* wqb  = (ushort*)(ws + 5 * BUF);
  ushort* wkb  = wqb + 65536;
  ushort* wvb  = wkb + 65536;
  ushort* wpb  = wvb + 65536;
  float* scaleB = (float*)(wpb + 65536);
  float* shiftB = scaleB + 8 * 256;
  float* mlbuf  = (float*)d_out;         // 512KB scratch; overwritten by proj GEMM

  cvt_w_kernel<<<64, 256, 0, stream>>>(wq, wk, wv, wp, wqb, wkb, wvb, wpb);
  gn_stats_kernel<<<64, 256, 0, stream>>>(x, gnw, gnb, scaleB, shiftB);
  gn_apply_kernel<<<2048, 256, 0, stream>>>(x, scaleB, shiftB, y);

  gemm_bt<0><<<dim3(64, 8), 256, 0, stream>>>(y, wqb, MAT, 0, 4096, 256, bq,
                                              nullptr, 0, qb, MAT);
  gemm_bt<0><<<dim3(64, 8), 256, 0, stream>>>(y, wkb, MAT, 0, 4096, 256, bk,
                                              nullptr, 0, kb_, MAT);
  gemm_bt<1><<<dim3(64, 8), 256, 0, stream>>>(wvb, y, 0, MAT, 256, 4096, bv,
                                              nullptr, 0, vtb, MAT);

  attn8_kernel<<<512, 256, 0, stream>>>(qb, kb_, vtb, pb0, pb1, mlbuf);
  attn_merge_kernel<<<4096, 256, 0, stream>>>(pb0, pb1, mlbuf, oab);

  gemm_bt<2><<<dim3(64, 8), 256, 0, stream>>>(wpb, oab, 0, MAT, 256, 4096, bp,
                                              x, MAT, d_out, MAT);
}

// Round 11
// 346.068 us; speedup vs baseline: 1.1384x; 1.0581x over previous
//
#include <hip/hip_runtime.h>

typedef __attribute__((ext_vector_type(8))) short s16x8;
typedef __attribute__((ext_vector_type(4))) float f32x4;
typedef __attribute__((ext_vector_type(16))) float f32x16;
typedef __attribute__((ext_vector_type(4))) uint u32x4;

#define MFMA16(a, b, c) __builtin_amdgcn_mfma_f32_16x16x32_bf16((a), (b), (c), 0, 0, 0)
#define MFMA32(a, b, c) __builtin_amdgcn_mfma_f32_32x32x16_bf16((a), (b), (c), 0, 0, 0)

__device__ __forceinline__ ushort f2bf(float f) {
  uint u = __builtin_bit_cast(uint, f);
  u = (u + 0x7fffu + ((u >> 16) & 1u)) >> 16;
  return (ushort)u;
}

// ---------------- weight fp32 -> bf16 ----------------
__global__ __launch_bounds__(256) void cvt_w_kernel(
    const float* __restrict__ s0, const float* __restrict__ s1,
    const float* __restrict__ s2, const float* __restrict__ s3,
    ushort* __restrict__ d0, ushort* __restrict__ d1,
    ushort* __restrict__ d2, ushort* __restrict__ d3) {
  int i = blockIdx.x * 256 + threadIdx.x;
  const float4* s[4] = {(const float4*)s0, (const float4*)s1, (const float4*)s2, (const float4*)s3};
  ushort* d[4] = {d0, d1, d2, d3};
#pragma unroll
  for (int m = 0; m < 4; ++m) {
    float4 v = s[m][i];
    uint lo = (uint)f2bf(v.x) | ((uint)f2bf(v.y) << 16);
    uint hi = (uint)f2bf(v.z) | ((uint)f2bf(v.w) << 16);
    *(uint2*)(d[m] + (size_t)i * 4) = make_uint2(lo, hi);
  }
}

// ---------------- GroupNorm stats -> per-channel scale/shift ----------------
__global__ __launch_bounds__(256) void gn_stats_kernel(
    const float* __restrict__ x, const float* __restrict__ gw,
    const float* __restrict__ gb, float* __restrict__ scaleB,
    float* __restrict__ shiftB) {
  int b = blockIdx.x >> 3, g = blockIdx.x & 7;
  const float4* src = (const float4*)(x + ((size_t)b * 256 + g * 32) * 4096);
  float s = 0.f, ss = 0.f;
  for (int i = threadIdx.x; i < 32768; i += 256) {
    float4 v = src[i];
    s += v.x + v.y + v.z + v.w;
    ss += v.x * v.x + v.y * v.y + v.z * v.z + v.w * v.w;
  }
#pragma unroll
  for (int off = 32; off; off >>= 1) {
    s += __shfl_down(s, off);
    ss += __shfl_down(ss, off);
  }
  __shared__ float ps[4], pss[4];
  __shared__ float smu, srs;
  int w = threadIdx.x >> 6, lane = threadIdx.x & 63;
  if (lane == 0) { ps[w] = s; pss[w] = ss; }
  __syncthreads();
  if (threadIdx.x == 0) {
    float S = ps[0] + ps[1] + ps[2] + ps[3];
    float SS = pss[0] + pss[1] + pss[2] + pss[3];
    float mu = S * (1.f / 131072.f);
    float var = SS * (1.f / 131072.f) - mu * mu;
    smu = mu;
    srs = rsqrtf(var + 1e-5f);
  }
  __syncthreads();
  if (threadIdx.x < 32) {
    int ch = g * 32 + threadIdx.x;
    float sc = gw[ch] * srs;
    scaleB[b * 256 + ch] = sc;
    shiftB[b * 256 + ch] = gb[ch] - smu * sc;
  }
}

// ---------------- GN apply + transpose: x[b][c][n] -> y[b][n][c] bf16 ----------------
__global__ __launch_bounds__(256) void gn_apply_kernel(
    const float* __restrict__ x, const float* __restrict__ scaleB,
    const float* __restrict__ shiftB, ushort* __restrict__ y) {
  int bid = blockIdx.x;
  int b = bid >> 8;
  int rem = bid & 255;
  int ct = rem >> 6, nt = rem & 63;
  int t = threadIdx.x;
  __shared__ float xs[64][65];
  const float* xb = x + ((size_t)b * 256 + ct * 64) * 4096 + nt * 64;
  {
    int r = t >> 2, q = t & 3;
    const float4* src = (const float4*)(xb + (size_t)r * 4096 + q * 16);
#pragma unroll
    for (int i = 0; i < 4; ++i) {
      float4 v = src[i];
      xs[r][q * 16 + i * 4 + 0] = v.x;
      xs[r][q * 16 + i * 4 + 1] = v.y;
      xs[r][q * 16 + i * 4 + 2] = v.z;
      xs[r][q * 16 + i * 4 + 3] = v.w;
    }
  }
  __syncthreads();
  {
    int nr = t >> 2, q = t & 3;
    int c0 = q * 16;
    ushort tmp[16];
#pragma unroll
    for (int i = 0; i < 16; ++i) {
      int ch = ct * 64 + c0 + i;
      float v = xs[c0 + i][nr] * scaleB[b * 256 + ch] + shiftB[b * 256 + ch];
      tmp[i] = f2bf(v);
    }
    ushort* dst = y + ((size_t)b * 4096 + nt * 64 + nr) * 256 + ct * 64 + c0;
    uint p[8];
#pragma unroll
    for (int j = 0; j < 8; ++j) p[j] = (uint)tmp[2 * j] | ((uint)tmp[2 * j + 1] << 16);
    *(uint4*)dst = make_uint4(p[0], p[1], p[2], p[3]);
    *((uint4*)dst + 1) = make_uint4(p[4], p[5], p[6], p[7]);
  }
}

// ---------------- GEMM: C[M][N] = A[M][256] . B[N][256]^T (+bias, +resid) ----------------
template <int MODE>
__global__ __launch_bounds__(256) void gemm_bt(
    const ushort* __restrict__ A, const ushort* __restrict__ B,
    size_t aB, size_t bB, int M, int N,
    const float* __restrict__ bias, const float* __restrict__ resid,
    size_t rB, void* __restrict__ Cout, size_t cB) {
  int mTiles = M >> 7;
  int tm = blockIdx.x % mTiles, tn = blockIdx.x / mTiles;
  const ushort* Ab = A + blockIdx.y * aB + (size_t)tm * 128 * 256;
  const ushort* Bb = B + blockIdx.y * bB + (size_t)tn * 128 * 256;

  __shared__ ushort As[128 * 72];
  __shared__ ushort Bs[128 * 72];

  int t = threadIdx.x, lane = t & 63, w = t >> 6;
  int wr = w >> 1, wc = w & 1, lq = lane & 15, lg = lane >> 4;

  f32x4 acc[4][4];
#pragma unroll
  for (int i = 0; i < 4; ++i)
#pragma unroll
    for (int j = 0; j < 4; ++j) acc[i][j] = f32x4{0.f, 0.f, 0.f, 0.f};

  int srow = t >> 1, shalf = t & 1;
#pragma unroll 1
  for (int kb = 0; kb < 4; ++kb) {
    __syncthreads();
    {
      const ushort* sa = Ab + (size_t)srow * 256 + kb * 64 + shalf * 32;
      const ushort* sb = Bb + (size_t)srow * 256 + kb * 64 + shalf * 32;
      ushort* da = &As[srow * 72 + shalf * 32];
      ushort* db = &Bs[srow * 72 + shalf * 32];
#pragma unroll
      for (int j = 0; j < 4; ++j) {
        *(uint4*)(da + j * 8) = *(const uint4*)(sa + j * 8);
        *(uint4*)(db + j * 8) = *(const uint4*)(sb + j * 8);
      }
    }
    __syncthreads();
#pragma unroll
    for (int ks = 0; ks < 2; ++ks) {
      s16x8 af[4], bf[4];
#pragma unroll
      for (int mt = 0; mt < 4; ++mt)
        af[mt] = *(const s16x8*)&As[(wr * 64 + mt * 16 + lq) * 72 + ks * 32 + lg * 8];
#pragma unroll
      for (int nt = 0; nt < 4; ++nt)
        bf[nt] = *(const s16x8*)&Bs[(wc * 64 + nt * 16 + lq) * 72 + ks * 32 + lg * 8];
#pragma unroll
      for (int mt = 0; mt < 4; ++mt)
#pragma unroll
        for (int nt = 0; nt < 4; ++nt)
          acc[mt][nt] = MFMA16(af[mt], bf[nt], acc[mt][nt]);
    }
  }

  int mBase = tm * 128 + wr * 64;
  int nBase = tn * 128 + wc * 64;
#pragma unroll
  for (int mt = 0; mt < 4; ++mt) {
#pragma unroll
    for (int nt = 0; nt < 4; ++nt) {
#pragma unroll
      for (int r = 0; r < 4; ++r) {
        int row = mBase + mt * 16 + lg * 4 + r;
        int col = nBase + nt * 16 + lq;
        size_t idx = (size_t)row * N + col;
        float v = acc[mt][nt][r];
        if (MODE == 0) v += bias[col];
        else v += bias[row];
        if (MODE == 2) {
          float* C = (float*)Cout + blockIdx.y * cB;
          C[idx] = v + resid[blockIdx.y * rB + idx];
        } else {
          ushort* C = (ushort*)Cout + blockIdx.y * cB;
          C[idx] = f2bf(v);
        }
      }
    }
  }
}

// ---------------- Flash attention v9: lean-reg attn8 -> 2 independent blocks/CU ----------------
// Grid 512 = 8 batch x 32 qtiles(128 rows) x 2 kv-halves; 256 thr = 4 waves x 32 q-rows.
// __launch_bounds__(256,2): 2 waves/SIMD -> <=256 total regs/wave, so TWO blocks
// (uncorrelated barrier groups) co-reside and fill each other's stalls.
// Softmax in exp2 domain (v_exp_f32 native); p overwrites sv in place.
__global__ __launch_bounds__(256, 2) void attn9_kernel(
    const ushort* __restrict__ q, const ushort* __restrict__ k,
    const ushort* __restrict__ vT, ushort* __restrict__ pb0,
    ushort* __restrict__ pb1, float* __restrict__ mlbuf) {
  const int bb = blockIdx.x & 7;          // batch -> XCD pinning
  const int rem = blockIdx.x >> 3;        // 0..63
  const int qt = rem & 31;                // 32 qtiles x 128 rows
  const int half = rem >> 5;              // kv half
  const int t = threadIdx.x, w = t >> 6, lane = t & 63;
  const int lq = lane & 31, lh = lane >> 5;

  __shared__ ushort Lf[32768];            // 2 bufs x (K 16KB + V 16KB) = 64KB

  const ushort* kb = k + (size_t)bb * (4096 * 256);
  const ushort* vb = vT + (size_t)bb * (4096 * 256);

  // Q fragments (loop-invariant)
  const int qrow = bb * 4096 + qt * 128 + w * 32 + lq;
  s16x8 qf[16];
  {
    const ushort* qp = q + (size_t)qrow * 256 + lh * 8;
#pragma unroll
    for (int ct = 0; ct < 16; ++ct) qf[ct] = *(const s16x8*)(qp + ct * 16);
  }
  f32x16 oacc[8];
#pragma unroll
  for (int i = 0; i < 8; ++i) oacc[i] = (f32x16)(0.f);
  float mrun = -3e38f, lrun = 0.f;        // mrun in exp2 (log2) domain
  const float cs = 0.0625f * 1.44269504f; // scale * log2(e)

  // stage one 32-row chunk (32KB) into buffer db; 8 gload_lds per thread
  auto stage = [&](int it, int db) {
    const int ci = half * 64 + it;
    const ushort* kcb = kb + (size_t)ci * (32 * 256);
    const ushort* vcb = vb + (size_t)ci * 32;
    ushort* Kd = Lf + db * 16384;
    ushort* Vd = Kd + 8192;
#pragma unroll
    for (int i = 0; i < 4; ++i) {
      int Lu = (w * 4 + i) * 64 + lane;
      // K: LDS(row, c) holds global K(row, c ^ (row&7)); row-major 512B rows
      int row = Lu >> 5, c = Lu & 31;
      const ushort* ksrc = kcb + row * 256 + ((c ^ (row & 7)) << 3);
      __builtin_amdgcn_global_load_lds(
          (const __attribute__((address_space(1))) uint*)ksrc,
          (__attribute__((address_space(3))) uint*)(Kd + (w * 4 + i) * 512), 16, 0, 0);
      // V: row-pair 128B blocks, slot8(row,u) = ((row&1)*4+u) ^ ((row>>1)&7)
      int rp = Lu >> 3, s8 = Lu & 7;
      int x = s8 ^ (rp & 7);
      int vrow = rp * 2 + (x >> 2), uu = x & 3;
      const ushort* vsrc = vcb + (size_t)vrow * 4096 + uu * 8;
      __builtin_amdgcn_global_load_lds(
          (const __attribute__((address_space(1))) uint*)vsrc,
          (__attribute__((address_space(3))) uint*)(Vd + (w * 4 + i) * 512), 16, 0, 0);
    }
  };

  const int rp7 = (lq >> 1) & 7;
  const int b4 = (lq & 1) * 4;

  stage(0, 0);

#pragma unroll 1
  for (int j = 0; j < 64; ++j) {
    if (j < 63) {
      stage(j + 1, (j + 1) & 1);
      asm volatile("s_waitcnt vmcnt(8)" ::: "memory");
    } else {
      asm volatile("s_waitcnt vmcnt(0)" ::: "memory");
    }
    __builtin_amdgcn_s_barrier();

    const ushort* Kbf = Lf + (j & 1) * 16384;
    const ushort* Vbf = Kbf + 8192;

    // ---- QK^T: 16 MFMAs, 2 interleaved accumulator chains ----
    __builtin_amdgcn_s_setprio(1);
    f32x16 s0 = (f32x16)(0.f), s1 = (f32x16)(0.f);
#pragma unroll
    for (int ct = 0; ct < 16; ct += 2) {
      int u0 = (ct * 2 + lh) ^ (lq & 7);
      int u1 = ((ct + 1) * 2 + lh) ^ (lq & 7);
      s16x8 kf0 = *(const s16x8*)(Kbf + lq * 256 + u0 * 8);
      s16x8 kf1 = *(const s16x8*)(Kbf + lq * 256 + u1 * 8);
      s0 = MFMA32(kf0, qf[ct], s0);
      s1 = MFMA32(kf1, qf[ct + 1], s1);
    }
    __builtin_amdgcn_s_setprio(0);
    // ---- in-register online softmax (exp2 domain, p in-place over sv) ----
    float sv[16];
#pragma unroll
    for (int r = 0; r < 16; ++r) sv[r] = (s0[r] + s1[r]) * cs;
    float pmax = sv[0];
#pragma unroll
    for (int r = 1; r < 16; ++r) pmax = fmaxf(pmax, sv[r]);
    pmax = fmaxf(pmax, __shfl_xor(pmax, 32));
    if (!__all(pmax - mrun <= 11.54f)) {  // defer-max (T13), 8*log2e
      float mnew = fmaxf(mrun, pmax);
      float alpha = __builtin_exp2f(mrun - mnew);
#pragma unroll
      for (int i = 0; i < 8; ++i) oacc[i] *= alpha;
      lrun *= alpha;
      mrun = mnew;
    }
    float psum = 0.f;
#pragma unroll
    for (int r = 0; r < 16; ++r) {
      sv[r] = __builtin_exp2f(sv[r] - mrun);
      psum += sv[r];
    }
    psum += __shfl_xor(psum, 32);
    lrun += psum;
    // ---- P -> PV B-frags (T12) ----
    uint c00, c01, c10, c11, c20, c21, c30, c31;
    asm("v_cvt_pk_bf16_f32 %0, %1, %2" : "=v"(c00) : "v"(sv[0]),  "v"(sv[1]));
    asm("v_cvt_pk_bf16_f32 %0, %1, %2" : "=v"(c01) : "v"(sv[2]),  "v"(sv[3]));
    asm("v_cvt_pk_bf16_f32 %0, %1, %2" : "=v"(c10) : "v"(sv[4]),  "v"(sv[5]));
    asm("v_cvt_pk_bf16_f32 %0, %1, %2" : "=v"(c11) : "v"(sv[6]),  "v"(sv[7]));
    asm("v_cvt_pk_bf16_f32 %0, %1, %2" : "=v"(c20) : "v"(sv[8]),  "v"(sv[9]));
    asm("v_cvt_pk_bf16_f32 %0, %1, %2" : "=v"(c21) : "v"(sv[10]), "v"(sv[11]));
    asm("v_cvt_pk_bf16_f32 %0, %1, %2" : "=v"(c30) : "v"(sv[12]), "v"(sv[13]));
    asm("v_cvt_pk_bf16_f32 %0, %1, %2" : "=v"(c31) : "v"(sv[14]), "v"(sv[15]));
    asm("v_permlane32_swap_b32 %0, %1" : "+v"(c00), "+v"(c10));
    asm("v_permlane32_swap_b32 %0, %1" : "+v"(c01), "+v"(c11));
    asm("v_permlane32_swap_b32 %0, %1" : "+v"(c20), "+v"(c30));
    asm("v_permlane32_swap_b32 %0, %1" : "+v"(c21), "+v"(c31));
    u32x4 t0 = {c00, c01, c10, c11};
    u32x4 t1 = {c20, c21, c30, c31};
    s16x8 pf0 = __builtin_bit_cast(s16x8, t0);
    s16x8 pf1 = __builtin_bit_cast(s16x8, t1);
    // ---- PV: A-frags from swizzled V LDS ----
    __builtin_amdgcn_s_setprio(1);
#pragma unroll
    for (int db = 0; db < 8; ++db) {
      const ushort* base = Vbf + (db * 16 + (lq >> 1)) * 64;
      int sl0 = (b4 + lh) ^ rp7;
      int sl1 = (b4 + 2 + lh) ^ rp7;
      s16x8 vf0 = *(const s16x8*)(base + sl0 * 8);
      s16x8 vf1 = *(const s16x8*)(base + sl1 * 8);
      oacc[db] = MFMA32(vf0, pf0, oacc[db]);
      oacc[db] = MFMA32(vf1, pf1, oacc[db]);
    }
    __builtin_amdgcn_s_setprio(0);
    asm volatile("" ::: "memory");
    __builtin_amdgcn_s_barrier();
    asm volatile("" ::: "memory");
  }

  // ---- epilogue: raw partials -> LDS transpose (XOR-swz) -> coalesced store ----
  {
    uint* wregu = (uint*)Lf + w * 4096;   // 32 q-rows x 128 uints per wave
#pragma unroll
    for (int db = 0; db < 8; ++db)
#pragma unroll
      for (int rp = 0; rp < 8; ++rp) {
        int r0 = rp * 2;
        int d0 = db * 32 + (r0 & 3) + 8 * (r0 >> 2) + 4 * lh;
        uint pk;
        asm("v_cvt_pk_bf16_f32 %0, %1, %2"
            : "=v"(pk) : "v"(oacc[db][r0]), "v"(oacc[db][r0 + 1]));
        int idx = lq * 128 + (d0 >> 1);
        wregu[idx ^ ((lq & 7) << 2)] = pk;
      }
    if (lh == 0) {
      int idx = half * 32768 + bb * 4096 + qt * 128 + w * 32 + lq;
      mlbuf[idx] = mrun;                  // exp2-domain max
      mlbuf[65536 + idx] = lrun;
    }
  }
  __syncthreads();
  {
    int r = t >> 1;                        // 0..127 row in tile
    int wv2 = r >> 5, lqr = r & 31;
    const uint* basep = (const uint*)Lf + wv2 * 4096;
    ushort* pbase = half ? pb1 : pb0;
    ushort* dstr = pbase + ((size_t)bb * 4096 + qt * 128 + r) * 256 + (t & 1) * 128;
#pragma unroll
    for (int jj = 0; jj < 16; ++jj) {
      int ui = lqr * 128 + (t & 1) * 64 + jj * 4;
      u32x4 v = *(const u32x4*)(basep + (ui ^ ((lqr & 7) << 2)));
      *(u32x4*)(dstr + jj * 8) = v;
    }
  }
}

// ---------------- merge the two kv-half partials (exp2 domain) ----------------
__global__ __launch_bounds__(256) void attn_merge_kernel(
    const ushort* __restrict__ pb0, const ushort* __restrict__ pb1,
    const float* __restrict__ mlbuf, ushort* __restrict__ o) {
  int gr = blockIdx.x * 8 + (threadIdx.x >> 5);   // global row 0..32767
  int dq = threadIdx.x & 31;                      // 8 d-elems each
  float m0 = mlbuf[gr], m1 = mlbuf[32768 + gr];
  float l0 = mlbuf[65536 + gr], l1 = mlbuf[65536 + 32768 + gr];
  float M = fmaxf(m0, m1);
  float e0 = __builtin_exp2f(m0 - M), e1 = __builtin_exp2f(m1 - M);
  float inv = 1.f / (l0 * e0 + l1 * e1);
  float w0 = e0 * inv, w1 = e1 * inv;
  const size_t off = (size_t)gr * 256 + dq * 8;
  u32x4 a = *(const u32x4*)(pb0 + off);
  u32x4 b = *(const u32x4*)(pb1 + off);
  uint outw[4];
#pragma unroll
  for (int i = 0; i < 4; ++i) {
    float alo = __builtin_bit_cast(float, a[i] << 16);
    float ahi = __builtin_bit_cast(float, a[i] & 0xffff0000u);
    float blo = __builtin_bit_cast(float, b[i] << 16);
    float bhi = __builtin_bit_cast(float, b[i] & 0xffff0000u);
    float flo = alo * w0 + blo * w1;
    float fhi = ahi * w0 + bhi * w1;
    asm("v_cvt_pk_bf16_f32 %0, %1, %2" : "=v"(outw[i]) : "v"(flo), "v"(fhi));
  }
  u32x4 ov = {outw[0], outw[1], outw[2], outw[3]};
  *(u32x4*)(o + off) = ov;
}

extern "C" void kernel_launch(void* const* d_in, const int* in_sizes, int n_in,
                              void* d_out, int out_size, void* d_ws, size_t ws_size,
                              hipStream_t stream) {
  const float* x   = (const float*)d_in[0];
  const float* gnw = (const float*)d_in[1];
  const float* gnb = (const float*)d_in[2];
  const float* wq  = (const float*)d_in[3];
  const float* bq  = (const float*)d_in[4];
  const float* wk  = (const float*)d_in[5];
  const float* bk  = (const float*)d_in[6];
  const float* wv  = (const float*)d_in[7];
  const float* bv  = (const float*)d_in[8];
  const float* wp  = (const float*)d_in[9];
  const float* bp  = (const float*)d_in[10];

  const size_t SEQ = 4096, CH = 256;
  const size_t MAT = SEQ * CH;
  char* ws = (char*)d_ws;
  const size_t BUF = 8 * MAT * 2;        // 16 MiB
  ushort* y    = (ushort*)(ws + 0 * BUF);
  ushort* qb   = (ushort*)(ws + 1 * BUF);
  ushort* kb_  = (ushort*)(ws + 2 * BUF);
  ushort* vtb  = (ushort*)(ws + 3 * BUF);
  ushort* pb1  = (ushort*)(ws + 4 * BUF);
  ushort* pb0  = y;                      // y dead after V GEMM
  ushort* oab  = qb;                     // q dead after attn; merge writes here
  ushort* wqb  = (ushort*)(ws + 5 * BUF);
  ushort* wkb  = wqb + 65536;
  ushort* wvb  = wkb + 65536;
  ushort* wpb  = wvb + 65536;
  float* scaleB = (float*)(wpb + 65536);
  float* shiftB = scaleB + 8 * 256;
  float* mlbuf  = (float*)d_out;         // 512KB scratch; overwritten by proj GEMM

  cvt_w_kernel<<<64, 256, 0, stream>>>(wq, wk, wv, wp, wqb, wkb, wvb, wpb);
  gn_stats_kernel<<<64, 256, 0, stream>>>(x, gnw, gnb, scaleB, shiftB);
  gn_apply_kernel<<<2048, 256, 0, stream>>>(x, scaleB, shiftB, y);

  gemm_bt<0><<<dim3(64, 8), 256, 0, stream>>>(y, wqb, MAT, 0, 4096, 256, bq,
                                              nullptr, 0, qb, MAT);
  gemm_bt<0><<<dim3(64, 8), 256, 0, stream>>>(y, wkb, MAT, 0, 4096, 256, bk,
                                              nullptr, 0, kb_, MAT);
  gemm_bt<1><<<dim3(64, 8), 256, 0, stream>>>(wvb, y, 0, MAT, 256, 4096, bv,
                                              nullptr, 0, vtb, MAT);

  attn9_kernel<<<512, 256, 0, stream>>>(qb, kb_, vtb, pb0, pb1, mlbuf);
  attn_merge_kernel<<<4096, 256, 0, stream>>>(pb0, pb1, mlbuf, oab);

  gemm_bt<2><<<dim3(64, 8), 256, 0, stream>>>(wpb, oab, 0, MAT, 256, 4096, bp,
                                              x, MAT, d_out, MAT);
}

// Round 12
// 240.346 us; speedup vs baseline: 1.6392x; 1.4399x over previous
//
#include <hip/hip_runtime.h>

typedef __attribute__((ext_vector_type(8))) short s16x8;
typedef __attribute__((ext_vector_type(4))) float f32x4;
typedef __attribute__((ext_vector_type(16))) float f32x16;
typedef __attribute__((ext_vector_type(4))) uint u32x4;
typedef __attribute__((ext_vector_type(2))) uint u32x2;
typedef __attribute__((ext_vector_type(2))) long s64x2;
typedef unsigned char u8;

#define MFMA16(a, b, c) __builtin_amdgcn_mfma_f32_16x16x32_bf16((a), (b), (c), 0, 0, 0)
#define MFMAF8(a, b, c) __builtin_amdgcn_mfma_f32_32x32x16_fp8_fp8((a), (b), (c), 0, 0, 0)

__device__ __forceinline__ ushort f2bf(float f) {
  uint u = __builtin_bit_cast(uint, f);
  u = (u + 0x7fffu + ((u >> 16) & 1u)) >> 16;
  return (ushort)u;
}

// ---------------- weight fp32 -> bf16 ----------------
__global__ __launch_bounds__(256) void cvt_w_kernel(
    const float* __restrict__ s0, const float* __restrict__ s1,
    const float* __restrict__ s2, const float* __restrict__ s3,
    ushort* __restrict__ d0, ushort* __restrict__ d1,
    ushort* __restrict__ d2, ushort* __restrict__ d3) {
  int i = blockIdx.x * 256 + threadIdx.x;
  const float4* s[4] = {(const float4*)s0, (const float4*)s1, (const float4*)s2, (const float4*)s3};
  ushort* d[4] = {d0, d1, d2, d3};
#pragma unroll
  for (int m = 0; m < 4; ++m) {
    float4 v = s[m][i];
    uint lo = (uint)f2bf(v.x) | ((uint)f2bf(v.y) << 16);
    uint hi = (uint)f2bf(v.z) | ((uint)f2bf(v.w) << 16);
    *(uint2*)(d[m] + (size_t)i * 4) = make_uint2(lo, hi);
  }
}

// ---------------- GroupNorm stats -> per-channel scale/shift ----------------
__global__ __launch_bounds__(256) void gn_stats_kernel(
    const float* __restrict__ x, const float* __restrict__ gw,
    const float* __restrict__ gb, float* __restrict__ scaleB,
    float* __restrict__ shiftB) {
  int b = blockIdx.x >> 3, g = blockIdx.x & 7;
  const float4* src = (const float4*)(x + ((size_t)b * 256 + g * 32) * 4096);
  float s = 0.f, ss = 0.f;
  for (int i = threadIdx.x; i < 32768; i += 256) {
    float4 v = src[i];
    s += v.x + v.y + v.z + v.w;
    ss += v.x * v.x + v.y * v.y + v.z * v.z + v.w * v.w;
  }
#pragma unroll
  for (int off = 32; off; off >>= 1) {
    s += __shfl_down(s, off);
    ss += __shfl_down(ss, off);
  }
  __shared__ float ps[4], pss[4];
  __shared__ float smu, srs;
  int w = threadIdx.x >> 6, lane = threadIdx.x & 63;
  if (lane == 0) { ps[w] = s; pss[w] = ss; }
  __syncthreads();
  if (threadIdx.x == 0) {
    float S = ps[0] + ps[1] + ps[2] + ps[3];
    float SS = pss[0] + pss[1] + pss[2] + pss[3];
    float mu = S * (1.f / 131072.f);
    float var = SS * (1.f / 131072.f) - mu * mu;
    smu = mu;
    srs = rsqrtf(var + 1e-5f);
  }
  __syncthreads();
  if (threadIdx.x < 32) {
    int ch = g * 32 + threadIdx.x;
    float sc = gw[ch] * srs;
    scaleB[b * 256 + ch] = sc;
    shiftB[b * 256 + ch] = gb[ch] - smu * sc;
  }
}

// ---------------- GN apply + transpose: x[b][c][n] -> y[b][n][c] bf16 ----------------
__global__ __launch_bounds__(256) void gn_apply_kernel(
    const float* __restrict__ x, const float* __restrict__ scaleB,
    const float* __restrict__ shiftB, ushort* __restrict__ y) {
  int bid = blockIdx.x;
  int b = bid >> 8;
  int rem = bid & 255;
  int ct = rem >> 6, nt = rem & 63;
  int t = threadIdx.x;
  __shared__ float xs[64][65];
  const float* xb = x + ((size_t)b * 256 + ct * 64) * 4096 + nt * 64;
  {
    int r = t >> 2, q = t & 3;
    const float4* src = (const float4*)(xb + (size_t)r * 4096 + q * 16);
#pragma unroll
    for (int i = 0; i < 4; ++i) {
      float4 v = src[i];
      xs[r][q * 16 + i * 4 + 0] = v.x;
      xs[r][q * 16 + i * 4 + 1] = v.y;
      xs[r][q * 16 + i * 4 + 2] = v.z;
      xs[r][q * 16 + i * 4 + 3] = v.w;
    }
  }
  __syncthreads();
  {
    int nr = t >> 2, q = t & 3;
    int c0 = q * 16;
    ushort tmp[16];
#pragma unroll
    for (int i = 0; i < 16; ++i) {
      int ch = ct * 64 + c0 + i;
      float v = xs[c0 + i][nr] * scaleB[b * 256 + ch] + shiftB[b * 256 + ch];
      tmp[i] = f2bf(v);
    }
    ushort* dst = y + ((size_t)b * 4096 + nt * 64 + nr) * 256 + ct * 64 + c0;
    uint p[8];
#pragma unroll
    for (int j = 0; j < 8; ++j) p[j] = (uint)tmp[2 * j] | ((uint)tmp[2 * j + 1] << 16);
    *(uint4*)dst = make_uint4(p[0], p[1], p[2], p[3]);
    *((uint4*)dst + 1) = make_uint4(p[4], p[5], p[6], p[7]);
  }
}

// ---------------- GEMM: C[M][N] = A[M][256] . B[N][256]^T (+bias, +resid) ----------------
// MODE 0: bf16 out, bias col. MODE 1: bf16 out, bias row. MODE 2: f32 out, bias row
// + residual. MODE 3: fp8 out, bias col. MODE 4: fp8 out, bias row, kv-perm cols.
template <int MODE>
__global__ __launch_bounds__(256) void gemm_bt(
    const ushort* __restrict__ A, const ushort* __restrict__ B,
    size_t aB, size_t bB, int M, int N,
    const float* __restrict__ bias, const float* __restrict__ resid,
    size_t rB, void* __restrict__ Cout, size_t cB) {
  int mTiles = M >> 7;
  int tm = blockIdx.x % mTiles, tn = blockIdx.x / mTiles;
  const ushort* Ab = A + blockIdx.y * aB + (size_t)tm * 128 * 256;
  const ushort* Bb = B + blockIdx.y * bB + (size_t)tn * 128 * 256;

  __shared__ ushort As[128 * 72];
  __shared__ ushort Bs[128 * 72];

  int t = threadIdx.x, lane = t & 63, w = t >> 6;
  int wr = w >> 1, wc = w & 1, lq = lane & 15, lg = lane >> 4;

  f32x4 acc[4][4];
#pragma unroll
  for (int i = 0; i < 4; ++i)
#pragma unroll
    for (int j = 0; j < 4; ++j) acc[i][j] = f32x4{0.f, 0.f, 0.f, 0.f};

  int srow = t >> 1, shalf = t & 1;
#pragma unroll 1
  for (int kb = 0; kb < 4; ++kb) {
    __syncthreads();
    {
      const ushort* sa = Ab + (size_t)srow * 256 + kb * 64 + shalf * 32;
      const ushort* sb = Bb + (size_t)srow * 256 + kb * 64 + shalf * 32;
      ushort* da = &As[srow * 72 + shalf * 32];
      ushort* db = &Bs[srow * 72 + shalf * 32];
#pragma unroll
      for (int j = 0; j < 4; ++j) {
        *(uint4*)(da + j * 8) = *(const uint4*)(sa + j * 8);
        *(uint4*)(db + j * 8) = *(const uint4*)(sb + j * 8);
      }
    }
    __syncthreads();
#pragma unroll
    for (int ks = 0; ks < 2; ++ks) {
      s16x8 af[4], bf[4];
#pragma unroll
      for (int mt = 0; mt < 4; ++mt)
        af[mt] = *(const s16x8*)&As[(wr * 64 + mt * 16 + lq) * 72 + ks * 32 + lg * 8];
#pragma unroll
      for (int nt = 0; nt < 4; ++nt)
        bf[nt] = *(const s16x8*)&Bs[(wc * 64 + nt * 16 + lq) * 72 + ks * 32 + lg * 8];
#pragma unroll
      for (int mt = 0; mt < 4; ++mt)
#pragma unroll
        for (int nt = 0; nt < 4; ++nt)
          acc[mt][nt] = MFMA16(af[mt], bf[nt], acc[mt][nt]);
    }
  }

  int mBase = tm * 128 + wr * 64;
  int nBase = tn * 128 + wc * 64;
#pragma unroll
  for (int mt = 0; mt < 4; ++mt) {
#pragma unroll
    for (int nt = 0; nt < 4; ++nt) {
#pragma unroll
      for (int r = 0; r < 4; ++r) {
        int row = mBase + mt * 16 + lg * 4 + r;
        int col = nBase + nt * 16 + lq;
        size_t idx = (size_t)row * N + col;
        float v = acc[mt][nt][r];
        if (MODE == 0 || MODE == 3) v += bias[col];
        else v += bias[row];
        if (MODE == 2) {
          float* C = (float*)Cout + blockIdx.y * cB;
          C[idx] = v + resid[blockIdx.y * rB + idx];
        } else if (MODE == 3 || MODE == 4) {
          u8* C = (u8*)Cout + blockIdx.y * cB;
          int c2 = col;
          if (MODE == 4) {
            int rr = col & 31;
            c2 = (col & ~31) | ((rr & 7) | (((rr >> 4) & 1) << 3) | (((rr >> 3) & 1) << 4));
          }
          uint pk8 = (uint)__builtin_amdgcn_cvt_pk_fp8_f32(v, v, 0, false);
          C[(size_t)row * N + c2] = (u8)(pk8 & 0xff);
        } else {
          ushort* C = (ushort*)Cout + blockIdx.y * cB;
          C[idx] = f2bf(v);
        }
      }
    }
  }
}

// ---------------- Flash attention v10: fp8 Q/K/V/P datapath ----------------
// Grid 512 = 8 batch x 32 qtiles(128 rows) x 2 kv-halves; 256 thr = 4 waves.
// mfma_f32_32x32x16_fp8_fp8: one b128 LDS read feeds TWO MFMAs -> 16 reads/iter.
// K swizzle: P = L ^ ((L>>4)&7) (units of 16B); V: P = L ^ ((L>>3)&7); both give
// even 8-quad bank spread on read AND linear DMA dest (source pre-swizzled).
// vT buffer stored with kv-perm [0-7,16-23,8-15,24-31] per 32-block (GEMM MODE 4).
__global__ __launch_bounds__(256, 2) void attn10_kernel(
    const u8* __restrict__ q, const u8* __restrict__ k,
    const u8* __restrict__ vT, ushort* __restrict__ pb0,
    ushort* __restrict__ pb1, float* __restrict__ mlbuf) {
  const int bb = blockIdx.x & 7;          // batch -> XCD pinning
  const int rem = blockIdx.x >> 3;        // 0..63
  const int qt = rem & 31;                // 32 qtiles x 128 rows
  const int half = rem >> 5;              // kv half
  const int t = threadIdx.x, w = t >> 6, lane = t & 63;
  const int lq = lane & 31, lh = lane >> 5;

  __shared__ u8 Lf[65536];   // main loop: 2 bufs x (K 8KB + V 8KB) = 32KB; epilogue 64KB

  const u8* kb = k + (size_t)bb * (4096 * 256);
  const u8* vb = vT + (size_t)bb * (4096 * 256);

  // Q fragments (loop-invariant): 8 x 16B, frag cb feeds MFMAs 2cb, 2cb+1
  const int qrow = bb * 4096 + qt * 128 + w * 32 + lq;
  u32x4 qf[8];
  {
    const u8* qp = q + (size_t)qrow * 256;
#pragma unroll
    for (int cb = 0; cb < 8; ++cb) qf[cb] = *(const u32x4*)(qp + cb * 32 + lh * 16);
  }
  f32x16 oacc[8];
#pragma unroll
  for (int i = 0; i < 8; ++i) oacc[i] = (f32x16)(0.f);
  float mrun = -3e38f, lrun = 0.f;        // exp2 (log2) domain
  const float cs = 0.0625f * 1.44269504f; // scale * log2(e)

  // stage one 32-row chunk (16KB) into buffer db; 4 gload_lds per thread
  auto stage = [&](int it, int db) {
    const int ci = half * 64 + it;
    const u8* kcb = kb + (size_t)ci * (32 * 256);
    const u8* vcb = vb + (size_t)ci * 32;
    u8* base = Lf + db * 16384;
#pragma unroll
    for (int i = 0; i < 2; ++i) {
      int bu = w * 128 + i * 64;          // wave-uniform base unit (16B units)
      int Pu = bu + lane;
      {  // K region: logical L = row*16 + off16; P = L ^ ((L>>4)&7)
        int Lu = Pu ^ ((Pu >> 4) & 7);
        const u8* ksrc = kcb + (Lu >> 4) * 256 + (Lu & 15) * 16;
        __builtin_amdgcn_global_load_lds(
            (const __attribute__((address_space(1))) uint*)ksrc,
            (__attribute__((address_space(3))) uint*)(base + bu * 16), 16, 0, 0);
      }
      {  // V region: logical L = drow*2 + lhv; P = L ^ ((L>>3)&7)
        int Lu = Pu ^ ((Pu >> 3) & 7);
        const u8* vsrc = vcb + (size_t)(Lu >> 1) * 4096 + (Lu & 1) * 16;
        __builtin_amdgcn_global_load_lds(
            (const __attribute__((address_space(1))) uint*)vsrc,
            (__attribute__((address_space(3))) uint*)(base + 8192 + bu * 16), 16, 0, 0);
      }
    }
  };

  stage(0, 0);

#pragma unroll 1
  for (int j = 0; j < 64; ++j) {
    if (j < 63) {
      stage(j + 1, (j + 1) & 1);
      asm volatile("s_waitcnt vmcnt(4)" ::: "memory");
    } else {
      asm volatile("s_waitcnt vmcnt(0)" ::: "memory");
    }
    __builtin_amdgcn_s_barrier();

    const u8* Kbf = Lf + (j & 1) * 16384;
    const u8* Vbf = Kbf + 8192;

    // ---- QK^T: 16 fp8 MFMAs from 8 b128 reads (2 acc chains) ----
    __builtin_amdgcn_s_setprio(1);
    f32x16 s0 = (f32x16)(0.f), s1 = (f32x16)(0.f);
#pragma unroll
    for (int cb = 0; cb < 8; ++cb) {
      int Pu = (lq * 16 + cb * 2 + lh) ^ (lq & 7);
      u32x4 kr = *(const u32x4*)(Kbf + Pu * 16);
      s64x2 kp = __builtin_bit_cast(s64x2, kr);
      s64x2 qp2 = __builtin_bit_cast(s64x2, qf[cb]);
      s0 = MFMAF8(kp[0], qp2[0], s0);
      s1 = MFMAF8(kp[1], qp2[1], s1);
    }
    __builtin_amdgcn_s_setprio(0);
    // ---- in-register online softmax (exp2 domain) ----
    float sv[16];
#pragma unroll
    for (int r = 0; r < 16; ++r) sv[r] = (s0[r] + s1[r]) * cs;
    float pmax = sv[0];
#pragma unroll
    for (int r = 1; r < 16; ++r) pmax = fmaxf(pmax, sv[r]);
    pmax = fmaxf(pmax, __shfl_xor(pmax, 32));
    if (!__all(pmax - mrun <= 11.54f)) {  // defer-max (T13)
      float mnew = fmaxf(mrun, pmax);
      float alpha = __builtin_exp2f(mrun - mnew);
#pragma unroll
      for (int i = 0; i < 8; ++i) oacc[i] *= alpha;
      lrun *= alpha;
      mrun = mnew;
    }
    float psum = 0.f;
#pragma unroll
    for (int r = 0; r < 16; ++r) {
      sv[r] = __builtin_exp2f(sv[r] - mrun);
      psum += sv[r];
    }
    psum += __shfl_xor(psum, 32);
    lrun += psum;
    // ---- P -> fp8 B-frags: 8 cvt_pk_fp8 + 2 permlane32_swap ----
    uint Aw = (uint)__builtin_amdgcn_cvt_pk_fp8_f32(sv[0], sv[1], 0, false);
    Aw = (uint)__builtin_amdgcn_cvt_pk_fp8_f32(sv[2], sv[3], (int)Aw, true);
    uint Bw = (uint)__builtin_amdgcn_cvt_pk_fp8_f32(sv[4], sv[5], 0, false);
    Bw = (uint)__builtin_amdgcn_cvt_pk_fp8_f32(sv[6], sv[7], (int)Bw, true);
    uint Cw = (uint)__builtin_amdgcn_cvt_pk_fp8_f32(sv[8], sv[9], 0, false);
    Cw = (uint)__builtin_amdgcn_cvt_pk_fp8_f32(sv[10], sv[11], (int)Cw, true);
    uint Dw = (uint)__builtin_amdgcn_cvt_pk_fp8_f32(sv[12], sv[13], 0, false);
    Dw = (uint)__builtin_amdgcn_cvt_pk_fp8_f32(sv[14], sv[15], (int)Dw, true);
    asm("v_permlane32_swap_b32 %0, %1" : "+v"(Aw), "+v"(Bw));
    asm("v_permlane32_swap_b32 %0, %1" : "+v"(Cw), "+v"(Dw));
    long pf0 = __builtin_bit_cast(long, (u32x2){Aw, Bw});  // kv slots 0..15
    long pf1 = __builtin_bit_cast(long, (u32x2){Cw, Dw});  // kv slots 16..31
    // ---- PV: one b128 per d-block feeds both MFMAs ----
    __builtin_amdgcn_s_setprio(1);
#pragma unroll
    for (int db = 0; db < 8; ++db) {
      int L = (db * 32 + lq) * 2 + lh;
      int Pu = L ^ ((L >> 3) & 7);
      u32x4 vr = *(const u32x4*)(Vbf + Pu * 16);
      s64x2 vp = __builtin_bit_cast(s64x2, vr);
      oacc[db] = MFMAF8(vp[0], pf0, oacc[db]);
      oacc[db] = MFMAF8(vp[1], pf1, oacc[db]);
    }
    __builtin_amdgcn_s_setprio(0);
    asm volatile("" ::: "memory");
    __builtin_amdgcn_s_barrier();
    asm volatile("" ::: "memory");
  }

  // ---- epilogue: raw partials -> LDS transpose (XOR-swz) -> coalesced store ----
  {
    uint* wregu = (uint*)Lf + w * 4096;   // 32 q-rows x 128 uints per wave
#pragma unroll
    for (int db = 0; db < 8; ++db)
#pragma unroll
      for (int rp = 0; rp < 8; ++rp) {
        int r0 = rp * 2;
        int d0 = db * 32 + (r0 & 3) + 8 * (r0 >> 2) + 4 * lh;
        uint pk;
        asm("v_cvt_pk_bf16_f32 %0, %1, %2"
            : "=v"(pk) : "v"(oacc[db][r0]), "v"(oacc[db][r0 + 1]));
        int idx = lq * 128 + (d0 >> 1);
        wregu[idx ^ ((lq & 7) << 2)] = pk;
      }
    if (lh == 0) {
      int idx = half * 32768 + bb * 4096 + qt * 128 + w * 32 + lq;
      mlbuf[idx] = mrun;                  // exp2-domain max
      mlbuf[65536 + idx] = lrun;
    }
  }
  __syncthreads();
  {
    int r = t >> 1;                        // 0..127 row in tile
    int wv2 = r >> 5, lqr = r & 31;
    const uint* basep = (const uint*)Lf + wv2 * 4096;
    ushort* pbase = half ? pb1 : pb0;
    ushort* dstr = pbase + ((size_t)bb * 4096 + qt * 128 + r) * 256 + (t & 1) * 128;
#pragma unroll
    for (int jj = 0; jj < 16; ++jj) {
      int ui = lqr * 128 + (t & 1) * 64 + jj * 4;
      u32x4 v = *(const u32x4*)(basep + (ui ^ ((lqr & 7) << 2)));
      *(u32x4*)(dstr + jj * 8) = v;
    }
  }
}

// ---------------- merge the two kv-half partials (exp2 domain) ----------------
__global__ __launch_bounds__(256) void attn_merge_kernel(
    const ushort* __restrict__ pb0, const ushort* __restrict__ pb1,
    const float* __restrict__ mlbuf, ushort* __restrict__ o) {
  int gr = blockIdx.x * 8 + (threadIdx.x >> 5);   // global row 0..32767
  int dq = threadIdx.x & 31;                      // 8 d-elems each
  float m0 = mlbuf[gr], m1 = mlbuf[32768 + gr];
  float l0 = mlbuf[65536 + gr], l1 = mlbuf[65536 + 32768 + gr];
  float M = fmaxf(m0, m1);
  float e0 = __builtin_exp2f(m0 - M), e1 = __builtin_exp2f(m1 - M);
  float inv = 1.f / (l0 * e0 + l1 * e1);
  float w0 = e0 * inv, w1 = e1 * inv;
  const size_t off = (size_t)gr * 256 + dq * 8;
  u32x4 a = *(const u32x4*)(pb0 + off);
  u32x4 b = *(const u32x4*)(pb1 + off);
  uint outw[4];
#pragma unroll
  for (int i = 0; i < 4; ++i) {
    float alo = __builtin_bit_cast(float, a[i] << 16);
    float ahi = __builtin_bit_cast(float, a[i] & 0xffff0000u);
    float blo = __builtin_bit_cast(float, b[i] << 16);
    float bhi = __builtin_bit_cast(float, b[i] & 0xffff0000u);
    float flo = alo * w0 + blo * w1;
    float fhi = ahi * w0 + bhi * w1;
    asm("v_cvt_pk_bf16_f32 %0, %1, %2" : "=v"(outw[i]) : "v"(flo), "v"(fhi));
  }
  u32x4 ov = {outw[0], outw[1], outw[2], outw[3]};
  *(u32x4*)(o + off) = ov;
}

extern "C" void kernel_launch(void* const* d_in, const int* in_sizes, int n_in,
                              void* d_out, int out_size, void* d_ws, size_t ws_size,
                              hipStream_t stream) {
  const float* x   = (const float*)d_in[0];
  const float* gnw = (const float*)d_in[1];
  const float* gnb = (const float*)d_in[2];
  const float* wq  = (const float*)d_in[3];
  const float* bq  = (const float*)d_in[4];
  const float* wk  = (const float*)d_in[5];
  const float* bk  = (const float*)d_in[6];
  const float* wv  = (const float*)d_in[7];
  const float* bv  = (const float*)d_in[8];
  const float* wp  = (const float*)d_in[9];
  const float* bp  = (const float*)d_in[10];

  const size_t SEQ = 4096, CH = 256;
  const size_t MAT = SEQ * CH;
  char* ws = (char*)d_ws;
  const size_t BUF = 8 * MAT * 2;        // 16 MiB
  ushort* y    = (ushort*)(ws + 0 * BUF);
  u8*     qb8  = (u8*)(ws + 1 * BUF);    // fp8 q [b][n][c]  (8 MB)
  u8*     kb8  = (u8*)(ws + 2 * BUF);    // fp8 k [b][n][c]
  u8*     vtb8 = (u8*)(ws + 3 * BUF);    // fp8 vT [b][c][n], kv-permuted per 32
  ushort* pb1  = (ushort*)(ws + 4 * BUF);
  ushort* pb0  = y;                      // y dead after V GEMM
  ushort* oab  = (ushort*)(ws + 1 * BUF);// q dead after attn; merge writes here
  ushort* wqb  = (ushort*)(ws + 5 * BUF);
  ushort* wkb  = wqb + 65536;
  ushort* wvb  = wkb + 65536;
  ushort* wpb  = wvb + 65536;
  float* scaleB = (float*)(wpb + 65536);
  float* shiftB = scaleB + 8 * 256;
  float* mlbuf  = (float*)d_out;         // 512KB scratch; overwritten by proj GEMM

  cvt_w_kernel<<<64, 256, 0, stream>>>(wq, wk, wv, wp, wqb, wkb, wvb, wpb);
  gn_stats_kernel<<<64, 256, 0, stream>>>(x, gnw, gnb, scaleB, shiftB);
  gn_apply_kernel<<<2048, 256, 0, stream>>>(x, scaleB, shiftB, y);

  gemm_bt<3><<<dim3(64, 8), 256, 0, stream>>>(y, wqb, MAT, 0, 4096, 256, bq,
                                              nullptr, 0, qb8, MAT);
  gemm_bt<3><<<dim3(64, 8), 256, 0, stream>>>(y, wkb, MAT, 0, 4096, 256, bk,
                                              nullptr, 0, kb8, MAT);
  gemm_bt<4><<<dim3(64, 8), 256, 0, stream>>>(wvb, y, 0, MAT, 256, 4096, bv,
                                              nullptr, 0, vtb8, MAT);

  attn10_kernel<<<512, 256, 0, stream>>>(qb8, kb8, vtb8, pb0, pb1, mlbuf);
  attn_merge_kernel<<<4096, 256, 0, stream>>>(pb0, pb1, mlbuf, oab);

  gemm_bt<2><<<dim3(64, 8), 256, 0, stream>>>(wpb, oab, 0, MAT, 256, 4096, bp,
                                              x, MAT, d_out, MAT);
}

// Round 13
// 238.215 us; speedup vs baseline: 1.6539x; 1.0089x over previous
//
#include <hip/hip_runtime.h>

typedef __attribute__((ext_vector_type(8))) short s16x8;
typedef __attribute__((ext_vector_type(4))) float f32x4;
typedef __attribute__((ext_vector_type(16))) float f32x16;
typedef __attribute__((ext_vector_type(4))) uint u32x4;
typedef __attribute__((ext_vector_type(2))) uint u32x2;
typedef __attribute__((ext_vector_type(2))) long s64x2;
typedef unsigned char u8;

#define MFMA16(a, b, c) __builtin_amdgcn_mfma_f32_16x16x32_bf16((a), (b), (c), 0, 0, 0)
#define MFMAF8(a, b, c) __builtin_amdgcn_mfma_f32_32x32x16_fp8_fp8((a), (b), (c), 0, 0, 0)

__device__ __forceinline__ ushort f2bf(float f) {
  uint u = __builtin_bit_cast(uint, f);
  u = (u + 0x7fffu + ((u >> 16) & 1u)) >> 16;
  return (ushort)u;
}
__device__ __forceinline__ float max3f(float a, float b, float c) {
  return fmaxf(fmaxf(a, b), c);   // clang fuses to v_max3_f32
}

// ---------------- weight fp32 -> bf16 ----------------
__global__ __launch_bounds__(256) void cvt_w_kernel(
    const float* __restrict__ s0, const float* __restrict__ s1,
    const float* __restrict__ s2, const float* __restrict__ s3,
    ushort* __restrict__ d0, ushort* __restrict__ d1,
    ushort* __restrict__ d2, ushort* __restrict__ d3) {
  int i = blockIdx.x * 256 + threadIdx.x;
  const float4* s[4] = {(const float4*)s0, (const float4*)s1, (const float4*)s2, (const float4*)s3};
  ushort* d[4] = {d0, d1, d2, d3};
#pragma unroll
  for (int m = 0; m < 4; ++m) {
    float4 v = s[m][i];
    uint lo = (uint)f2bf(v.x) | ((uint)f2bf(v.y) << 16);
    uint hi = (uint)f2bf(v.z) | ((uint)f2bf(v.w) << 16);
    *(uint2*)(d[m] + (size_t)i * 4) = make_uint2(lo, hi);
  }
}

// ---------------- GroupNorm stats -> per-channel scale/shift ----------------
__global__ __launch_bounds__(256) void gn_stats_kernel(
    const float* __restrict__ x, const float* __restrict__ gw,
    const float* __restrict__ gb, float* __restrict__ scaleB,
    float* __restrict__ shiftB) {
  int b = blockIdx.x >> 3, g = blockIdx.x & 7;
  const float4* src = (const float4*)(x + ((size_t)b * 256 + g * 32) * 4096);
  float s = 0.f, ss = 0.f;
  for (int i = threadIdx.x; i < 32768; i += 256) {
    float4 v = src[i];
    s += v.x + v.y + v.z + v.w;
    ss += v.x * v.x + v.y * v.y + v.z * v.z + v.w * v.w;
  }
#pragma unroll
  for (int off = 32; off; off >>= 1) {
    s += __shfl_down(s, off);
    ss += __shfl_down(ss, off);
  }
  __shared__ float ps[4], pss[4];
  __shared__ float smu, srs;
  int w = threadIdx.x >> 6, lane = threadIdx.x & 63;
  if (lane == 0) { ps[w] = s; pss[w] = ss; }
  __syncthreads();
  if (threadIdx.x == 0) {
    float S = ps[0] + ps[1] + ps[2] + ps[3];
    float SS = pss[0] + pss[1] + pss[2] + pss[3];
    float mu = S * (1.f / 131072.f);
    float var = SS * (1.f / 131072.f) - mu * mu;
    smu = mu;
    srs = rsqrtf(var + 1e-5f);
  }
  __syncthreads();
  if (threadIdx.x < 32) {
    int ch = g * 32 + threadIdx.x;
    float sc = gw[ch] * srs;
    scaleB[b * 256 + ch] = sc;
    shiftB[b * 256 + ch] = gb[ch] - smu * sc;
  }
}

// ---------------- GN apply + transpose: x[b][c][n] -> y[b][n][c] bf16 ----------------
__global__ __launch_bounds__(256) void gn_apply_kernel(
    const float* __restrict__ x, const float* __restrict__ scaleB,
    const float* __restrict__ shiftB, ushort* __restrict__ y) {
  int bid = blockIdx.x;
  int b = bid >> 8;
  int rem = bid & 255;
  int ct = rem >> 6, nt = rem & 63;
  int t = threadIdx.x;
  __shared__ float xs[64][65];
  const float* xb = x + ((size_t)b * 256 + ct * 64) * 4096 + nt * 64;
  {
    int r = t >> 2, q = t & 3;
    const float4* src = (const float4*)(xb + (size_t)r * 4096 + q * 16);
#pragma unroll
    for (int i = 0; i < 4; ++i) {
      float4 v = src[i];
      xs[r][q * 16 + i * 4 + 0] = v.x;
      xs[r][q * 16 + i * 4 + 1] = v.y;
      xs[r][q * 16 + i * 4 + 2] = v.z;
      xs[r][q * 16 + i * 4 + 3] = v.w;
    }
  }
  __syncthreads();
  {
    int nr = t >> 2, q = t & 3;
    int c0 = q * 16;
    ushort tmp[16];
#pragma unroll
    for (int i = 0; i < 16; ++i) {
      int ch = ct * 64 + c0 + i;
      float v = xs[c0 + i][nr] * scaleB[b * 256 + ch] + shiftB[b * 256 + ch];
      tmp[i] = f2bf(v);
    }
    ushort* dst = y + ((size_t)b * 4096 + nt * 64 + nr) * 256 + ct * 64 + c0;
    uint p[8];
#pragma unroll
    for (int j = 0; j < 8; ++j) p[j] = (uint)tmp[2 * j] | ((uint)tmp[2 * j + 1] << 16);
    *(uint4*)dst = make_uint4(p[0], p[1], p[2], p[3]);
    *((uint4*)dst + 1) = make_uint4(p[4], p[5], p[6], p[7]);
  }
}

// ---------------- GEMM: C[M][N] = A[M][256] . B[N][256]^T (+bias, +resid) ----------------
// MODE 0: bf16 out, bias col. MODE 1: bf16 out, bias row. MODE 2: f32 out, bias row
// + residual. MODE 3: fp8 out, bias col. MODE 4: fp8 out, bias row, kv-perm cols.
// MODE 5: fused q|k fp8 out: col<256 -> Cout (bias[col]), col>=256 -> Cout+16MB
//         (resid reused as 2nd bias ptr).
template <int MODE>
__global__ __launch_bounds__(256) void gemm_bt(
    const ushort* __restrict__ A, const ushort* __restrict__ B,
    size_t aB, size_t bB, int M, int N,
    const float* __restrict__ bias, const float* __restrict__ resid,
    size_t rB, void* __restrict__ Cout, size_t cB) {
  int mTiles = M >> 7;
  int tm = blockIdx.x % mTiles, tn = blockIdx.x / mTiles;
  const ushort* Ab = A + blockIdx.y * aB + (size_t)tm * 128 * 256;
  const ushort* Bb = B + blockIdx.y * bB + (size_t)tn * 128 * 256;

  __shared__ ushort As[128 * 72];
  __shared__ ushort Bs[128 * 72];

  int t = threadIdx.x, lane = t & 63, w = t >> 6;
  int wr = w >> 1, wc = w & 1, lq = lane & 15, lg = lane >> 4;

  f32x4 acc[4][4];
#pragma unroll
  for (int i = 0; i < 4; ++i)
#pragma unroll
    for (int j = 0; j < 4; ++j) acc[i][j] = f32x4{0.f, 0.f, 0.f, 0.f};

  int srow = t >> 1, shalf = t & 1;
#pragma unroll 1
  for (int kb = 0; kb < 4; ++kb) {
    __syncthreads();
    {
      const ushort* sa = Ab + (size_t)srow * 256 + kb * 64 + shalf * 32;
      const ushort* sb = Bb + (size_t)srow * 256 + kb * 64 + shalf * 32;
      ushort* da = &As[srow * 72 + shalf * 32];
      ushort* db = &Bs[srow * 72 + shalf * 32];
#pragma unroll
      for (int j = 0; j < 4; ++j) {
        *(uint4*)(da + j * 8) = *(const uint4*)(sa + j * 8);
        *(uint4*)(db + j * 8) = *(const uint4*)(sb + j * 8);
      }
    }
    __syncthreads();
#pragma unroll
    for (int ks = 0; ks < 2; ++ks) {
      s16x8 af[4], bf[4];
#pragma unroll
      for (int mt = 0; mt < 4; ++mt)
        af[mt] = *(const s16x8*)&As[(wr * 64 + mt * 16 + lq) * 72 + ks * 32 + lg * 8];
#pragma unroll
      for (int nt = 0; nt < 4; ++nt)
        bf[nt] = *(const s16x8*)&Bs[(wc * 64 + nt * 16 + lq) * 72 + ks * 32 + lg * 8];
#pragma unroll
      for (int mt = 0; mt < 4; ++mt)
#pragma unroll
        for (int nt = 0; nt < 4; ++nt)
          acc[mt][nt] = MFMA16(af[mt], bf[nt], acc[mt][nt]);
    }
  }

  int mBase = tm * 128 + wr * 64;
  int nBase = tn * 128 + wc * 64;
#pragma unroll
  for (int mt = 0; mt < 4; ++mt) {
#pragma unroll
    for (int nt = 0; nt < 4; ++nt) {
#pragma unroll
      for (int r = 0; r < 4; ++r) {
        int row = mBase + mt * 16 + lg * 4 + r;
        int col = nBase + nt * 16 + lq;
        size_t idx = (size_t)row * N + col;
        float v = acc[mt][nt][r];
        if (MODE == 0 || MODE == 3) v += bias[col];
        else if (MODE == 5) v += (col < 256) ? bias[col] : resid[col - 256];
        else v += bias[row];
        if (MODE == 2) {
          float* C = (float*)Cout + blockIdx.y * cB;
          C[idx] = v + resid[blockIdx.y * rB + idx];
        } else if (MODE == 3 || MODE == 4 || MODE == 5) {
          u8* C = (u8*)Cout + blockIdx.y * cB;
          int c2 = col;
          if (MODE == 4) {
            int rr = col & 31;
            c2 = (col & ~31) | ((rr & 7) | (((rr >> 4) & 1) << 3) | (((rr >> 3) & 1) << 4));
          }
          if (MODE == 5) {
            if (col >= 256) C += 16777216;   // kb8 = qb8 + 16MB
            c2 = col & 255;
          }
          uint pk8 = (uint)__builtin_amdgcn_cvt_pk_fp8_f32(v, v, 0, false);
          C[(size_t)row * ((MODE == 5) ? 256 : N) + c2] = (u8)(pk8 & 0xff);
        } else {
          ushort* C = (ushort*)Cout + blockIdx.y * cB;
          C[idx] = f2bf(v);
        }
      }
    }
  }
}

// ---------------- Flash attention v10b: fp8 datapath, lean softmax ----------------
// Grid 512 = 8 batch x 32 qtiles(128 rows) x 2 kv-halves; 256 thr = 4 waves.
__global__ __launch_bounds__(256, 2) void attn10_kernel(
    const u8* __restrict__ q, const u8* __restrict__ k,
    const u8* __restrict__ vT, ushort* __restrict__ pb0,
    ushort* __restrict__ pb1, float* __restrict__ mlbuf) {
  const int bb = blockIdx.x & 7;          // batch -> XCD pinning
  const int rem = blockIdx.x >> 3;        // 0..63
  const int qt = rem & 31;                // 32 qtiles x 128 rows
  const int half = rem >> 5;              // kv half
  const int t = threadIdx.x, w = t >> 6, lane = t & 63;
  const int lq = lane & 31, lh = lane >> 5;

  __shared__ u8 Lf[65536];   // main loop: 2 bufs x (K 8KB + V 8KB) = 32KB; epilogue 64KB

  const u8* kb = k + (size_t)bb * (4096 * 256);
  const u8* vb = vT + (size_t)bb * (4096 * 256);

  // Q fragments (loop-invariant): 8 x 16B, frag cb feeds MFMAs 2cb, 2cb+1
  const int qrow = bb * 4096 + qt * 128 + w * 32 + lq;
  u32x4 qf[8];
  {
    const u8* qp = q + (size_t)qrow * 256;
#pragma unroll
    for (int cb = 0; cb < 8; ++cb) qf[cb] = *(const u32x4*)(qp + cb * 32 + lh * 16);
  }
  f32x16 oacc[8];
#pragma unroll
  for (int i = 0; i < 8; ++i) oacc[i] = (f32x16)(0.f);
  float mrun = -3e38f, lrun = 0.f;        // exp2 (log2) domain
  const float cs = 0.0625f * 1.44269504f; // scale * log2(e)

  // stage one 32-row chunk (16KB) into buffer db; 4 gload_lds per thread
  auto stage = [&](int it, int db) {
    const int ci = half * 64 + it;
    const u8* kcb = kb + (size_t)ci * (32 * 256);
    const u8* vcb = vb + (size_t)ci * 32;
    u8* base = Lf + db * 16384;
#pragma unroll
    for (int i = 0; i < 2; ++i) {
      int bu = w * 128 + i * 64;          // wave-uniform base unit (16B units)
      int Pu = bu + lane;
      {  // K region: logical L = row*16 + off16; P = L ^ ((L>>4)&7)
        int Lu = Pu ^ ((Pu >> 4) & 7);
        const u8* ksrc = kcb + (Lu >> 4) * 256 + (Lu & 15) * 16;
        __builtin_amdgcn_global_load_lds(
            (const __attribute__((address_space(1))) uint*)ksrc,
            (__attribute__((address_space(3))) uint*)(base + bu * 16), 16, 0, 0);
      }
      {  // V region: logical L = drow*2 + lhv; P = L ^ ((L>>3)&7)
        int Lu = Pu ^ ((Pu >> 3) & 7);
        const u8* vsrc = vcb + (size_t)(Lu >> 1) * 4096 + (Lu & 1) * 16;
        __builtin_amdgcn_global_load_lds(
            (const __attribute__((address_space(1))) uint*)vsrc,
            (__attribute__((address_space(3))) uint*)(base + 8192 + bu * 16), 16, 0, 0);
      }
    }
  };

  stage(0, 0);

#pragma unroll 1
  for (int j = 0; j < 64; ++j) {
    if (j < 63) {
      stage(j + 1, (j + 1) & 1);
      asm volatile("s_waitcnt vmcnt(4)" ::: "memory");
    } else {
      asm volatile("s_waitcnt vmcnt(0)" ::: "memory");
    }
    __builtin_amdgcn_s_barrier();

    const u8* Kbf = Lf + (j & 1) * 16384;
    const u8* Vbf = Kbf + 8192;

    // ---- QK^T: 16 fp8 MFMAs from 8 b128 reads (2 acc chains) ----
    __builtin_amdgcn_s_setprio(1);
    f32x16 s0 = (f32x16)(0.f), s1 = (f32x16)(0.f);
#pragma unroll
    for (int cb = 0; cb < 8; ++cb) {
      int Pu = (lq * 16 + cb * 2 + lh) ^ (lq & 7);
      u32x4 kr = *(const u32x4*)(Kbf + Pu * 16);
      s64x2 kp = __builtin_bit_cast(s64x2, kr);
      s64x2 qp2 = __builtin_bit_cast(s64x2, qf[cb]);
      s0 = MFMAF8(kp[0], qp2[0], s0);
      s1 = MFMAF8(kp[1], qp2[1], s1);
    }
    __builtin_amdgcn_s_setprio(0);
    // ---- lean online softmax: max on raw sums (1 mul), fma+exp2 fused ----
    float tv[16];
#pragma unroll
    for (int r = 0; r < 16; ++r) tv[r] = s0[r] + s1[r];
    float g0 = max3f(tv[0], tv[1], tv[2]);
    float g1 = max3f(tv[3], tv[4], tv[5]);
    float g2 = max3f(tv[6], tv[7], tv[8]);
    float g3 = max3f(tv[9], tv[10], tv[11]);
    float g4 = max3f(tv[12], tv[13], tv[14]);
    float pmax_t = max3f(max3f(g0, g1, tv[15]), fmaxf(g2, g3), g4);
    pmax_t = fmaxf(pmax_t, __shfl_xor(pmax_t, 32));
    float pmax = pmax_t * cs;
    if (!__all(pmax - mrun <= 8.f)) {     // defer-max; 2^8=256 < fp8 max 448
      float mnew = fmaxf(mrun, pmax);
      float alpha = __builtin_exp2f(mrun - mnew);
#pragma unroll
      for (int i = 0; i < 8; ++i) oacc[i] *= alpha;
      lrun *= alpha;
      mrun = mnew;
    }
    float nm = -mrun;
    float sv[16], psum = 0.f;
#pragma unroll
    for (int r = 0; r < 16; ++r) {
      sv[r] = __builtin_exp2f(__builtin_fmaf(tv[r], cs, nm));
      psum += sv[r];
    }
    psum += __shfl_xor(psum, 32);
    lrun += psum;
    // ---- P -> fp8 B-frags: 8 cvt_pk_fp8 + 2 permlane32_swap ----
    uint Aw = (uint)__builtin_amdgcn_cvt_pk_fp8_f32(sv[0], sv[1], 0, false);
    Aw = (uint)__builtin_amdgcn_cvt_pk_fp8_f32(sv[2], sv[3], (int)Aw, true);
    uint Bw = (uint)__builtin_amdgcn_cvt_pk_fp8_f32(sv[4], sv[5], 0, false);
    Bw = (uint)__builtin_amdgcn_cvt_pk_fp8_f32(sv[6], sv[7], (int)Bw, true);
    uint Cw = (uint)__builtin_amdgcn_cvt_pk_fp8_f32(sv[8], sv[9], 0, false);
    Cw = (uint)__builtin_amdgcn_cvt_pk_fp8_f32(sv[10], sv[11], (int)Cw, true);
    uint Dw = (uint)__builtin_amdgcn_cvt_pk_fp8_f32(sv[12], sv[13], 0, false);
    Dw = (uint)__builtin_amdgcn_cvt_pk_fp8_f32(sv[14], sv[15], (int)Dw, true);
    asm("v_permlane32_swap_b32 %0, %1" : "+v"(Aw), "+v"(Bw));
    asm("v_permlane32_swap_b32 %0, %1" : "+v"(Cw), "+v"(Dw));
    long pf0 = __builtin_bit_cast(long, (u32x2){Aw, Bw});  // kv slots 0..15
    long pf1 = __builtin_bit_cast(long, (u32x2){Cw, Dw});  // kv slots 16..31
    // ---- PV: one b128 per d-block feeds both MFMAs ----
    __builtin_amdgcn_s_setprio(1);
#pragma unroll
    for (int db = 0; db < 8; ++db) {
      int L = (db * 32 + lq) * 2 + lh;
      int Pu = L ^ ((L >> 3) & 7);
      u32x4 vr = *(const u32x4*)(Vbf + Pu * 16);
      s64x2 vp = __builtin_bit_cast(s64x2, vr);
      oacc[db] = MFMAF8(vp[0], pf0, oacc[db]);
      oacc[db] = MFMAF8(vp[1], pf1, oacc[db]);
    }
    __builtin_amdgcn_s_setprio(0);
    asm volatile("" ::: "memory");
    __builtin_amdgcn_s_barrier();
    asm volatile("" ::: "memory");
  }

  // ---- epilogue: raw partials -> LDS transpose (XOR-swz) -> coalesced store ----
  {
    uint* wregu = (uint*)Lf + w * 4096;   // 32 q-rows x 128 uints per wave
#pragma unroll
    for (int db = 0; db < 8; ++db)
#pragma unroll
      for (int rp = 0; rp < 8; ++rp) {
        int r0 = rp * 2;
        int d0 = db * 32 + (r0 & 3) + 8 * (r0 >> 2) + 4 * lh;
        uint pk;
        asm("v_cvt_pk_bf16_f32 %0, %1, %2"
            : "=v"(pk) : "v"(oacc[db][r0]), "v"(oacc[db][r0 + 1]));
        int idx = lq * 128 + (d0 >> 1);
        wregu[idx ^ ((lq & 7) << 2)] = pk;
      }
    if (lh == 0) {
      int idx = half * 32768 + bb * 4096 + qt * 128 + w * 32 + lq;
      mlbuf[idx] = mrun;                  // exp2-domain max
      mlbuf[65536 + idx] = lrun;
    }
  }
  __syncthreads();
  {
    int r = t >> 1;                        // 0..127 row in tile
    int wv2 = r >> 5, lqr = r & 31;
    const uint* basep = (const uint*)Lf + wv2 * 4096;
    ushort* pbase = half ? pb1 : pb0;
    ushort* dstr = pbase + ((size_t)bb * 4096 + qt * 128 + r) * 256 + (t & 1) * 128;
#pragma unroll
    for (int jj = 0; jj < 16; ++jj) {
      int ui = lqr * 128 + (t & 1) * 64 + jj * 4;
      u32x4 v = *(const u32x4*)(basep + (ui ^ ((lqr & 7) << 2)));
      *(u32x4*)(dstr + jj * 8) = v;
    }
  }
}

// ---------------- merge the two kv-half partials (exp2 domain) ----------------
__global__ __launch_bounds__(256) void attn_merge_kernel(
    const ushort* __restrict__ pb0, const ushort* __restrict__ pb1,
    const float* __restrict__ mlbuf, ushort* __restrict__ o) {
  int gr = blockIdx.x * 8 + (threadIdx.x >> 5);   // global row 0..32767
  int dq = threadIdx.x & 31;                      // 8 d-elems each
  float m0 = mlbuf[gr], m1 = mlbuf[32768 + gr];
  float l0 = mlbuf[65536 + gr], l1 = mlbuf[65536 + 32768 + gr];
  float M = fmaxf(m0, m1);
  float e0 = __builtin_exp2f(m0 - M), e1 = __builtin_exp2f(m1 - M);
  float inv = 1.f / (l0 * e0 + l1 * e1);
  float w0 = e0 * inv, w1 = e1 * inv;
  const size_t off = (size_t)gr * 256 + dq * 8;
  u32x4 a = *(const u32x4*)(pb0 + off);
  u32x4 b = *(const u32x4*)(pb1 + off);
  uint outw[4];
#pragma unroll
  for (int i = 0; i < 4; ++i) {
    float alo = __builtin_bit_cast(float, a[i] << 16);
    float ahi = __builtin_bit_cast(float, a[i] & 0xffff0000u);
    float blo = __builtin_bit_cast(float, b[i] << 16);
    float bhi = __builtin_bit_cast(float, b[i] & 0xffff0000u);
    float flo = alo * w0 + blo * w1;
    float fhi = ahi * w0 + bhi * w1;
    asm("v_cvt_pk_bf16_f32 %0, %1, %2" : "=v"(outw[i]) : "v"(flo), "v"(fhi));
  }
  u32x4 ov = {outw[0], outw[1], outw[2], outw[3]};
  *(u32x4*)(o + off) = ov;
}

extern "C" void kernel_launch(void* const* d_in, const int* in_sizes, int n_in,
                              void* d_out, int out_size, void* d_ws, size_t ws_size,
                              hipStream_t stream) {
  const float* x   = (const float*)d_in[0];
  const float* gnw = (const float*)d_in[1];
  const float* gnb = (const float*)d_in[2];
  const float* wq  = (const float*)d_in[3];
  const float* bq  = (const float*)d_in[4];
  const float* wk  = (const float*)d_in[5];
  const float* bk  = (const float*)d_in[6];
  const float* wv  = (const float*)d_in[7];
  const float* bv  = (const float*)d_in[8];
  const float* wp  = (const float*)d_in[9];
  const float* bp  = (const float*)d_in[10];

  const size_t SEQ = 4096, CH = 256;
  const size_t MAT = SEQ * CH;
  char* ws = (char*)d_ws;
  const size_t BUF = 8 * MAT * 2;        // 16 MiB
  ushort* y    = (ushort*)(ws + 0 * BUF);
  u8*     qb8  = (u8*)(ws + 1 * BUF);    // fp8 q [b][n][c]  (8 MB)
  u8*     kb8  = (u8*)(ws + 2 * BUF);    // fp8 k [b][n][c]  (= qb8 + 16MB)
  u8*     vtb8 = (u8*)(ws + 3 * BUF);    // fp8 vT [b][c][n], kv-permuted per 32
  ushort* pb1  = (ushort*)(ws + 4 * BUF);
  ushort* pb0  = y;                      // y dead after V GEMM
  ushort* oab  = (ushort*)(ws + 1 * BUF);// q dead after attn; merge writes here
  ushort* wqb  = (ushort*)(ws + 5 * BUF);
  ushort* wkb  = wqb + 65536;            // contiguous with wqb -> fused q|k B
  ushort* wvb  = wkb + 65536;
  ushort* wpb  = wvb + 65536;
  float* scaleB = (float*)(wpb + 65536);
  float* shiftB = scaleB + 8 * 256;
  float* mlbuf  = (float*)d_out;         // 512KB scratch; overwritten by proj GEMM

  cvt_w_kernel<<<64, 256, 0, stream>>>(wq, wk, wv, wp, wqb, wkb, wvb, wpb);
  gn_stats_kernel<<<64, 256, 0, stream>>>(x, gnw, gnb, scaleB, shiftB);
  gn_apply_kernel<<<2048, 256, 0, stream>>>(x, scaleB, shiftB, y);

  // fused q|k GEMM: B = [wq;wk] (512 rows), outputs qb8 / kb8 (+16MB)
  gemm_bt<5><<<dim3(128, 8), 256, 0, stream>>>(y, wqb, MAT, 0, 4096, 512, bq,
                                               bk, 0, qb8, MAT);
  gemm_bt<4><<<dim3(64, 8), 256, 0, stream>>>(wvb, y, 0, MAT, 256, 4096, bv,
                                              nullptr, 0, vtb8, MAT);

  attn10_kernel<<<512, 256, 0, stream>>>(qb8, kb8, vtb8, pb0, pb1, mlbuf);
  attn_merge_kernel<<<4096, 256, 0, stream>>>(pb0, pb1, mlbuf, oab);

  gemm_bt<2><<<dim3(64, 8), 256, 0, stream>>>(wpb, oab, 0, MAT, 256, 4096, bp,
                                              x, MAT, d_out, MAT);
}

// Round 14
// 232.885 us; speedup vs baseline: 1.6917x; 1.0229x over previous
//
#include <hip/hip_runtime.h>

typedef __attribute__((ext_vector_type(8))) short s16x8;
typedef __attribute__((ext_vector_type(4))) float f32x4;
typedef __attribute__((ext_vector_type(16))) float f32x16;
typedef __attribute__((ext_vector_type(4))) uint u32x4;
typedef __attribute__((ext_vector_type(2))) uint u32x2;
typedef __attribute__((ext_vector_type(2))) long s64x2;
typedef unsigned char u8;

#define MFMA16(a, b, c) __builtin_amdgcn_mfma_f32_16x16x32_bf16((a), (b), (c), 0, 0, 0)
#define MFMAF8(a, b, c) __builtin_amdgcn_mfma_f32_32x32x16_fp8_fp8((a), (b), (c), 0, 0, 0)

__device__ __forceinline__ ushort f2bf(float f) {
  uint u = __builtin_bit_cast(uint, f);
  u = (u + 0x7fffu + ((u >> 16) & 1u)) >> 16;
  return (ushort)u;
}
__device__ __forceinline__ float max3f(float a, float b, float c) {
  return fmaxf(fmaxf(a, b), c);   // clang fuses to v_max3_f32
}

// ---------------- weight fp32 -> bf16 ----------------
__global__ __launch_bounds__(256) void cvt_w_kernel(
    const float* __restrict__ s0, const float* __restrict__ s1,
    const float* __restrict__ s2, const float* __restrict__ s3,
    ushort* __restrict__ d0, ushort* __restrict__ d1,
    ushort* __restrict__ d2, ushort* __restrict__ d3) {
  int i = blockIdx.x * 256 + threadIdx.x;
  const float4* s[4] = {(const float4*)s0, (const float4*)s1, (const float4*)s2, (const float4*)s3};
  ushort* d[4] = {d0, d1, d2, d3};
#pragma unroll
  for (int m = 0; m < 4; ++m) {
    float4 v = s[m][i];
    uint lo = (uint)f2bf(v.x) | ((uint)f2bf(v.y) << 16);
    uint hi = (uint)f2bf(v.z) | ((uint)f2bf(v.w) << 16);
    *(uint2*)(d[m] + (size_t)i * 4) = make_uint2(lo, hi);
  }
}

// ---------------- GroupNorm stats -> per-channel scale/shift ----------------
__global__ __launch_bounds__(256) void gn_stats_kernel(
    const float* __restrict__ x, const float* __restrict__ gw,
    const float* __restrict__ gb, float* __restrict__ scaleB,
    float* __restrict__ shiftB) {
  int b = blockIdx.x >> 3, g = blockIdx.x & 7;
  const float4* src = (const float4*)(x + ((size_t)b * 256 + g * 32) * 4096);
  float s = 0.f, ss = 0.f;
  for (int i = threadIdx.x; i < 32768; i += 256) {
    float4 v = src[i];
    s += v.x + v.y + v.z + v.w;
    ss += v.x * v.x + v.y * v.y + v.z * v.z + v.w * v.w;
  }
#pragma unroll
  for (int off = 32; off; off >>= 1) {
    s += __shfl_down(s, off);
    ss += __shfl_down(ss, off);
  }
  __shared__ float ps[4], pss[4];
  __shared__ float smu, srs;
  int w = threadIdx.x >> 6, lane = threadIdx.x & 63;
  if (lane == 0) { ps[w] = s; pss[w] = ss; }
  __syncthreads();
  if (threadIdx.x == 0) {
    float S = ps[0] + ps[1] + ps[2] + ps[3];
    float SS = pss[0] + pss[1] + pss[2] + pss[3];
    float mu = S * (1.f / 131072.f);
    float var = SS * (1.f / 131072.f) - mu * mu;
    smu = mu;
    srs = rsqrtf(var + 1e-5f);
  }
  __syncthreads();
  if (threadIdx.x < 32) {
    int ch = g * 32 + threadIdx.x;
    float sc = gw[ch] * srs;
    scaleB[b * 256 + ch] = sc;
    shiftB[b * 256 + ch] = gb[ch] - smu * sc;
  }
}

// ---------------- GN apply + transpose: x[b][c][n] -> y[b][n][c] bf16 ----------------
__global__ __launch_bounds__(256) void gn_apply_kernel(
    const float* __restrict__ x, const float* __restrict__ scaleB,
    const float* __restrict__ shiftB, ushort* __restrict__ y) {
  int bid = blockIdx.x;
  int b = bid >> 8;
  int rem = bid & 255;
  int ct = rem >> 6, nt = rem & 63;
  int t = threadIdx.x;
  __shared__ float xs[64][65];
  const float* xb = x + ((size_t)b * 256 + ct * 64) * 4096 + nt * 64;
  {
    int r = t >> 2, q = t & 3;
    const float4* src = (const float4*)(xb + (size_t)r * 4096 + q * 16);
#pragma unroll
    for (int i = 0; i < 4; ++i) {
      float4 v = src[i];
      xs[r][q * 16 + i * 4 + 0] = v.x;
      xs[r][q * 16 + i * 4 + 1] = v.y;
      xs[r][q * 16 + i * 4 + 2] = v.z;
      xs[r][q * 16 + i * 4 + 3] = v.w;
    }
  }
  __syncthreads();
  {
    int nr = t >> 2, q = t & 3;
    int c0 = q * 16;
    ushort tmp[16];
#pragma unroll
    for (int i = 0; i < 16; ++i) {
      int ch = ct * 64 + c0 + i;
      float v = xs[c0 + i][nr] * scaleB[b * 256 + ch] + shiftB[b * 256 + ch];
      tmp[i] = f2bf(v);
    }
    ushort* dst = y + ((size_t)b * 4096 + nt * 64 + nr) * 256 + ct * 64 + c0;
    uint p[8];
#pragma unroll
    for (int j = 0; j < 8; ++j) p[j] = (uint)tmp[2 * j] | ((uint)tmp[2 * j + 1] << 16);
    *(uint4*)dst = make_uint4(p[0], p[1], p[2], p[3]);
    *((uint4*)dst + 1) = make_uint4(p[4], p[5], p[6], p[7]);
  }
}

// ---------------- GEMM: C[M][N] = A[M][256] . B[N][256]^T (+bias, +resid) ----------------
// v2 staging: global_load_lds w=16, linear [128][64] LDS tiles, XOR-swizzled
// source+reads (rule #21), double-buffered with counted vmcnt(8).
// MODE 0: bf16 out, bias col. MODE 1: bf16 out, bias row. MODE 2: f32 out, bias row
// + residual. MODE 3: fp8 out, bias col. MODE 4: fp8 out, bias row, kv-perm cols.
// MODE 5: fused q|k fp8 out: col<256 -> Cout (bias[col]), col>=256 -> Cout+16MB.
template <int MODE>
__global__ __launch_bounds__(256) void gemm_bt(
    const ushort* __restrict__ A, const ushort* __restrict__ B,
    size_t aB, size_t bB, int M, int N,
    const float* __restrict__ bias, const float* __restrict__ resid,
    size_t rB, void* __restrict__ Cout, size_t cB) {
  int mTiles = M >> 7;
  int tm = blockIdx.x % mTiles, tn = blockIdx.x / mTiles;
  const ushort* Ab = A + blockIdx.y * aB + (size_t)tm * 128 * 256;
  const ushort* Bb = B + blockIdx.y * bB + (size_t)tn * 128 * 256;

  __shared__ ushort As[2][8192];   // [128][64] linear, XOR-swizzled contents
  __shared__ ushort Bs[2][8192];

  int t = threadIdx.x, lane = t & 63, w = t >> 6;
  int wr = w >> 1, wc = w & 1, lq = lane & 15, lg = lane >> 4;

  f32x4 acc[4][4];
#pragma unroll
  for (int i = 0; i < 4; ++i)
#pragma unroll
    for (int j = 0; j < 4; ++j) acc[i][j] = f32x4{0.f, 0.f, 0.f, 0.f};

  // stage 128x64 A- and B-subtiles for K-step kb into buffer db (DMA, 8 loads/thr)
  auto stageT = [&](int kb, int db) {
#pragma unroll
    for (int i = 0; i < 4; ++i) {
      int bu = i * 256 + w * 64;          // wave-uniform base unit (16B units)
      int u = bu + lane;
      int row = u >> 3, c = u & 7;
      int cl = c ^ (row & 7);             // pre-swizzled logical column unit
      const ushort* sa = Ab + (size_t)row * 256 + kb * 64 + cl * 8;
      __builtin_amdgcn_global_load_lds(
          (const __attribute__((address_space(1))) uint*)sa,
          (__attribute__((address_space(3))) uint*)(&As[db][0] + bu * 8), 16, 0, 0);
      const ushort* sb = Bb + (size_t)row * 256 + kb * 64 + cl * 8;
      __builtin_amdgcn_global_load_lds(
          (const __attribute__((address_space(1))) uint*)sb,
          (__attribute__((address_space(3))) uint*)(&Bs[db][0] + bu * 8), 16, 0, 0);
    }
  };

  stageT(0, 0);

#pragma unroll 1
  for (int kb = 0; kb < 4; ++kb) {
    if (kb < 3) {
      stageT(kb + 1, (kb + 1) & 1);
      asm volatile("s_waitcnt vmcnt(8)" ::: "memory");
    } else {
      asm volatile("s_waitcnt vmcnt(0)" ::: "memory");
    }
    __builtin_amdgcn_s_barrier();
    const ushort* Abf = &As[kb & 1][0];
    const ushort* Bbf = &Bs[kb & 1][0];
#pragma unroll
    for (int ks = 0; ks < 2; ++ks) {
      s16x8 af[4], bf[4];
#pragma unroll
      for (int mt = 0; mt < 4; ++mt) {
        int row = wr * 64 + mt * 16 + lq;
        af[mt] = *(const s16x8*)&Abf[row * 64 + (((ks * 4 + lg) ^ (row & 7)) << 3)];
      }
#pragma unroll
      for (int nt = 0; nt < 4; ++nt) {
        int row = wc * 64 + nt * 16 + lq;
        bf[nt] = *(const s16x8*)&Bbf[row * 64 + (((ks * 4 + lg) ^ (row & 7)) << 3)];
      }
#pragma unroll
      for (int mt = 0; mt < 4; ++mt)
#pragma unroll
        for (int nt = 0; nt < 4; ++nt)
          acc[mt][nt] = MFMA16(af[mt], bf[nt], acc[mt][nt]);
    }
    asm volatile("" ::: "memory");
    __builtin_amdgcn_s_barrier();
    asm volatile("" ::: "memory");
  }

  int mBase = tm * 128 + wr * 64;
  int nBase = tn * 128 + wc * 64;
#pragma unroll
  for (int mt = 0; mt < 4; ++mt) {
#pragma unroll
    for (int nt = 0; nt < 4; ++nt) {
#pragma unroll
      for (int r = 0; r < 4; ++r) {
        int row = mBase + mt * 16 + lg * 4 + r;
        int col = nBase + nt * 16 + lq;
        size_t idx = (size_t)row * N + col;
        float v = acc[mt][nt][r];
        if (MODE == 0 || MODE == 3) v += bias[col];
        else if (MODE == 5) v += (col < 256) ? bias[col] : resid[col - 256];
        else v += bias[row];
        if (MODE == 2) {
          float* C = (float*)Cout + blockIdx.y * cB;
          C[idx] = v + resid[blockIdx.y * rB + idx];
        } else if (MODE == 3 || MODE == 4 || MODE == 5) {
          u8* C = (u8*)Cout + blockIdx.y * cB;
          int c2 = col;
          if (MODE == 4) {
            int rr = col & 31;
            c2 = (col & ~31) | ((rr & 7) | (((rr >> 4) & 1) << 3) | (((rr >> 3) & 1) << 4));
          }
          if (MODE == 5) {
            if (col >= 256) C += 16777216;   // kb8 = qb8 + 16MB
            c2 = col & 255;
          }
          uint pk8 = (uint)__builtin_amdgcn_cvt_pk_fp8_f32(v, v, 0, false);
          C[(size_t)row * ((MODE == 5) ? 256 : N) + c2] = (u8)(pk8 & 0xff);
        } else {
          ushort* C = (ushort*)Cout + blockIdx.y * cB;
          C[idx] = f2bf(v);
        }
      }
    }
  }
}

// ---------------- Flash attention v10b: fp8 datapath, lean softmax ----------------
// Grid 512 = 8 batch x 32 qtiles(128 rows) x 2 kv-halves; 256 thr = 4 waves.
__global__ __launch_bounds__(256, 2) void attn10_kernel(
    const u8* __restrict__ q, const u8* __restrict__ k,
    const u8* __restrict__ vT, ushort* __restrict__ pb0,
    ushort* __restrict__ pb1, float* __restrict__ mlbuf) {
  const int bb = blockIdx.x & 7;          // batch -> XCD pinning
  const int rem = blockIdx.x >> 3;        // 0..63
  const int qt = rem & 31;                // 32 qtiles x 128 rows
  const int half = rem >> 5;              // kv half
  const int t = threadIdx.x, w = t >> 6, lane = t & 63;
  const int lq = lane & 31, lh = lane >> 5;

  __shared__ u8 Lf[65536];   // main loop: 2 bufs x (K 8KB + V 8KB) = 32KB; epilogue 64KB

  const u8* kb = k + (size_t)bb * (4096 * 256);
  const u8* vb = vT + (size_t)bb * (4096 * 256);

  // Q fragments (loop-invariant): 8 x 16B, frag cb feeds MFMAs 2cb, 2cb+1
  const int qrow = bb * 4096 + qt * 128 + w * 32 + lq;
  u32x4 qf[8];
  {
    const u8* qp = q + (size_t)qrow * 256;
#pragma unroll
    for (int cb = 0; cb < 8; ++cb) qf[cb] = *(const u32x4*)(qp + cb * 32 + lh * 16);
  }
  f32x16 oacc[8];
#pragma unroll
  for (int i = 0; i < 8; ++i) oacc[i] = (f32x16)(0.f);
  float mrun = -3e38f, lrun = 0.f;        // exp2 (log2) domain
  const float cs = 0.0625f * 1.44269504f; // scale * log2(e)

  // stage one 32-row chunk (16KB) into buffer db; 4 gload_lds per thread
  auto stage = [&](int it, int db) {
    const int ci = half * 64 + it;
    const u8* kcb = kb + (size_t)ci * (32 * 256);
    const u8* vcb = vb + (size_t)ci * 32;
    u8* base = Lf + db * 16384;
#pragma unroll
    for (int i = 0; i < 2; ++i) {
      int bu = w * 128 + i * 64;          // wave-uniform base unit (16B units)
      int Pu = bu + lane;
      {  // K region: logical L = row*16 + off16; P = L ^ ((L>>4)&7)
        int Lu = Pu ^ ((Pu >> 4) & 7);
        const u8* ksrc = kcb + (Lu >> 4) * 256 + (Lu & 15) * 16;
        __builtin_amdgcn_global_load_lds(
            (const __attribute__((address_space(1))) uint*)ksrc,
            (__attribute__((address_space(3))) uint*)(base + bu * 16), 16, 0, 0);
      }
      {  // V region: logical L = drow*2 + lhv; P = L ^ ((L>>3)&7)
        int Lu = Pu ^ ((Pu >> 3) & 7);
        const u8* vsrc = vcb + (size_t)(Lu >> 1) * 4096 + (Lu & 1) * 16;
        __builtin_amdgcn_global_load_lds(
            (const __attribute__((address_space(1))) uint*)vsrc,
            (__attribute__((address_space(3))) uint*)(base + 8192 + bu * 16), 16, 0, 0);
      }
    }
  };

  stage(0, 0);

#pragma unroll 1
  for (int j = 0; j < 64; ++j) {
    if (j < 63) {
      stage(j + 1, (j + 1) & 1);
      asm volatile("s_waitcnt vmcnt(4)" ::: "memory");
    } else {
      asm volatile("s_waitcnt vmcnt(0)" ::: "memory");
    }
    __builtin_amdgcn_s_barrier();

    const u8* Kbf = Lf + (j & 1) * 16384;
    const u8* Vbf = Kbf + 8192;

    // ---- QK^T: 16 fp8 MFMAs from 8 b128 reads (2 acc chains) ----
    __builtin_amdgcn_s_setprio(1);
    f32x16 s0 = (f32x16)(0.f), s1 = (f32x16)(0.f);
#pragma unroll
    for (int cb = 0; cb < 8; ++cb) {
      int Pu = (lq * 16 + cb * 2 + lh) ^ (lq & 7);
      u32x4 kr = *(const u32x4*)(Kbf + Pu * 16);
      s64x2 kp = __builtin_bit_cast(s64x2, kr);
      s64x2 qp2 = __builtin_bit_cast(s64x2, qf[cb]);
      s0 = MFMAF8(kp[0], qp2[0], s0);
      s1 = MFMAF8(kp[1], qp2[1], s1);
    }
    __builtin_amdgcn_s_setprio(0);
    // ---- lean online softmax: max on raw sums (1 mul), fma+exp2 fused ----
    float tv[16];
#pragma unroll
    for (int r = 0; r < 16; ++r) tv[r] = s0[r] + s1[r];
    float g0 = max3f(tv[0], tv[1], tv[2]);
    float g1 = max3f(tv[3], tv[4], tv[5]);
    float g2 = max3f(tv[6], tv[7], tv[8]);
    float g3 = max3f(tv[9], tv[10], tv[11]);
    float g4 = max3f(tv[12], tv[13], tv[14]);
    float pmax_t = max3f(max3f(g0, g1, tv[15]), fmaxf(g2, g3), g4);
    pmax_t = fmaxf(pmax_t, __shfl_xor(pmax_t, 32));
    float pmax = pmax_t * cs;
    if (!__all(pmax - mrun <= 8.f)) {     // defer-max; 2^8=256 < fp8 max 448
      float mnew = fmaxf(mrun, pmax);
      float alpha = __builtin_exp2f(mrun - mnew);
#pragma unroll
      for (int i = 0; i < 8; ++i) oacc[i] *= alpha;
      lrun *= alpha;
      mrun = mnew;
    }
    float nm = -mrun;
    float sv[16], psum = 0.f;
#pragma unroll
    for (int r = 0; r < 16; ++r) {
      sv[r] = __builtin_exp2f(__builtin_fmaf(tv[r], cs, nm));
      psum += sv[r];
    }
    psum += __shfl_xor(psum, 32);
    lrun += psum;
    // ---- P -> fp8 B-frags: 8 cvt_pk_fp8 + 2 permlane32_swap ----
    uint Aw = (uint)__builtin_amdgcn_cvt_pk_fp8_f32(sv[0], sv[1], 0, false);
    Aw = (uint)__builtin_amdgcn_cvt_pk_fp8_f32(sv[2], sv[3], (int)Aw, true);
    uint Bw = (uint)__builtin_amdgcn_cvt_pk_fp8_f32(sv[4], sv[5], 0, false);
    Bw = (uint)__builtin_amdgcn_cvt_pk_fp8_f32(sv[6], sv[7], (int)Bw, true);
    uint Cw = (uint)__builtin_amdgcn_cvt_pk_fp8_f32(sv[8], sv[9], 0, false);
    Cw = (uint)__builtin_amdgcn_cvt_pk_fp8_f32(sv[10], sv[11], (int)Cw, true);
    uint Dw = (uint)__builtin_amdgcn_cvt_pk_fp8_f32(sv[12], sv[13], 0, false);
    Dw = (uint)__builtin_amdgcn_cvt_pk_fp8_f32(sv[14], sv[15], (int)Dw, true);
    asm("v_permlane32_swap_b32 %0, %1" : "+v"(Aw), "+v"(Bw));
    asm("v_permlane32_swap_b32 %0, %1" : "+v"(Cw), "+v"(Dw));
    long pf0 = __builtin_bit_cast(long, (u32x2){Aw, Bw});  // kv slots 0..15
    long pf1 = __builtin_bit_cast(long, (u32x2){Cw, Dw});  // kv slots 16..31
    // ---- PV: one b128 per d-block feeds both MFMAs ----
    __builtin_amdgcn_s_setprio(1);
#pragma unroll
    for (int db = 0; db < 8; ++db) {
      int L = (db * 32 + lq) * 2 + lh;
      int Pu = L ^ ((L >> 3) & 7);
      u32x4 vr = *(const u32x4*)(Vbf + Pu * 16);
      s64x2 vp = __builtin_bit_cast(s64x2, vr);
      oacc[db] = MFMAF8(vp[0], pf0, oacc[db]);
      oacc[db] = MFMAF8(vp[1], pf1, oacc[db]);
    }
    __builtin_amdgcn_s_setprio(0);
    asm volatile("" ::: "memory");
    __builtin_amdgcn_s_barrier();
    asm volatile("" ::: "memory");
  }

  // ---- epilogue: raw partials -> LDS transpose (XOR-swz) -> coalesced store ----
  {
    uint* wregu = (uint*)Lf + w * 4096;   // 32 q-rows x 128 uints per wave
#pragma unroll
    for (int db = 0; db < 8; ++db)
#pragma unroll
      for (int rp = 0; rp < 8; ++rp) {
        int r0 = rp * 2;
        int d0 = db * 32 + (r0 & 3) + 8 * (r0 >> 2) + 4 * lh;
        uint pk;
        asm("v_cvt_pk_bf16_f32 %0, %1, %2"
            : "=v"(pk) : "v"(oacc[db][r0]), "v"(oacc[db][r0 + 1]));
        int idx = lq * 128 + (d0 >> 1);
        wregu[idx ^ ((lq & 7) << 2)] = pk;
      }
    if (lh == 0) {
      int idx = half * 32768 + bb * 4096 + qt * 128 + w * 32 + lq;
      mlbuf[idx] = mrun;                  // exp2-domain max
      mlbuf[65536 + idx] = lrun;
    }
  }
  __syncthreads();
  {
    int r = t >> 1;                        // 0..127 row in tile
    int wv2 = r >> 5, lqr = r & 31;
    const uint* basep = (const uint*)Lf + wv2 * 4096;
    ushort* pbase = half ? pb1 : pb0;
    ushort* dstr = pbase + ((size_t)bb * 4096 + qt * 128 + r) * 256 + (t & 1) * 128;
#pragma unroll
    for (int jj = 0; jj < 16; ++jj) {
      int ui = lqr * 128 + (t & 1) * 64 + jj * 4;
      u32x4 v = *(const u32x4*)(basep + (ui ^ ((lqr & 7) << 2)));
      *(u32x4*)(dstr + jj * 8) = v;
    }
  }
}

// ---------------- merge the two kv-half partials (exp2 domain) ----------------
__global__ __launch_bounds__(256) void attn_merge_kernel(
    const ushort* __restrict__ pb0, const ushort* __restrict__ pb1,
    const float* __restrict__ mlbuf, ushort* __restrict__ o) {
  int gr = blockIdx.x * 8 + (threadIdx.x >> 5);   // global row 0..32767
  int dq = threadIdx.x & 31;                      // 8 d-elems each
  float m0 = mlbuf[gr], m1 = mlbuf[32768 + gr];
  float l0 = mlbuf[65536 + gr], l1 = mlbuf[65536 + 32768 + gr];
  float M = fmaxf(m0, m1);
  float e0 = __builtin_exp2f(m0 - M), e1 = __builtin_exp2f(m1 - M);
  float inv = 1.f / (l0 * e0 + l1 * e1);
  float w0 = e0 * inv, w1 = e1 * inv;
  const size_t off = (size_t)gr * 256 + dq * 8;
  u32x4 a = *(const u32x4*)(pb0 + off);
  u32x4 b = *(const u32x4*)(pb1 + off);
  uint outw[4];
#pragma unroll
  for (int i = 0; i < 4; ++i) {
    float alo = __builtin_bit_cast(float, a[i] << 16);
    float ahi = __builtin_bit_cast(float, a[i] & 0xffff0000u);
    float blo = __builtin_bit_cast(float, b[i] << 16);
    float bhi = __builtin_bit_cast(float, b[i] & 0xffff0000u);
    float flo = alo * w0 + blo * w1;
    float fhi = ahi * w0 + bhi * w1;
    asm("v_cvt_pk_bf16_f32 %0, %1, %2" : "=v"(outw[i]) : "v"(flo), "v"(fhi));
  }
  u32x4 ov = {outw[0], outw[1], outw[2], outw[3]};
  *(u32x4*)(o + off) = ov;
}

extern "C" void kernel_launch(void* const* d_in, const int* in_sizes, int n_in,
                              void* d_out, int out_size, void* d_ws, size_t ws_size,
                              hipStream_t stream) {
  const float* x   = (const float*)d_in[0];
  const float* gnw = (const float*)d_in[1];
  const float* gnb = (const float*)d_in[2];
  const float* wq  = (const float*)d_in[3];
  const float* bq  = (const float*)d_in[4];
  const float* wk  = (const float*)d_in[5];
  const float* bk  = (const float*)d_in[6];
  const float* wv  = (const float*)d_in[7];
  const float* bv  = (const float*)d_in[8];
  const float* wp  = (const float*)d_in[9];
  const float* bp  = (const float*)d_in[10];

  const size_t SEQ = 4096, CH = 256;
  const size_t MAT = SEQ * CH;
  char* ws = (char*)d_ws;
  const size_t BUF = 8 * MAT * 2;        // 16 MiB
  ushort* y    = (ushort*)(ws + 0 * BUF);
  u8*     qb8  = (u8*)(ws + 1 * BUF);    // fp8 q [b][n][c]  (8 MB)
  u8*     kb8  = (u8*)(ws + 2 * BUF);    // fp8 k [b][n][c]  (= qb8 + 16MB)
  u8*     vtb8 = (u8*)(ws + 3 * BUF);    // fp8 vT [b][c][n], kv-permuted per 32
  ushort* pb1  = (ushort*)(ws + 4 * BUF);
  ushort* pb0  = y;                      // y dead after V GEMM
  ushort* oab  = (ushort*)(ws + 1 * BUF);// q dead after attn; merge writes here
  ushort* wqb  = (ushort*)(ws + 5 * BUF);
  ushort* wkb  = wqb + 65536;            // contiguous with wqb -> fused q|k B
  ushort* wvb  = wkb + 65536;
  ushort* wpb  = wvb + 65536;
  float* scaleB = (float*)(wpb + 65536);
  float* shiftB = scaleB + 8 * 256;
  float* mlbuf  = (float*)d_out;         // 512KB scratch; overwritten by proj GEMM

  cvt_w_kernel<<<64, 256, 0, stream>>>(wq, wk, wv, wp, wqb, wkb, wvb, wpb);
  gn_stats_kernel<<<64, 256, 0, stream>>>(x, gnw, gnb, scaleB, shiftB);
  gn_apply_kernel<<<2048, 256, 0, stream>>>(x, scaleB, shiftB, y);

  // fused q|k GEMM: B = [wq;wk] (512 rows), outputs qb8 / kb8 (+16MB)
  gemm_bt<5><<<dim3(128, 8), 256, 0, stream>>>(y, wqb, MAT, 0, 4096, 512, bq,
                                               bk, 0, qb8, MAT);
  gemm_bt<4><<<dim3(64, 8), 256, 0, stream>>>(wvb, y, 0, MAT, 256, 4096, bv,
                                              nullptr, 0, vtb8, MAT);

  attn10_kernel<<<512, 256, 0, stream>>>(qb8, kb8, vtb8, pb0, pb1, mlbuf);
  attn_merge_kernel<<<4096, 256, 0, stream>>>(pb0, pb1, mlbuf, oab);

  gemm_bt<2><<<dim3(64, 8), 256, 0, stream>>>(wpb, oab, 0, MAT, 256, 4096, bp,
                                              x, MAT, d_out, MAT);
}

// Round 15
// 218.448 us; speedup vs baseline: 1.8035x; 1.0661x over previous
//
#include <hip/hip_runtime.h>

typedef __attribute__((ext_vector_type(8))) short s16x8;
typedef __attribute__((ext_vector_type(4))) float f32x4;
typedef __attribute__((ext_vector_type(16))) float f32x16;
typedef __attribute__((ext_vector_type(4))) uint u32x4;
typedef __attribute__((ext_vector_type(2))) uint u32x2;
typedef __attribute__((ext_vector_type(2))) long s64x2;
typedef unsigned char u8;

#define MFMA16(a, b, c) __builtin_amdgcn_mfma_f32_16x16x32_bf16((a), (b), (c), 0, 0, 0)
#define MFMAF8(a, b, c) __builtin_amdgcn_mfma_f32_32x32x16_fp8_fp8((a), (b), (c), 0, 0, 0)

__device__ __forceinline__ ushort f2bf(float f) {
  uint u = __builtin_bit_cast(uint, f);
  u = (u + 0x7fffu + ((u >> 16) & 1u)) >> 16;
  return (ushort)u;
}
__device__ __forceinline__ float max3f(float a, float b, float c) {
  return fmaxf(fmaxf(a, b), c);   // clang fuses to v_max3_f32
}

// ---------------- weight fp32 -> bf16 (+ pack bcat = bq|bk|bv) ----------------
__global__ __launch_bounds__(256) void cvt_w_kernel(
    const float* __restrict__ s0, const float* __restrict__ s1,
    const float* __restrict__ s2, const float* __restrict__ s3,
    ushort* __restrict__ d0, ushort* __restrict__ d1,
    ushort* __restrict__ d2, ushort* __restrict__ d3,
    const float* __restrict__ bq, const float* __restrict__ bk,
    const float* __restrict__ bv, float* __restrict__ bcat) {
  int i = blockIdx.x * 256 + threadIdx.x;
  const float4* s[4] = {(const float4*)s0, (const float4*)s1, (const float4*)s2, (const float4*)s3};
  ushort* d[4] = {d0, d1, d2, d3};
#pragma unroll
  for (int m = 0; m < 4; ++m) {
    float4 v = s[m][i];
    uint lo = (uint)f2bf(v.x) | ((uint)f2bf(v.y) << 16);
    uint hi = (uint)f2bf(v.z) | ((uint)f2bf(v.w) << 16);
    *(uint2*)(d[m] + (size_t)i * 4) = make_uint2(lo, hi);
  }
  if (blockIdx.x == 0) {
    int t = threadIdx.x;
    bcat[t] = bq[t];
    bcat[256 + t] = bk[t];
    bcat[512 + t] = bv[t];
  }
}

// ---------------- GroupNorm stats stage 1: 512-block partial sums ----------------
__global__ __launch_bounds__(256) void gn_stats_kernel(
    const float* __restrict__ x, float2* __restrict__ partial) {
  int bid = blockIdx.x;                 // b = bid>>6, g = (bid>>3)&7, slice = bid&7
  int b = bid >> 6, g = (bid >> 3) & 7, sl = bid & 7;
  const float4* src = (const float4*)(x + ((size_t)b * 256 + g * 32) * 4096) + sl * 4096;
  float s = 0.f, ss = 0.f;
#pragma unroll 4
  for (int i = threadIdx.x; i < 4096; i += 256) {
    float4 v = src[i];
    s += v.x + v.y + v.z + v.w;
    ss += v.x * v.x + v.y * v.y + v.z * v.z + v.w * v.w;
  }
#pragma unroll
  for (int off = 32; off; off >>= 1) {
    s += __shfl_down(s, off);
    ss += __shfl_down(ss, off);
  }
  __shared__ float ps[4], pss[4];
  int w = threadIdx.x >> 6, lane = threadIdx.x & 63;
  if (lane == 0) { ps[w] = s; pss[w] = ss; }
  __syncthreads();
  if (threadIdx.x == 0) {
    float2 r;
    r.x = ps[0] + ps[1] + ps[2] + ps[3];
    r.y = pss[0] + pss[1] + pss[2] + pss[3];
    partial[bid] = r;
  }
}

// ---------------- GN apply + transpose (finalizes stats in-block) ----------------
__global__ __launch_bounds__(256) void gn_apply_kernel(
    const float* __restrict__ x, const float2* __restrict__ partial,
    const float* __restrict__ gw, const float* __restrict__ gb,
    ushort* __restrict__ y) {
  int bid = blockIdx.x;
  int b = bid >> 8;
  int rem = bid & 255;
  int ct = rem >> 6, nt = rem & 63;   // 64-channel tile = groups 2ct, 2ct+1
  int t = threadIdx.x;
  __shared__ float xs[64][65];
  __shared__ float smu2[2], srs2[2];
  if (t < 2) {
    float S = 0.f, SS = 0.f;
#pragma unroll
    for (int i = 0; i < 8; ++i) {
      float2 p = partial[(b << 6) | ((2 * ct + t) << 3) | i];
      S += p.x;
      SS += p.y;
    }
    float mu = S * (1.f / 131072.f);
    float var = SS * (1.f / 131072.f) - mu * mu;
    smu2[t] = mu;
    srs2[t] = rsqrtf(var + 1e-5f);
  }
  const float* xb = x + ((size_t)b * 256 + ct * 64) * 4096 + nt * 64;
  {
    int r = t >> 2, q = t & 3;
    const float4* src = (const float4*)(xb + (size_t)r * 4096 + q * 16);
#pragma unroll
    for (int i = 0; i < 4; ++i) {
      float4 v = src[i];
      xs[r][q * 16 + i * 4 + 0] = v.x;
      xs[r][q * 16 + i * 4 + 1] = v.y;
      xs[r][q * 16 + i * 4 + 2] = v.z;
      xs[r][q * 16 + i * 4 + 3] = v.w;
    }
  }
  __syncthreads();
  {
    int nr = t >> 2, q = t & 3;
    int c0 = q * 16;
    ushort tmp[16];
#pragma unroll
    for (int i = 0; i < 16; ++i) {
      int ci = c0 + i;                  // 0..63 within tile
      int ch = ct * 64 + ci;
      int gsel = ci >> 5;
      float sc = gw[ch] * srs2[gsel];
      float sh = gb[ch] - smu2[gsel] * sc;
      float v = xs[ci][nr] * sc + sh;
      tmp[i] = f2bf(v);
    }
    ushort* dst = y + ((size_t)b * 4096 + nt * 64 + nr) * 256 + ct * 64 + c0;
    uint p[8];
#pragma unroll
    for (int j = 0; j < 8; ++j) p[j] = (uint)tmp[2 * j] | ((uint)tmp[2 * j + 1] << 16);
    *(uint4*)dst = make_uint4(p[0], p[1], p[2], p[3]);
    *((uint4*)dst + 1) = make_uint4(p[4], p[5], p[6], p[7]);
  }
}

// ---------------- GEMM: C[M][N] = A[M][256] . B[N][256]^T (+bias, +resid) ----------------
// DMA staging (gload_lds w=16), XOR-swizzled source+reads, dbuf + counted vmcnt.
// MODE 2: f32 out, bias row + residual.
// MODE 6: fused q|k|v fp8 out (N=768, bias=bcat):
//   col<256 -> qb8[row][col]; col<512 -> kb8(+16MB)[row][col-256];
//   col>=512 -> vtb8(+32MB)[col-512][perm(row)]  (kv-perm on n=row).
template <int MODE>
__global__ __launch_bounds__(256) void gemm_bt(
    const ushort* __restrict__ A, const ushort* __restrict__ B,
    size_t aB, size_t bB, int M, int N,
    const float* __restrict__ bias, const float* __restrict__ resid,
    size_t rB, void* __restrict__ Cout, size_t cB) {
  int mTiles = M >> 7;
  int tm = blockIdx.x % mTiles, tn = blockIdx.x / mTiles;
  const ushort* Ab = A + blockIdx.y * aB + (size_t)tm * 128 * 256;
  const ushort* Bb = B + blockIdx.y * bB + (size_t)tn * 128 * 256;

  __shared__ ushort As[2][8192];   // [128][64] linear, XOR-swizzled contents
  __shared__ ushort Bs[2][8192];

  int t = threadIdx.x, lane = t & 63, w = t >> 6;
  int wr = w >> 1, wc = w & 1, lq = lane & 15, lg = lane >> 4;

  f32x4 acc[4][4];
#pragma unroll
  for (int i = 0; i < 4; ++i)
#pragma unroll
    for (int j = 0; j < 4; ++j) acc[i][j] = f32x4{0.f, 0.f, 0.f, 0.f};

  auto stageT = [&](int kb, int db) {
#pragma unroll
    for (int i = 0; i < 4; ++i) {
      int bu = i * 256 + w * 64;          // wave-uniform base unit (16B units)
      int u = bu + lane;
      int row = u >> 3, c = u & 7;
      int cl = c ^ (row & 7);             // pre-swizzled logical column unit
      const ushort* sa = Ab + (size_t)row * 256 + kb * 64 + cl * 8;
      __builtin_amdgcn_global_load_lds(
          (const __attribute__((address_space(1))) uint*)sa,
          (__attribute__((address_space(3))) uint*)(&As[db][0] + bu * 8), 16, 0, 0);
      const ushort* sb = Bb + (size_t)row * 256 + kb * 64 + cl * 8;
      __builtin_amdgcn_global_load_lds(
          (const __attribute__((address_space(1))) uint*)sb,
          (__attribute__((address_space(3))) uint*)(&Bs[db][0] + bu * 8), 16, 0, 0);
    }
  };

  stageT(0, 0);

#pragma unroll 1
  for (int kb = 0; kb < 4; ++kb) {
    if (kb < 3) {
      stageT(kb + 1, (kb + 1) & 1);
      asm volatile("s_waitcnt vmcnt(8)" ::: "memory");
    } else {
      asm volatile("s_waitcnt vmcnt(0)" ::: "memory");
    }
    __builtin_amdgcn_s_barrier();
    const ushort* Abf = &As[kb & 1][0];
    const ushort* Bbf = &Bs[kb & 1][0];
#pragma unroll
    for (int ks = 0; ks < 2; ++ks) {
      s16x8 af[4], bf[4];
#pragma unroll
      for (int mt = 0; mt < 4; ++mt) {
        int row = wr * 64 + mt * 16 + lq;
        af[mt] = *(const s16x8*)&Abf[row * 64 + (((ks * 4 + lg) ^ (row & 7)) << 3)];
      }
#pragma unroll
      for (int nt = 0; nt < 4; ++nt) {
        int row = wc * 64 + nt * 16 + lq;
        bf[nt] = *(const s16x8*)&Bbf[row * 64 + (((ks * 4 + lg) ^ (row & 7)) << 3)];
      }
#pragma unroll
      for (int mt = 0; mt < 4; ++mt)
#pragma unroll
        for (int nt = 0; nt < 4; ++nt)
          acc[mt][nt] = MFMA16(af[mt], bf[nt], acc[mt][nt]);
    }
    asm volatile("" ::: "memory");
    __builtin_amdgcn_s_barrier();
    asm volatile("" ::: "memory");
  }

  int mBase = tm * 128 + wr * 64;
  int nBase = tn * 128 + wc * 64;
#pragma unroll
  for (int mt = 0; mt < 4; ++mt) {
#pragma unroll
    for (int nt = 0; nt < 4; ++nt) {
#pragma unroll
      for (int r = 0; r < 4; ++r) {
        int row = mBase + mt * 16 + lg * 4 + r;
        int col = nBase + nt * 16 + lq;
        float v = acc[mt][nt][r];
        if (MODE == 6) {
          v += bias[col];
          uint pk8 = (uint)__builtin_amdgcn_cvt_pk_fp8_f32(v, v, 0, false);
          u8* Cb = (u8*)Cout + blockIdx.y * cB;
          if (col < 512) {
            u8* C = Cb + ((col >= 256) ? 16777216 : 0);
            C[(size_t)row * 256 + (col & 255)] = (u8)(pk8 & 0xff);
          } else {
            int rr = row & 31;
            int pr = (row & ~31) |
                     ((rr & 7) | (((rr >> 4) & 1) << 3) | (((rr >> 3) & 1) << 4));
            u8* C = Cb + 33554432;
            C[(size_t)(col - 512) * 4096 + pr] = (u8)(pk8 & 0xff);
          }
        } else {  // MODE 2
          v += bias[row];
          size_t idx = (size_t)row * N + col;
          float* C = (float*)Cout + blockIdx.y * cB;
          C[idx] = v + resid[blockIdx.y * rB + idx];
        }
      }
    }
  }
}

// ---------------- Flash attention v10b: fp8 datapath, lean softmax ----------------
// Grid 512 = 8 batch x 32 qtiles(128 rows) x 2 kv-halves; 256 thr = 4 waves.
__global__ __launch_bounds__(256, 2) void attn10_kernel(
    const u8* __restrict__ q, const u8* __restrict__ k,
    const u8* __restrict__ vT, ushort* __restrict__ pb0,
    ushort* __restrict__ pb1, float* __restrict__ mlbuf) {
  const int bb = blockIdx.x & 7;          // batch -> XCD pinning
  const int rem = blockIdx.x >> 3;        // 0..63
  const int qt = rem & 31;                // 32 qtiles x 128 rows
  const int half = rem >> 5;              // kv half
  const int t = threadIdx.x, w = t >> 6, lane = t & 63;
  const int lq = lane & 31, lh = lane >> 5;

  __shared__ u8 Lf[65536];   // main loop: 2 bufs x (K 8KB + V 8KB) = 32KB; epilogue 64KB

  const u8* kb = k + (size_t)bb * (4096 * 256);
  const u8* vb = vT + (size_t)bb * (4096 * 256);

  // Q fragments (loop-invariant): 8 x 16B, frag cb feeds MFMAs 2cb, 2cb+1
  const int qrow = bb * 4096 + qt * 128 + w * 32 + lq;
  u32x4 qf[8];
  {
    const u8* qp = q + (size_t)qrow * 256;
#pragma unroll
    for (int cb = 0; cb < 8; ++cb) qf[cb] = *(const u32x4*)(qp + cb * 32 + lh * 16);
  }
  f32x16 oacc[8];
#pragma unroll
  for (int i = 0; i < 8; ++i) oacc[i] = (f32x16)(0.f);
  float mrun = -3e38f, lrun = 0.f;        // exp2 (log2) domain
  const float cs = 0.0625f * 1.44269504f; // scale * log2(e)

  // stage one 32-row chunk (16KB) into buffer db; 4 gload_lds per thread
  auto stage = [&](int it, int db) {
    const int ci = half * 64 + it;
    const u8* kcb = kb + (size_t)ci * (32 * 256);
    const u8* vcb = vb + (size_t)ci * 32;
    u8* base = Lf + db * 16384;
#pragma unroll
    for (int i = 0; i < 2; ++i) {
      int bu = w * 128 + i * 64;          // wave-uniform base unit (16B units)
      int Pu = bu + lane;
      {  // K region: logical L = row*16 + off16; P = L ^ ((L>>4)&7)
        int Lu = Pu ^ ((Pu >> 4) & 7);
        const u8* ksrc = kcb + (Lu >> 4) * 256 + (Lu & 15) * 16;
        __builtin_amdgcn_global_load_lds(
            (const __attribute__((address_space(1))) uint*)ksrc,
            (__attribute__((address_space(3))) uint*)(base + bu * 16), 16, 0, 0);
      }
      {  // V region: logical L = drow*2 + lhv; P = L ^ ((L>>3)&7)
        int Lu = Pu ^ ((Pu >> 3) & 7);
        const u8* vsrc = vcb + (size_t)(Lu >> 1) * 4096 + (Lu & 1) * 16;
        __builtin_amdgcn_global_load_lds(
            (const __attribute__((address_space(1))) uint*)vsrc,
            (__attribute__((address_space(3))) uint*)(base + 8192 + bu * 16), 16, 0, 0);
      }
    }
  };

  stage(0, 0);

#pragma unroll 1
  for (int j = 0; j < 64; ++j) {
    if (j < 63) {
      stage(j + 1, (j + 1) & 1);
      asm volatile("s_waitcnt vmcnt(4)" ::: "memory");
    } else {
      asm volatile("s_waitcnt vmcnt(0)" ::: "memory");
    }
    __builtin_amdgcn_s_barrier();

    const u8* Kbf = Lf + (j & 1) * 16384;
    const u8* Vbf = Kbf + 8192;

    // ---- QK^T: 16 fp8 MFMAs from 8 b128 reads (2 acc chains) ----
    __builtin_amdgcn_s_setprio(1);
    f32x16 s0 = (f32x16)(0.f), s1 = (f32x16)(0.f);
#pragma unroll
    for (int cb = 0; cb < 8; ++cb) {
      int Pu = (lq * 16 + cb * 2 + lh) ^ (lq & 7);
      u32x4 kr = *(const u32x4*)(Kbf + Pu * 16);
      s64x2 kp = __builtin_bit_cast(s64x2, kr);
      s64x2 qp2 = __builtin_bit_cast(s64x2, qf[cb]);
      s0 = MFMAF8(kp[0], qp2[0], s0);
      s1 = MFMAF8(kp[1], qp2[1], s1);
    }
    __builtin_amdgcn_s_setprio(0);
    // ---- lean online softmax: max on raw sums (1 mul), fma+exp2 fused ----
    float tv[16];
#pragma unroll
    for (int r = 0; r < 16; ++r) tv[r] = s0[r] + s1[r];
    float g0 = max3f(tv[0], tv[1], tv[2]);
    float g1 = max3f(tv[3], tv[4], tv[5]);
    float g2 = max3f(tv[6], tv[7], tv[8]);
    float g3 = max3f(tv[9], tv[10], tv[11]);
    float g4 = max3f(tv[12], tv[13], tv[14]);
    float pmax_t = max3f(max3f(g0, g1, tv[15]), fmaxf(g2, g3), g4);
    pmax_t = fmaxf(pmax_t, __shfl_xor(pmax_t, 32));
    float pmax = pmax_t * cs;
    if (!__all(pmax - mrun <= 8.f)) {     // defer-max; 2^8=256 < fp8 max 448
      float mnew = fmaxf(mrun, pmax);
      float alpha = __builtin_exp2f(mrun - mnew);
#pragma unroll
      for (int i = 0; i < 8; ++i) oacc[i] *= alpha;
      lrun *= alpha;
      mrun = mnew;
    }
    float nm = -mrun;
    float sv[16], psum = 0.f;
#pragma unroll
    for (int r = 0; r < 16; ++r) {
      sv[r] = __builtin_exp2f(__builtin_fmaf(tv[r], cs, nm));
      psum += sv[r];
    }
    psum += __shfl_xor(psum, 32);
    lrun += psum;
    // ---- P -> fp8 B-frags: 8 cvt_pk_fp8 + 2 permlane32_swap ----
    uint Aw = (uint)__builtin_amdgcn_cvt_pk_fp8_f32(sv[0], sv[1], 0, false);
    Aw = (uint)__builtin_amdgcn_cvt_pk_fp8_f32(sv[2], sv[3], (int)Aw, true);
    uint Bw = (uint)__builtin_amdgcn_cvt_pk_fp8_f32(sv[4], sv[5], 0, false);
    Bw = (uint)__builtin_amdgcn_cvt_pk_fp8_f32(sv[6], sv[7], (int)Bw, true);
    uint Cw = (uint)__builtin_amdgcn_cvt_pk_fp8_f32(sv[8], sv[9], 0, false);
    Cw = (uint)__builtin_amdgcn_cvt_pk_fp8_f32(sv[10], sv[11], (int)Cw, true);
    uint Dw = (uint)__builtin_amdgcn_cvt_pk_fp8_f32(sv[12], sv[13], 0, false);
    Dw = (uint)__builtin_amdgcn_cvt_pk_fp8_f32(sv[14], sv[15], (int)Dw, true);
    asm("v_permlane32_swap_b32 %0, %1" : "+v"(Aw), "+v"(Bw));
    asm("v_permlane32_swap_b32 %0, %1" : "+v"(Cw), "+v"(Dw));
    long pf0 = __builtin_bit_cast(long, (u32x2){Aw, Bw});  // kv slots 0..15
    long pf1 = __builtin_bit_cast(long, (u32x2){Cw, Dw});  // kv slots 16..31
    // ---- PV: one b128 per d-block feeds both MFMAs ----
    __builtin_amdgcn_s_setprio(1);
#pragma unroll
    for (int db = 0; db < 8; ++db) {
      int L = (db * 32 + lq) * 2 + lh;
      int Pu = L ^ ((L >> 3) & 7);
      u32x4 vr = *(const u32x4*)(Vbf + Pu * 16);
      s64x2 vp = __builtin_bit_cast(s64x2, vr);
      oacc[db] = MFMAF8(vp[0], pf0, oacc[db]);
      oacc[db] = MFMAF8(vp[1], pf1, oacc[db]);
    }
    __builtin_amdgcn_s_setprio(0);
    asm volatile("" ::: "memory");
    __builtin_amdgcn_s_barrier();
    asm volatile("" ::: "memory");
  }

  // ---- epilogue: raw partials -> LDS transpose (XOR-swz) -> coalesced store ----
  {
    uint* wregu = (uint*)Lf + w * 4096;   // 32 q-rows x 128 uints per wave
#pragma unroll
    for (int db = 0; db < 8; ++db)
#pragma unroll
      for (int rp = 0; rp < 8; ++rp) {
        int r0 = rp * 2;
        int d0 = db * 32 + (r0 & 3) + 8 * (r0 >> 2) + 4 * lh;
        uint pk;
        asm("v_cvt_pk_bf16_f32 %0, %1, %2"
            : "=v"(pk) : "v"(oacc[db][r0]), "v"(oacc[db][r0 + 1]));
        int idx = lq * 128 + (d0 >> 1);
        wregu[idx ^ ((lq & 7) << 2)] = pk;
      }
    if (lh == 0) {
      int idx = half * 32768 + bb * 4096 + qt * 128 + w * 32 + lq;
      mlbuf[idx] = mrun;                  // exp2-domain max
      mlbuf[65536 + idx] = lrun;
    }
  }
  __syncthreads();
  {
    int r = t >> 1;                        // 0..127 row in tile
    int wv2 = r >> 5, lqr = r & 31;
    const uint* basep = (const uint*)Lf + wv2 * 4096;
    ushort* pbase = half ? pb1 : pb0;
    ushort* dstr = pbase + ((size_t)bb * 4096 + qt * 128 + r) * 256 + (t & 1) * 128;
#pragma unroll
    for (int jj = 0; jj < 16; ++jj) {
      int ui = lqr * 128 + (t & 1) * 64 + jj * 4;
      u32x4 v = *(const u32x4*)(basep + (ui ^ ((lqr & 7) << 2)));
      *(u32x4*)(dstr + jj * 8) = v;
    }
  }
}

// ---------------- merge the two kv-half partials (exp2 domain) ----------------
__global__ __launch_bounds__(256) void attn_merge_kernel(
    const ushort* __restrict__ pb0, const ushort* __restrict__ pb1,
    const float* __restrict__ mlbuf, ushort* __restrict__ o) {
  int gr = blockIdx.x * 8 + (threadIdx.x >> 5);   // global row 0..32767
  int dq = threadIdx.x & 31;                      // 8 d-elems each
  float m0 = mlbuf[gr], m1 = mlbuf[32768 + gr];
  float l0 = mlbuf[65536 + gr], l1 = mlbuf[65536 + 32768 + gr];
  float M = fmaxf(m0, m1);
  float e0 = __builtin_exp2f(m0 - M), e1 = __builtin_exp2f(m1 - M);
  float inv = 1.f / (l0 * e0 + l1 * e1);
  float w0 = e0 * inv, w1 = e1 * inv;
  const size_t off = (size_t)gr * 256 + dq * 8;
  u32x4 a = *(const u32x4*)(pb0 + off);
  u32x4 b = *(const u32x4*)(pb1 + off);
  uint outw[4];
#pragma unroll
  for (int i = 0; i < 4; ++i) {
    float alo = __builtin_bit_cast(float, a[i] << 16);
    float ahi = __builtin_bit_cast(float, a[i] & 0xffff0000u);
    float blo = __builtin_bit_cast(float, b[i] << 16);
    float bhi = __builtin_bit_cast(float, b[i] & 0xffff0000u);
    float flo = alo * w0 + blo * w1;
    float fhi = ahi * w0 + bhi * w1;
    asm("v_cvt_pk_bf16_f32 %0, %1, %2" : "=v"(outw[i]) : "v"(flo), "v"(fhi));
  }
  u32x4 ov = {outw[0], outw[1], outw[2], outw[3]};
  *(u32x4*)(o + off) = ov;
}

extern "C" void kernel_launch(void* const* d_in, const int* in_sizes, int n_in,
                              void* d_out, int out_size, void* d_ws, size_t ws_size,
                              hipStream_t stream) {
  const float* x   = (const float*)d_in[0];
  const float* gnw = (const float*)d_in[1];
  const float* gnb = (const float*)d_in[2];
  const float* wq  = (const float*)d_in[3];
  const float* bq  = (const float*)d_in[4];
  const float* wk  = (const float*)d_in[5];
  const float* bk  = (const float*)d_in[6];
  const float* wv  = (const float*)d_in[7];
  const float* bv  = (const float*)d_in[8];
  const float* wp  = (const float*)d_in[9];
  const float* bp  = (const float*)d_in[10];

  const size_t SEQ = 4096, CH = 256;
  const size_t MAT = SEQ * CH;
  char* ws = (char*)d_ws;
  const size_t BUF = 8 * MAT * 2;        // 16 MiB
  ushort* y    = (ushort*)(ws + 0 * BUF);
  u8*     qb8  = (u8*)(ws + 1 * BUF);    // fp8 q [b][n][c]  (8 MB)
  u8*     kb8  = (u8*)(ws + 2 * BUF);    // fp8 k [b][n][c]  (= qb8 + 16MB)
  u8*     vtb8 = (u8*)(ws + 3 * BUF);    // fp8 vT [b][c][n], kv-permuted (= qb8 + 32MB)
  ushort* pb1  = (ushort*)(ws + 4 * BUF);
  ushort* pb0  = y;                      // y dead after QKV GEMM
  ushort* oab  = (ushort*)(ws + 1 * BUF);// q dead after attn; merge writes here
  ushort* wqb  = (ushort*)(ws + 5 * BUF);
  ushort* wkb  = wqb + 65536;            // contiguous: [wq;wk;wv] fused B
  ushort* wvb  = wkb + 65536;
  ushort* wpb  = wvb + 65536;
  float*  bcat   = (float*)(wpb + 65536);     // 768 floats
  float2* partial = (float2*)(bcat + 768);    // 512 float2 (4KB)
  float*  mlbuf  = (float*)d_out;        // 512KB scratch; overwritten by proj GEMM

  cvt_w_kernel<<<64, 256, 0, stream>>>(wq, wk, wv, wp, wqb, wkb, wvb, wpb,
                                       bq, bk, bv, bcat);
  gn_stats_kernel<<<512, 256, 0, stream>>>(x, partial);
  gn_apply_kernel<<<2048, 256, 0, stream>>>(x, partial, gnw, gnb, y);

  // fused q|k|v GEMM: B = [wq;wk;wv] (768 rows) -> qb8 / kb8 / vtb8
  gemm_bt<6><<<dim3(192, 8), 256, 0, stream>>>(y, wqb, MAT, 0, 4096, 768, bcat,
                                               nullptr, 0, qb8, MAT);

  attn10_kernel<<<512, 256, 0, stream>>>(qb8, kb8, vtb8, pb0, pb1, mlbuf);
  attn_merge_kernel<<<4096, 256, 0, stream>>>(pb0, pb1, mlbuf, oab);

  gemm_bt<2><<<dim3(64, 8), 256, 0, stream>>>(wpb, oab, 0, MAT, 256, 4096, bp,
                                              x, MAT, d_out, MAT);
}

// Round 16
// 199.865 us; speedup vs baseline: 1.9712x; 1.0930x over previous
//
#include <hip/hip_runtime.h>

typedef __attribute__((ext_vector_type(8))) short s16x8;
typedef __attribute__((ext_vector_type(4))) float f32x4;
typedef __attribute__((ext_vector_type(16))) float f32x16;
typedef __attribute__((ext_vector_type(4))) uint u32x4;
typedef __attribute__((ext_vector_type(2))) uint u32x2;
typedef __attribute__((ext_vector_type(2))) long s64x2;
typedef __attribute__((ext_vector_type(8))) int i32x8;
typedef unsigned char u8;

#define MFMA16(a, b, c) __builtin_amdgcn_mfma_f32_16x16x32_bf16((a), (b), (c), 0, 0, 0)
#define MFMAF8(a, b, c) __builtin_amdgcn_mfma_f32_32x32x16_fp8_fp8((a), (b), (c), 0, 0, 0)
// MX-scaled fp8 K=64; fmt 0,0 = e4m3/e4m3; scale bytes 0x7F = e8m0 1.0
#define MFMAMX(a, b, c) \
  __builtin_amdgcn_mfma_scale_f32_32x32x64_f8f6f4((a), (b), (c), 0, 0, 0, 0x7F7F7F7F, 0, 0x7F7F7F7F)

__device__ __forceinline__ ushort f2bf(float f) {
  uint u = __builtin_bit_cast(uint, f);
  u = (u + 0x7fffu + ((u >> 16) & 1u)) >> 16;
  return (ushort)u;
}
__device__ __forceinline__ float max3f(float a, float b, float c) {
  return fmaxf(fmaxf(a, b), c);   // clang fuses to v_max3_f32
}

// ---------------- weight fp32 -> bf16 (+ pack bcat = bq|bk|bv) ----------------
__global__ __launch_bounds__(256) void cvt_w_kernel(
    const float* __restrict__ s0, const float* __restrict__ s1,
    const float* __restrict__ s2, const float* __restrict__ s3,
    ushort* __restrict__ d0, ushort* __restrict__ d1,
    ushort* __restrict__ d2, ushort* __restrict__ d3,
    const float* __restrict__ bq, const float* __restrict__ bk,
    const float* __restrict__ bv, float* __restrict__ bcat) {
  int i = blockIdx.x * 256 + threadIdx.x;
  const float4* s[4] = {(const float4*)s0, (const float4*)s1, (const float4*)s2, (const float4*)s3};
  ushort* d[4] = {d0, d1, d2, d3};
#pragma unroll
  for (int m = 0; m < 4; ++m) {
    float4 v = s[m][i];
    uint lo = (uint)f2bf(v.x) | ((uint)f2bf(v.y) << 16);
    uint hi = (uint)f2bf(v.z) | ((uint)f2bf(v.w) << 16);
    *(uint2*)(d[m] + (size_t)i * 4) = make_uint2(lo, hi);
  }
  if (blockIdx.x == 0) {
    int t = threadIdx.x;
    bcat[t] = bq[t];
    bcat[256 + t] = bk[t];
    bcat[512 + t] = bv[t];
  }
}

// ---------------- GroupNorm stats stage 1: 512-block partial sums ----------------
__global__ __launch_bounds__(256) void gn_stats_kernel(
    const float* __restrict__ x, float2* __restrict__ partial) {
  int bid = blockIdx.x;                 // b = bid>>6, g = (bid>>3)&7, slice = bid&7
  int b = bid >> 6, g = (bid >> 3) & 7, sl = bid & 7;
  const float4* src = (const float4*)(x + ((size_t)b * 256 + g * 32) * 4096) + sl * 4096;
  float s = 0.f, ss = 0.f;
#pragma unroll 4
  for (int i = threadIdx.x; i < 4096; i += 256) {
    float4 v = src[i];
    s += v.x + v.y + v.z + v.w;
    ss += v.x * v.x + v.y * v.y + v.z * v.z + v.w * v.w;
  }
#pragma unroll
  for (int off = 32; off; off >>= 1) {
    s += __shfl_down(s, off);
    ss += __shfl_down(ss, off);
  }
  __shared__ float ps[4], pss[4];
  int w = threadIdx.x >> 6, lane = threadIdx.x & 63;
  if (lane == 0) { ps[w] = s; pss[w] = ss; }
  __syncthreads();
  if (threadIdx.x == 0) {
    float2 r;
    r.x = ps[0] + ps[1] + ps[2] + ps[3];
    r.y = pss[0] + pss[1] + pss[2] + pss[3];
    partial[bid] = r;
  }
}

// ---------------- GN apply + transpose (finalizes stats in-block) ----------------
__global__ __launch_bounds__(256) void gn_apply_kernel(
    const float* __restrict__ x, const float2* __restrict__ partial,
    const float* __restrict__ gw, const float* __restrict__ gb,
    ushort* __restrict__ y) {
  int bid = blockIdx.x;
  int b = bid >> 8;
  int rem = bid & 255;
  int ct = rem >> 6, nt = rem & 63;   // 64-channel tile = groups 2ct, 2ct+1
  int t = threadIdx.x;
  __shared__ float xs[64][65];
  __shared__ float smu2[2], srs2[2];
  if (t < 2) {
    float S = 0.f, SS = 0.f;
#pragma unroll
    for (int i = 0; i < 8; ++i) {
      float2 p = partial[(b << 6) | ((2 * ct + t) << 3) | i];
      S += p.x;
      SS += p.y;
    }
    float mu = S * (1.f / 131072.f);
    float var = SS * (1.f / 131072.f) - mu * mu;
    smu2[t] = mu;
    srs2[t] = rsqrtf(var + 1e-5f);
  }
  const float* xb = x + ((size_t)b * 256 + ct * 64) * 4096 + nt * 64;
  {
    int r = t >> 2, q = t & 3;
    const float4* src = (const float4*)(xb + (size_t)r * 4096 + q * 16);
#pragma unroll
    for (int i = 0; i < 4; ++i) {
      float4 v = src[i];
      xs[r][q * 16 + i * 4 + 0] = v.x;
      xs[r][q * 16 + i * 4 + 1] = v.y;
      xs[r][q * 16 + i * 4 + 2] = v.z;
      xs[r][q * 16 + i * 4 + 3] = v.w;
    }
  }
  __syncthreads();
  {
    int nr = t >> 2, q = t & 3;
    int c0 = q * 16;
    ushort tmp[16];
#pragma unroll
    for (int i = 0; i < 16; ++i) {
      int ci = c0 + i;                  // 0..63 within tile
      int ch = ct * 64 + ci;
      int gsel = ci >> 5;
      float sc = gw[ch] * srs2[gsel];
      float sh = gb[ch] - smu2[gsel] * sc;
      float v = xs[ci][nr] * sc + sh;
      tmp[i] = f2bf(v);
    }
    ushort* dst = y + ((size_t)b * 4096 + nt * 64 + nr) * 256 + ct * 64 + c0;
    uint p[8];
#pragma unroll
    for (int j = 0; j < 8; ++j) p[j] = (uint)tmp[2 * j] | ((uint)tmp[2 * j + 1] << 16);
    *(uint4*)dst = make_uint4(p[0], p[1], p[2], p[3]);
    *((uint4*)dst + 1) = make_uint4(p[4], p[5], p[6], p[7]);
  }
}

// ---------------- GEMM: C[M][N] = A[M][256] . B[N][256]^T (+bias, +resid) ----------------
// DMA staging (gload_lds w=16), XOR-swizzled source+reads, dbuf + counted vmcnt.
// MODE 2: f32 out, bias row + residual.
// MODE 6: fused q|k|v fp8 out (N=768, bias=bcat):
//   col<256 -> qb8[row][col]; col<512 -> kb8(+16MB)[row][col-256];
//   col>=512 -> vtb8(+32MB)[col-512][perm(row)]  (kv-perm on n=row).
template <int MODE>
__global__ __launch_bounds__(256) void gemm_bt(
    const ushort* __restrict__ A, const ushort* __restrict__ B,
    size_t aB, size_t bB, int M, int N,
    const float* __restrict__ bias, const float* __restrict__ resid,
    size_t rB, void* __restrict__ Cout, size_t cB) {
  int mTiles = M >> 7;
  int tm = blockIdx.x % mTiles, tn = blockIdx.x / mTiles;
  const ushort* Ab = A + blockIdx.y * aB + (size_t)tm * 128 * 256;
  const ushort* Bb = B + blockIdx.y * bB + (size_t)tn * 128 * 256;

  __shared__ ushort As[2][8192];   // [128][64] linear, XOR-swizzled contents
  __shared__ ushort Bs[2][8192];

  int t = threadIdx.x, lane = t & 63, w = t >> 6;
  int wr = w >> 1, wc = w & 1, lq = lane & 15, lg = lane >> 4;

  f32x4 acc[4][4];
#pragma unroll
  for (int i = 0; i < 4; ++i)
#pragma unroll
    for (int j = 0; j < 4; ++j) acc[i][j] = f32x4{0.f, 0.f, 0.f, 0.f};

  auto stageT = [&](int kb, int db) {
#pragma unroll
    for (int i = 0; i < 4; ++i) {
      int bu = i * 256 + w * 64;          // wave-uniform base unit (16B units)
      int u = bu + lane;
      int row = u >> 3, c = u & 7;
      int cl = c ^ (row & 7);             // pre-swizzled logical column unit
      const ushort* sa = Ab + (size_t)row * 256 + kb * 64 + cl * 8;
      __builtin_amdgcn_global_load_lds(
          (const __attribute__((address_space(1))) uint*)sa,
          (__attribute__((address_space(3))) uint*)(&As[db][0] + bu * 8), 16, 0, 0);
      const ushort* sb = Bb + (size_t)row * 256 + kb * 64 + cl * 8;
      __builtin_amdgcn_global_load_lds(
          (const __attribute__((address_space(1))) uint*)sb,
          (__attribute__((address_space(3))) uint*)(&Bs[db][0] + bu * 8), 16, 0, 0);
    }
  };

  stageT(0, 0);

#pragma unroll 1
  for (int kb = 0; kb < 4; ++kb) {
    if (kb < 3) {
      stageT(kb + 1, (kb + 1) & 1);
      asm volatile("s_waitcnt vmcnt(8)" ::: "memory");
    } else {
      asm volatile("s_waitcnt vmcnt(0)" ::: "memory");
    }
    __builtin_amdgcn_s_barrier();
    const ushort* Abf = &As[kb & 1][0];
    const ushort* Bbf = &Bs[kb & 1][0];
#pragma unroll
    for (int ks = 0; ks < 2; ++ks) {
      s16x8 af[4], bf[4];
#pragma unroll
      for (int mt = 0; mt < 4; ++mt) {
        int row = wr * 64 + mt * 16 + lq;
        af[mt] = *(const s16x8*)&Abf[row * 64 + (((ks * 4 + lg) ^ (row & 7)) << 3)];
      }
#pragma unroll
      for (int nt = 0; nt < 4; ++nt) {
        int row = wc * 64 + nt * 16 + lq;
        bf[nt] = *(const s16x8*)&Bbf[row * 64 + (((ks * 4 + lg) ^ (row & 7)) << 3)];
      }
#pragma unroll
      for (int mt = 0; mt < 4; ++mt)
#pragma unroll
        for (int nt = 0; nt < 4; ++nt)
          acc[mt][nt] = MFMA16(af[mt], bf[nt], acc[mt][nt]);
    }
    asm volatile("" ::: "memory");
    __builtin_amdgcn_s_barrier();
    asm volatile("" ::: "memory");
  }

  int mBase = tm * 128 + wr * 64;
  int nBase = tn * 128 + wc * 64;
#pragma unroll
  for (int mt = 0; mt < 4; ++mt) {
#pragma unroll
    for (int nt = 0; nt < 4; ++nt) {
#pragma unroll
      for (int r = 0; r < 4; ++r) {
        int row = mBase + mt * 16 + lg * 4 + r;
        int col = nBase + nt * 16 + lq;
        float v = acc[mt][nt][r];
        if (MODE == 6) {
          v += bias[col];
          uint pk8 = (uint)__builtin_amdgcn_cvt_pk_fp8_f32(v, v, 0, false);
          u8* Cb = (u8*)Cout + blockIdx.y * cB;
          if (col < 512) {
            u8* C = Cb + ((col >= 256) ? 16777216 : 0);
            C[(size_t)row * 256 + (col & 255)] = (u8)(pk8 & 0xff);
          } else {
            int rr = row & 31;
            int pr = (row & ~31) |
                     ((rr & 7) | (((rr >> 4) & 1) << 3) | (((rr >> 3) & 1) << 4));
            u8* C = Cb + 33554432;
            C[(size_t)(col - 512) * 4096 + pr] = (u8)(pk8 & 0xff);
          }
        } else {  // MODE 2
          v += bias[row];
          size_t idx = (size_t)row * N + col;
          float* C = (float*)Cout + blockIdx.y * cB;
          C[idx] = v + resid[blockIdx.y * rB + idx];
        }
      }
    }
  }
}

// ---------------- Flash attention v11: MX-scaled QK (K=64), fp8 PV ----------------
// Grid 512 = 8 batch x 32 qtiles(128 rows) x 2 kv-halves; 256 thr = 4 waves.
__global__ __launch_bounds__(256, 2) void attn11_kernel(
    const u8* __restrict__ q, const u8* __restrict__ k,
    const u8* __restrict__ vT, ushort* __restrict__ pb0,
    ushort* __restrict__ pb1, float* __restrict__ mlbuf) {
  const int bb = blockIdx.x & 7;          // batch -> XCD pinning
  const int rem = blockIdx.x >> 3;        // 0..63
  const int qt = rem & 31;                // 32 qtiles x 128 rows
  const int half = rem >> 5;              // kv half
  const int t = threadIdx.x, w = t >> 6, lane = t & 63;
  const int lq = lane & 31, lh = lane >> 5;

  __shared__ u8 Lf[65536];   // main loop: 2 bufs x (K 8KB + V 8KB) = 32KB; epilogue 64KB

  const u8* kb = k + (size_t)bb * (4096 * 256);
  const u8* vb = vT + (size_t)bb * (4096 * 256);

  // Q fragments for MX QK: frag ks holds channels ks*64 + lh*32 .. +31 (32B)
  const int qrow = bb * 4096 + qt * 128 + w * 32 + lq;
  i32x8 qf8[4];
  {
    const u8* qp = q + (size_t)qrow * 256 + lh * 32;
#pragma unroll
    for (int ks = 0; ks < 4; ++ks) {
      u32x4 lo = *(const u32x4*)(qp + ks * 64);
      u32x4 hi = *(const u32x4*)(qp + ks * 64 + 16);
      qf8[ks] = i32x8{(int)lo[0], (int)lo[1], (int)lo[2], (int)lo[3],
                      (int)hi[0], (int)hi[1], (int)hi[2], (int)hi[3]};
    }
  }
  f32x16 oacc[8];
#pragma unroll
  for (int i = 0; i < 8; ++i) oacc[i] = (f32x16)(0.f);
  float mrun = -3e38f, lrun = 0.f;        // exp2 (log2) domain
  const float cs = 0.0625f * 1.44269504f; // scale * log2(e)

  // stage one 32-row chunk (16KB) into buffer db; 4 gload_lds per thread
  auto stage = [&](int it, int db) {
    const int ci = half * 64 + it;
    const u8* kcb = kb + (size_t)ci * (32 * 256);
    const u8* vcb = vb + (size_t)ci * 32;
    u8* base = Lf + db * 16384;
#pragma unroll
    for (int i = 0; i < 2; ++i) {
      int bu = w * 128 + i * 64;          // wave-uniform base unit (16B units)
      int Pu = bu + lane;
      {  // K region: logical L = row*16 + off16; P = L ^ ((L>>4)&7)
        int Lu = Pu ^ ((Pu >> 4) & 7);
        const u8* ksrc = kcb + (Lu >> 4) * 256 + (Lu & 15) * 16;
        __builtin_amdgcn_global_load_lds(
            (const __attribute__((address_space(1))) uint*)ksrc,
            (__attribute__((address_space(3))) uint*)(base + bu * 16), 16, 0, 0);
      }
      {  // V region: logical L = drow*2 + lhv; P = L ^ ((L>>3)&7)
        int Lu = Pu ^ ((Pu >> 3) & 7);
        const u8* vsrc = vcb + (size_t)(Lu >> 1) * 4096 + (Lu & 1) * 16;
        __builtin_amdgcn_global_load_lds(
            (const __attribute__((address_space(1))) uint*)vsrc,
            (__attribute__((address_space(3))) uint*)(base + 8192 + bu * 16), 16, 0, 0);
      }
    }
  };

  stage(0, 0);

#pragma unroll 1
  for (int j = 0; j < 64; ++j) {
    if (j < 63) {
      stage(j + 1, (j + 1) & 1);
      asm volatile("s_waitcnt vmcnt(4)" ::: "memory");
    } else {
      asm volatile("s_waitcnt vmcnt(0)" ::: "memory");
    }
    __builtin_amdgcn_s_barrier();

    const u8* Kbf = Lf + (j & 1) * 16384;
    const u8* Vbf = Kbf + 8192;

    // ---- QK^T: 4 MX-scaled MFMAs (K=64 each), 2 acc chains ----
    __builtin_amdgcn_s_setprio(1);
    f32x16 sA = (f32x16)(0.f), sB = (f32x16)(0.f);
#pragma unroll
    for (int ks = 0; ks < 4; ++ks) {
      int u0 = (lq * 16 + ks * 4 + lh * 2) ^ (lq & 7);
      int u1 = (lq * 16 + ks * 4 + lh * 2 + 1) ^ (lq & 7);
      u32x4 k0 = *(const u32x4*)(Kbf + u0 * 16);
      u32x4 k1 = *(const u32x4*)(Kbf + u1 * 16);
      i32x8 kf = i32x8{(int)k0[0], (int)k0[1], (int)k0[2], (int)k0[3],
                       (int)k1[0], (int)k1[1], (int)k1[2], (int)k1[3]};
      if (ks & 1) sB = MFMAMX(kf, qf8[ks], sB);
      else        sA = MFMAMX(kf, qf8[ks], sA);
    }
    __builtin_amdgcn_s_setprio(0);
    // ---- lean online softmax: max on raw sums (1 mul), fma+exp2 fused ----
    float tv[16];
#pragma unroll
    for (int r = 0; r < 16; ++r) tv[r] = sA[r] + sB[r];
    float g0 = max3f(tv[0], tv[1], tv[2]);
    float g1 = max3f(tv[3], tv[4], tv[5]);
    float g2 = max3f(tv[6], tv[7], tv[8]);
    float g3 = max3f(tv[9], tv[10], tv[11]);
    float g4 = max3f(tv[12], tv[13], tv[14]);
    float pmax_t = max3f(max3f(g0, g1, tv[15]), fmaxf(g2, g3), g4);
    pmax_t = fmaxf(pmax_t, __shfl_xor(pmax_t, 32));
    float pmax = pmax_t * cs;
    if (!__all(pmax - mrun <= 8.f)) {     // defer-max; 2^8=256 < fp8 max 448
      float mnew = fmaxf(mrun, pmax);
      float alpha = __builtin_exp2f(mrun - mnew);
#pragma unroll
      for (int i = 0; i < 8; ++i) oacc[i] *= alpha;
      lrun *= alpha;
      mrun = mnew;
    }
    float nm = -mrun;
    float sv[16], psum = 0.f;
#pragma unroll
    for (int r = 0; r < 16; ++r) {
      sv[r] = __builtin_exp2f(__builtin_fmaf(tv[r], cs, nm));
      psum += sv[r];
    }
    psum += __shfl_xor(psum, 32);
    lrun += psum;
    // ---- P -> fp8 B-frags: 8 cvt_pk_fp8 + 2 permlane32_swap ----
    uint Aw = (uint)__builtin_amdgcn_cvt_pk_fp8_f32(sv[0], sv[1], 0, false);
    Aw = (uint)__builtin_amdgcn_cvt_pk_fp8_f32(sv[2], sv[3], (int)Aw, true);
    uint Bw = (uint)__builtin_amdgcn_cvt_pk_fp8_f32(sv[4], sv[5], 0, false);
    Bw = (uint)__builtin_amdgcn_cvt_pk_fp8_f32(sv[6], sv[7], (int)Bw, true);
    uint Cw = (uint)__builtin_amdgcn_cvt_pk_fp8_f32(sv[8], sv[9], 0, false);
    Cw = (uint)__builtin_amdgcn_cvt_pk_fp8_f32(sv[10], sv[11], (int)Cw, true);
    uint Dw = (uint)__builtin_amdgcn_cvt_pk_fp8_f32(sv[12], sv[13], 0, false);
    Dw = (uint)__builtin_amdgcn_cvt_pk_fp8_f32(sv[14], sv[15], (int)Dw, true);
    asm("v_permlane32_swap_b32 %0, %1" : "+v"(Aw), "+v"(Bw));
    asm("v_permlane32_swap_b32 %0, %1" : "+v"(Cw), "+v"(Dw));
    long pf0 = __builtin_bit_cast(long, (u32x2){Aw, Bw});  // kv slots 0..15
    long pf1 = __builtin_bit_cast(long, (u32x2){Cw, Dw});  // kv slots 16..31
    // ---- PV: one b128 per d-block feeds both MFMAs ----
    __builtin_amdgcn_s_setprio(1);
#pragma unroll
    for (int db = 0; db < 8; ++db) {
      int L = (db * 32 + lq) * 2 + lh;
      int Pu = L ^ ((L >> 3) & 7);
      u32x4 vr = *(const u32x4*)(Vbf + Pu * 16);
      s64x2 vp = __builtin_bit_cast(s64x2, vr);
      oacc[db] = MFMAF8(vp[0], pf0, oacc[db]);
      oacc[db] = MFMAF8(vp[1], pf1, oacc[db]);
    }
    __builtin_amdgcn_s_setprio(0);
    asm volatile("" ::: "memory");
    __builtin_amdgcn_s_barrier();
    asm volatile("" ::: "memory");
  }

  // ---- epilogue: raw partials -> LDS transpose (XOR-swz) -> coalesced store ----
  {
    uint* wregu = (uint*)Lf + w * 4096;   // 32 q-rows x 128 uints per wave
#pragma unroll
    for (int db = 0; db < 8; ++db)
#pragma unroll
      for (int rp = 0; rp < 8; ++rp) {
        int r0 = rp * 2;
        int d0 = db * 32 + (r0 & 3) + 8 * (r0 >> 2) + 4 * lh;
        uint pk;
        asm("v_cvt_pk_bf16_f32 %0, %1, %2"
            : "=v"(pk) : "v"(oacc[db][r0]), "v"(oacc[db][r0 + 1]));
        int idx = lq * 128 + (d0 >> 1);
        wregu[idx ^ ((lq & 7) << 2)] = pk;
      }
    if (lh == 0) {
      int idx = half * 32768 + bb * 4096 + qt * 128 + w * 32 + lq;
      mlbuf[idx] = mrun;                  // exp2-domain max
      mlbuf[65536 + idx] = lrun;
    }
  }
  __syncthreads();
  {
    int r = t >> 1;                        // 0..127 row in tile
    int wv2 = r >> 5, lqr = r & 31;
    const uint* basep = (const uint*)Lf + wv2 * 4096;
    ushort* pbase = half ? pb1 : pb0;
    ushort* dstr = pbase + ((size_t)bb * 4096 + qt * 128 + r) * 256 + (t & 1) * 128;
#pragma unroll
    for (int jj = 0; jj < 16; ++jj) {
      int ui = lqr * 128 + (t & 1) * 64 + jj * 4;
      u32x4 v = *(const u32x4*)(basep + (ui ^ ((lqr & 7) << 2)));
      *(u32x4*)(dstr + jj * 8) = v;
    }
  }
}

// ---------------- merge the two kv-half partials (exp2 domain) ----------------
__global__ __launch_bounds__(256) void attn_merge_kernel(
    const ushort* __restrict__ pb0, const ushort* __restrict__ pb1,
    const float* __restrict__ mlbuf, ushort* __restrict__ o) {
  int gr = blockIdx.x * 8 + (threadIdx.x >> 5);   // global row 0..32767
  int dq = threadIdx.x & 31;                      // 8 d-elems each
  float m0 = mlbuf[gr], m1 = mlbuf[32768 + gr];
  float l0 = mlbuf[65536 + gr], l1 = mlbuf[65536 + 32768 + gr];
  float M = fmaxf(m0, m1);
  float e0 = __builtin_exp2f(m0 - M), e1 = __builtin_exp2f(m1 - M);
  float inv = 1.f / (l0 * e0 + l1 * e1);
  float w0 = e0 * inv, w1 = e1 * inv;
  const size_t off = (size_t)gr * 256 + dq * 8;
  u32x4 a = *(const u32x4*)(pb0 + off);
  u32x4 b = *(const u32x4*)(pb1 + off);
  uint outw[4];
#pragma unroll
  for (int i = 0; i < 4; ++i) {
    float alo = __builtin_bit_cast(float, a[i] << 16);
    float ahi = __builtin_bit_cast(float, a[i] & 0xffff0000u);
    float blo = __builtin_bit_cast(float, b[i] << 16);
    float bhi = __builtin_bit_cast(float, b[i] & 0xffff0000u);
    float flo = alo * w0 + blo * w1;
    float fhi = ahi * w0 + bhi * w1;
    asm("v_cvt_pk_bf16_f32 %0, %1, %2" : "=v"(outw[i]) : "v"(flo), "v"(fhi));
  }
  u32x4 ov = {outw[0], outw[1], outw[2], outw[3]};
  *(u32x4*)(o + off) = ov;
}

extern "C" void kernel_launch(void* const* d_in, const int* in_sizes, int n_in,
                              void* d_out, int out_size, void* d_ws, size_t ws_size,
                              hipStream_t stream) {
  const float* x   = (const float*)d_in[0];
  const float* gnw = (const float*)d_in[1];
  const float* gnb = (const float*)d_in[2];
  const float* wq  = (const float*)d_in[3];
  const float* bq  = (const float*)d_in[4];
  const float* wk  = (const float*)d_in[5];
  const float* bk  = (const float*)d_in[6];
  const float* wv  = (const float*)d_in[7];
  const float* bv  = (const float*)d_in[8];
  const float* wp  = (const float*)d_in[9];
  const float* bp  = (const float*)d_in[10];

  const size_t SEQ = 4096, CH = 256;
  const size_t MAT = SEQ * CH;
  char* ws = (char*)d_ws;
  const size_t BUF = 8 * MAT * 2;        // 16 MiB
  ushort* y    = (ushort*)(ws + 0 * BUF);
  u8*     qb8  = (u8*)(ws + 1 * BUF);    // fp8 q [b][n][c]  (8 MB)
  u8*     kb8  = (u8*)(ws + 2 * BUF);    // fp8 k [b][n][c]  (= qb8 + 16MB)
  u8*     vtb8 = (u8*)(ws + 3 * BUF);    // fp8 vT [b][c][n], kv-permuted (= qb8 + 32MB)
  ushort* pb1  = (ushort*)(ws + 4 * BUF);
  ushort* pb0  = y;                      // y dead after QKV GEMM
  ushort* oab  = (ushort*)(ws + 1 * BUF);// q dead after attn; merge writes here
  ushort* wqb  = (ushort*)(ws + 5 * BUF);
  ushort* wkb  = wqb + 65536;            // contiguous: [wq;wk;wv] fused B
  ushort* wvb  = wkb + 65536;
  ushort* wpb  = wvb + 65536;
  float*  bcat   = (float*)(wpb + 65536);     // 768 floats
  float2* partial = (float2*)(bcat + 768);    // 512 float2 (4KB)
  float*  mlbuf  = (float*)d_out;        // 512KB scratch; overwritten by proj GEMM

  cvt_w_kernel<<<64, 256, 0, stream>>>(wq, wk, wv, wp, wqb, wkb, wvb, wpb,
                                       bq, bk, bv, bcat);
  gn_stats_kernel<<<512, 256, 0, stream>>>(x, partial);
  gn_apply_kernel<<<2048, 256, 0, stream>>>(x, partial, gnw, gnb, y);

  // fused q|k|v GEMM: B = [wq;wk;wv] (768 rows) -> qb8 / kb8 / vtb8
  gemm_bt<6><<<dim3(192, 8), 256, 0, stream>>>(y, wqb, MAT, 0, 4096, 768, bcat,
                                               nullptr, 0, qb8, MAT);

  attn11_kernel<<<512, 256, 0, stream>>>(qb8, kb8, vtb8, pb0, pb1, mlbuf);
  attn_merge_kernel<<<4096, 256, 0, stream>>>(pb0, pb1, mlbuf, oab);

  gemm_bt<2><<<dim3(64, 8), 256, 0, stream>>>(wpb, oab, 0, MAT, 256, 4096, bp,
                                              x, MAT, d_out, MAT);
}